// Round 5
// baseline (734.675 us; speedup 1.0000x reference)
//
#include <hip/hip_runtime.h>
#include <math.h>

// ---------------- constants ----------------
constexpr int L      = 2048;
constexpr int NH     = 16;
constexpr int DINNER = 1024;
constexpr int MNH    = 32;
constexpr int CONVCH = 1152;
constexpr int INDIMP = 2304;   // padded stride for zxbcdt (2208 -> 2304, N%128)
constexpr int CHUNK  = 64;
constexpr int NCH    = 32;

using bf16x8 = __attribute__((ext_vector_type(8))) short;
using f32x4  = __attribute__((ext_vector_type(4))) float;

__device__ __forceinline__ f32x4 splat4(float x) { return (f32x4){x, x, x, x}; }

__device__ __forceinline__ unsigned short f2bf(float f) {
  unsigned u = __float_as_uint(f);
  return (unsigned short)((u + 0x7fffu + ((u >> 16) & 1u)) >> 16);
}
__device__ __forceinline__ float bf2f(unsigned short h) {
  return __uint_as_float((unsigned)h << 16);
}

// ---------------- fp32 GEMM v3 (small index-critical shapes) ----------------
__global__ __launch_bounds__(256) void gemm_f32_v3(
    const float* __restrict__ A, const float* __restrict__ W,
    float* __restrict__ C, int M, int N, int K) {
  __shared__ float As[16][132];
  __shared__ float Ws[16][132];
  int tid = threadIdx.x;
  int bm = blockIdx.y * 128, bn = blockIdx.x * 128;
  int kper = K / gridDim.z;
  int kb = blockIdx.z * kper, ke = kb + kper;
  int lr = tid >> 1;
  int lh = (tid & 1) * 8;
  int tx = tid & 15, ty = tid >> 4;
  bool wok = (bn + lr < N);
  const float* arow = A + (size_t)(bm + lr) * K + lh;
  const float* wrow = W + (size_t)(bn + lr) * K + lh;
  float4 a0, a1, w0, w1;
  auto gload = [&](int k0) {
    a0 = *(const float4*)(arow + k0);
    a1 = *(const float4*)(arow + k0 + 4);
    w0 = make_float4(0.f, 0.f, 0.f, 0.f); w1 = w0;
    if (wok) {
      w0 = *(const float4*)(wrow + k0);
      w1 = *(const float4*)(wrow + k0 + 4);
    }
  };
  f32x4 acc0[8] = {}, acc1[8] = {};
  gload(kb);
  for (int k0 = kb; k0 < ke; k0 += 16) {
    __syncthreads();
    As[lh+0][lr]=a0.x; As[lh+1][lr]=a0.y; As[lh+2][lr]=a0.z; As[lh+3][lr]=a0.w;
    As[lh+4][lr]=a1.x; As[lh+5][lr]=a1.y; As[lh+6][lr]=a1.z; As[lh+7][lr]=a1.w;
    Ws[lh+0][lr]=w0.x; Ws[lh+1][lr]=w0.y; Ws[lh+2][lr]=w0.z; Ws[lh+3][lr]=w0.w;
    Ws[lh+4][lr]=w1.x; Ws[lh+5][lr]=w1.y; Ws[lh+6][lr]=w1.z; Ws[lh+7][lr]=w1.w;
    __syncthreads();
    if (k0 + 16 < ke) gload(k0 + 16);
#pragma unroll
    for (int kk = 0; kk < 16; ++kk) {
      f32x4 b0 = *(const f32x4*)&Ws[kk][tx * 4];
      f32x4 b1 = *(const f32x4*)&Ws[kk][64 + tx * 4];
      f32x4 al = *(const f32x4*)&As[kk][ty * 8];
      f32x4 ah = *(const f32x4*)&As[kk][ty * 8 + 4];
#pragma unroll
      for (int i = 0; i < 4; ++i) {
        acc0[i]     += splat4(al[i]) * b0;
        acc1[i]     += splat4(al[i]) * b1;
        acc0[i + 4] += splat4(ah[i]) * b0;
        acc1[i + 4] += splat4(ah[i]) * b1;
      }
    }
  }
  bool single = (gridDim.z == 1);
#pragma unroll
  for (int i = 0; i < 8; ++i) {
    int row = bm + ty * 8 + i;
    float* crow = C + (size_t)row * N;
    int c0 = bn + tx * 4, c1 = bn + 64 + tx * 4;
    if (c0 + 3 < N) {
      if (single) *(f32x4*)(crow + c0) = acc0[i];
      else {
        atomicAdd(crow + c0 + 0, acc0[i][0]); atomicAdd(crow + c0 + 1, acc0[i][1]);
        atomicAdd(crow + c0 + 2, acc0[i][2]); atomicAdd(crow + c0 + 3, acc0[i][3]);
      }
    }
    if (c1 + 3 < N) {
      if (single) *(f32x4*)(crow + c1) = acc1[i];
      else {
        atomicAdd(crow + c1 + 0, acc1[i][0]); atomicAdd(crow + c1 + 1, acc1[i][1]);
        atomicAdd(crow + c1 + 2, acc1[i][2]); atomicAdd(crow + c1 + 3, acc1[i][3]);
      }
    }
  }
}

// ---------------- 1024x1024 transpose ----------------
__global__ __launch_bounds__(256) void transpose1024_kernel(
    const float* __restrict__ src, float* __restrict__ dst) {
  __shared__ float t[32][33];
  int bx = blockIdx.x & 31, by = blockIdx.x >> 5;
  int tx = threadIdx.x & 31, ty8 = threadIdx.x >> 5;
  for (int r = ty8; r < 32; r += 8)
    t[r][tx] = src[(size_t)(by * 32 + r) * 1024 + bx * 32 + tx];
  __syncthreads();
  for (int r = ty8; r < 32; r += 8)
    dst[(size_t)(bx * 32 + r) * 1024 + by * 32 + tx] = t[tx][r];
}

// ---------------- bf16 MFMA GEMM (double-buffered LDS: stage(t+1) || compute(t)) ----------------
// T1: XCD-aware (x,y) tile swizzle (identity fallback when nwg%8!=0).
// T3-min: 2-deep pipeline (structure-bound at ~445 TF for the 2048-class shapes;
// 128²+8-phase is the documented open/failed quadrant — do not deepen further).
__global__ __launch_bounds__(256) void gemm_bf16_kernel(
    const unsigned short* __restrict__ A, const unsigned short* __restrict__ W,
    float* __restrict__ C, int M, int N, int K, int lda, int ldb, int ldc) {
  __shared__ unsigned short As[2][128 * 64];
  __shared__ unsigned short Ws[2][128 * 64];
  int tid = threadIdx.x;
  int bx = blockIdx.x, by = blockIdx.y;
  int nxy = gridDim.x * gridDim.y;
  if ((nxy & 7) == 0) {
    int lin = by * gridDim.x + bx;
    int cpx = nxy >> 3;
    int swz = (lin & 7) * cpx + (lin >> 3);
    bx = swz % gridDim.x;
    by = swz / gridDim.x;
  }
  int bm = by * 128, bn = bx * 128;
  int kper = K / gridDim.z;
  int k_begin = blockIdx.z * kper;
  int k_end = k_begin + kper;
  int wv = tid >> 6, lane = tid & 63;
  int wrow = (wv >> 1) * 64, wcol = (wv & 1) * 64;
  int lrow = lane & 15, quad = lane >> 4;

  f32x4 acc[4][4] = {};

  auto stage = [&](int b, int k0) {
#pragma unroll
    for (int it = 0; it < 4; ++it) {
      int s = it * 256 + tid;
      int r = s >> 3;
      int q = (s & 7) ^ (r & 7);
      const unsigned short* ga = A + (size_t)(bm + r) * lda + k0 + q * 8;
      const unsigned short* gw = W + (size_t)(bn + r) * ldb + k0 + q * 8;
      __builtin_amdgcn_global_load_lds((const __attribute__((address_space(1))) void*)ga,
                                       (__attribute__((address_space(3))) void*)&As[b][s * 8], 16, 0, 0);
      __builtin_amdgcn_global_load_lds((const __attribute__((address_space(1))) void*)gw,
                                       (__attribute__((address_space(3))) void*)&Ws[b][s * 8], 16, 0, 0);
    }
  };

  stage(0, k_begin);
  int cur = 0;
  for (int k0 = k_begin; k0 < k_end; k0 += 64) {
    __syncthreads();
    if (k0 + 64 < k_end) stage(cur ^ 1, k0 + 64);
#pragma unroll
    for (int ks = 0; ks < 2; ++ks) {
      bf16x8 af[4], wf[4];
#pragma unroll
      for (int i = 0; i < 4; ++i) {
        int ra = wrow + i * 16 + lrow;
        int qa = (ks * 4 + quad) ^ (ra & 7);
        af[i] = *(const bf16x8*)&As[cur][(ra * 8 + qa) * 8];
        int rw = wcol + i * 16 + lrow;
        int qw = (ks * 4 + quad) ^ (rw & 7);
        wf[i] = *(const bf16x8*)&Ws[cur][(rw * 8 + qw) * 8];
      }
#pragma unroll
      for (int i = 0; i < 4; ++i)
#pragma unroll
        for (int j = 0; j < 4; ++j)
          acc[i][j] = __builtin_amdgcn_mfma_f32_16x16x32_bf16(af[i], wf[j], acc[i][j], 0, 0, 0);
    }
    cur ^= 1;
  }
  bool single = (gridDim.z == 1);
#pragma unroll
  for (int i = 0; i < 4; ++i)
#pragma unroll
    for (int j = 0; j < 4; ++j)
#pragma unroll
      for (int r = 0; r < 4; ++r) {
        int row = bm + wrow + i * 16 + quad * 4 + r;
        int col = bn + wcol + j * 16 + lrow;
        float v = acc[i][j][r];
        if (single) C[(size_t)row * ldc + col] = v;
        else atomicAdd(&C[(size_t)row * ldc + col], v);
      }
}

// ---------------- conversions ----------------
// 3-slot aug (value path): A=[h,l,h], W=[h,h,l]
__global__ __launch_bounds__(256) void conv_augA_kernel(
    const float* __restrict__ src, unsigned short* __restrict__ dst,
    int total, int K, int sld) {
  int i = blockIdx.x * 256 + threadIdx.x;
  if (i >= total) return;
  int m = i / K, k = i - m * K;
  float f = src[(size_t)m * sld + k];
  unsigned short hi = f2bf(f);
  unsigned short lo = f2bf(f - bf2f(hi));
  size_t o = ((size_t)m * K + k) * 3;
  dst[o] = hi; dst[o + 1] = lo; dst[o + 2] = hi;
}
__global__ __launch_bounds__(256) void conv_augW_kernel(
    const float* __restrict__ src, unsigned short* __restrict__ dst,
    int rows, int total, int K, int sld) {
  int i = blockIdx.x * 256 + threadIdx.x;
  if (i >= total) return;
  int n = i / K, k = i - n * K;
  unsigned short hi = 0, lo = 0;
  if (n < rows) {
    float f = src[(size_t)n * sld + k];
    hi = f2bf(f);
    lo = f2bf(f - bf2f(hi));
  }
  size_t o = ((size_t)n * K + k) * 3;
  dst[o] = hi; dst[o + 1] = hi; dst[o + 2] = lo;
}
// 6-slot triple split (index path): A=[h,m,l,h,m,h], W=[h,h,h,m,m,l]
__global__ __launch_bounds__(256) void conv_tripA_kernel(
    const float* __restrict__ src, unsigned short* __restrict__ dst,
    int total, int K) {
  int i = blockIdx.x * 256 + threadIdx.x;
  if (i >= total) return;
  float f = src[i];
  unsigned short h = f2bf(f);
  float r1 = f - bf2f(h);
  unsigned short m = f2bf(r1);
  unsigned short l = f2bf(r1 - bf2f(m));
  size_t o = (size_t)i * 6;
  dst[o] = h; dst[o + 1] = m; dst[o + 2] = l;
  dst[o + 3] = h; dst[o + 4] = m; dst[o + 5] = h;
}
__global__ __launch_bounds__(256) void conv_tripW_kernel(
    const float* __restrict__ src, unsigned short* __restrict__ dst,
    int rows, int total, int K) {
  int i = blockIdx.x * 256 + threadIdx.x;
  if (i >= total) return;
  int n = i / K, k = i - n * K;
  unsigned short h = 0, m = 0, l = 0;
  if (n < rows) {
    float f = src[(size_t)n * K + k];
    h = f2bf(f);
    float r1 = f - bf2f(h);
    m = f2bf(r1);
    l = f2bf(r1 - bf2f(m));
  }
  size_t o = (size_t)i * 6;
  dst[o] = h; dst[o + 1] = h; dst[o + 2] = h;
  dst[o + 3] = m; dst[o + 4] = m; dst[o + 5] = l;
}

// ---------------- conv1d(4-tap, causal) + SiLU (float4 across channels) ----------------
// G13: vectorized. Same per-element tap order as the scalar version.
__global__ __launch_bounds__(256) void conv_silu_kernel(
    const float* __restrict__ zxbcdt, const float* __restrict__ conv_w,
    const float* __restrict__ conv_b, float* __restrict__ xBC) {
  int idx = blockIdx.x * 256 + threadIdx.x;
  if (idx >= L * (CONVCH / 4)) return;
  int l = idx / (CONVCH / 4);
  int c4 = (idx - l * (CONVCH / 4)) * 4;
  f32x4 acc = *(const f32x4*)(conv_b + c4);
  f32x4 w0 = *(const f32x4*)(conv_w + (c4 + 0) * 4);
  f32x4 w1 = *(const f32x4*)(conv_w + (c4 + 1) * 4);
  f32x4 w2 = *(const f32x4*)(conv_w + (c4 + 2) * 4);
  f32x4 w3 = *(const f32x4*)(conv_w + (c4 + 3) * 4);
#pragma unroll
  for (int k = 0; k < 4; ++k) {
    int ls = l - 3 + k;
    if (ls >= 0) {
      f32x4 z = *(const f32x4*)(zxbcdt + (size_t)ls * INDIMP + DINNER + c4);
      acc[0] += z[0] * w0[k];
      acc[1] += z[1] * w1[k];
      acc[2] += z[2] * w2[k];
      acc[3] += z[3] * w3[k];
    }
  }
  f32x4 r;
#pragma unroll
  for (int j = 0; j < 4; ++j) r[j] = acc[j] / (1.f + expf(-acc[j]));
  *(f32x4*)(xBC + (size_t)l * CONVCH + c4) = r;
}

// ---------------- fused dt/softplus + lcd cumulative scan ----------------
// Replaces dt_kernel + lcd_kernel; logdA buffer eliminated.
// thread i = (c,h): sequential scan over the 64 chunk steps.
__global__ __launch_bounds__(256) void dtlcd_kernel(
    const float* __restrict__ zxbcdt, const float* __restrict__ dt_bias,
    const float* __restrict__ A_log, float* __restrict__ dt,
    float* __restrict__ lcd) {
  int i = blockIdx.x * 256 + threadIdx.x;   // i < NCH*MNH = 1024
  int c = i >> 5, h = i & 31;
  float bias = dt_bias[h];
  float nega = -expf(A_log[h]);
  float s = 0.f;
  const float* zp = zxbcdt + (size_t)(c * CHUNK) * INDIMP + 2176 + h;
  float* lp = lcd + (size_t)i * CHUNK;
  for (int t = 0; t < CHUNK; ++t) {
    float xv = zp[(size_t)t * INDIMP] + bias;
    float sp = fmaxf(xv, 0.f) + log1pf(expf(-fabsf(xv)));
    dt[(c * CHUNK + t) * MNH + h] = sp;
    s += sp * nega;
    lp[t] = s;
  }
}

// ---------------- G[c][t][s] = C_t . B_s ----------------
__global__ __launch_bounds__(256) void chunk_G_kernel(
    const float* __restrict__ xBC, float* __restrict__ G) {
  int c = blockIdx.x, tid = threadIdx.x;
  __shared__ float BsT[64][68];
  __shared__ float Cs[64][65];
  int t = tid >> 2, q = tid & 3;
  const float* row = xBC + (size_t)(c * 64 + t) * CONVCH + DINNER;
#pragma unroll
  for (int j = 0; j < 16; j += 4) {
    float4 b = *(const float4*)(row + q * 16 + j);
    BsT[q * 16 + j + 0][t] = b.x; BsT[q * 16 + j + 1][t] = b.y;
    BsT[q * 16 + j + 2][t] = b.z; BsT[q * 16 + j + 3][t] = b.w;
    float4 cv = *(const float4*)(row + 64 + q * 16 + j);
    Cs[t][q * 16 + j + 0] = cv.x; Cs[t][q * 16 + j + 1] = cv.y;
    Cs[t][q * 16 + j + 2] = cv.z; Cs[t][q * 16 + j + 3] = cv.w;
  }
  __syncthreads();
  int s0 = q * 16;
  f32x4 g0 = {}, g1 = {}, g2 = {}, g3 = {};
  for (int n = 0; n < 64; ++n) {
    f32x4 cv = splat4(Cs[t][n]);
    g0 += cv * *(const f32x4*)&BsT[n][s0];
    g1 += cv * *(const f32x4*)&BsT[n][s0 + 4];
    g2 += cv * *(const f32x4*)&BsT[n][s0 + 8];
    g3 += cv * *(const f32x4*)&BsT[n][s0 + 12];
  }
  float* gp = G + ((size_t)c * 64 + t) * 64 + s0;
  *(f32x4*)gp = g0; *(f32x4*)(gp + 4) = g1; *(f32x4*)(gp + 8) = g2; *(f32x4*)(gp + 12) = g3;
}

// ---------------- scan pass A ----------------
__global__ __launch_bounds__(256) void scan_local_kernel(
    const float* __restrict__ xBC, const float* __restrict__ dt,
    const float* __restrict__ lcd, float* __restrict__ hstate) {
  int c = blockIdx.x >> 5, h = blockIdx.x & 31;
  int tid = threadIdx.x;
  __shared__ float Bs[64][68];
  __shared__ float xss[64][36];
  __shared__ float w2s[64];
  int t0 = c * CHUNK;
  int t = tid >> 2, q = tid & 3;
  const float* row = xBC + (size_t)(t0 + t) * CONVCH;
#pragma unroll
  for (int j = 0; j < 16; j += 4)
    *(float4*)&Bs[t][q * 16 + j] = *(const float4*)(row + DINNER + q * 16 + j);
  if (q < 2) {
#pragma unroll
    for (int j = 0; j < 16; j += 4)
      *(float4*)&xss[t][q * 16 + j] = *(const float4*)(row + h * 32 + q * 16 + j);
  }
  if (tid < 64) {
    const float* lc = lcd + ((size_t)c * 32 + h) * CHUNK;
    w2s[tid] = expf(lc[63] - lc[tid]) * dt[(t0 + tid) * MNH + h];
  }
  __syncthreads();
  int n = tid >> 2, pg = (tid & 3) * 8;
  f32x4 h0 = {}, h1 = {};
  for (int s = 0; s < 64; ++s) {
    f32x4 wb = splat4(w2s[s] * Bs[s][n]);
    h0 += wb * *(const f32x4*)&xss[s][pg];
    h1 += wb * *(const f32x4*)&xss[s][pg + 4];
  }
  float* hp = hstate + ((size_t)c * 32 + h) * 2048 + n * 32 + pg;
  *(f32x4*)hp = h0; *(f32x4*)(hp + 4) = h1;
}

// ---------------- scan pass B ----------------
__global__ __launch_bounds__(256) void scan_combine_kernel(
    float* __restrict__ hstate, const float* __restrict__ lcd) {
  int i = blockIdx.x * 256 + threadIdx.x;
  int h = i >> 11;
  float H = 0.f;
  for (int c = 0; c < NCH; ++c) {
    float hl = hstate[(size_t)c * 65536 + i];
    hstate[(size_t)c * 65536 + i] = H;
    float P = expf(lcd[((size_t)c * 32 + h) * CHUNK + CHUNK - 1]);
    H = H * P + hl;
  }
}

// ---------------- scan pass C ----------------
__global__ __launch_bounds__(256) void scan_y_kernel(
    const float* __restrict__ xBC, const float* __restrict__ G,
    const float* __restrict__ dt, const float* __restrict__ lcd,
    const float* __restrict__ hstate, float* __restrict__ y) {
  int c = blockIdx.x >> 5, h = blockIdx.x & 31;
  int tid = threadIdx.x;
  __shared__ float Ms[64][65];
  __shared__ float Cs[64][65];
  __shared__ float xss[64][36];
  __shared__ float Hss[64][36];
  __shared__ float lcds[64], dts[64];
  int t0 = c * CHUNK;
  int t = tid >> 2, q = tid & 3;
  const float* row = xBC + (size_t)(t0 + t) * CONVCH;
#pragma unroll
  for (int j = 0; j < 16; j += 4) {
    float4 cv = *(const float4*)(row + DINNER + 64 + q * 16 + j);
    Cs[t][q * 16 + j + 0] = cv.x; Cs[t][q * 16 + j + 1] = cv.y;
    Cs[t][q * 16 + j + 2] = cv.z; Cs[t][q * 16 + j + 3] = cv.w;
  }
  if (q < 2) {
#pragma unroll
    for (int j = 0; j < 16; j += 4)
      *(float4*)&xss[t][q * 16 + j] = *(const float4*)(row + h * 32 + q * 16 + j);
  }
  {
    const float* gp = G + ((size_t)c * 64 + t) * 64 + q * 16;
#pragma unroll
    for (int j = 0; j < 16; j += 4) {
      float4 g = *(const float4*)(gp + j);
      Ms[t][q * 16 + j + 0] = g.x; Ms[t][q * 16 + j + 1] = g.y;
      Ms[t][q * 16 + j + 2] = g.z; Ms[t][q * 16 + j + 3] = g.w;
    }
  }
  {
    const float* hp = hstate + ((size_t)c * 32 + h) * 2048 + tid * 8;
    int n = tid >> 2, p0 = (tid & 3) * 8;
    *(float4*)&Hss[n][p0]     = *(const float4*)hp;
    *(float4*)&Hss[n][p0 + 4] = *(const float4*)(hp + 4);
  }
  if (tid < 64) {
    lcds[tid] = lcd[((size_t)c * 32 + h) * CHUNK + tid];
    dts[tid]  = dt[(t0 + tid) * MNH + h];
  }
  __syncthreads();
  {
    int s0 = q * 16;
#pragma unroll
    for (int j = 0; j < 16; ++j) {
      int s = s0 + j;
      float m = (s <= t) ? expf(lcds[t] - lcds[s]) * dts[s] * Ms[t][s] : 0.f;
      Ms[t][s] = m;
    }
  }
  __syncthreads();
  int pg = q * 8;
  f32x4 y0 = {}, y1 = {}, a0 = {}, a1 = {};
  for (int s = 0; s < 64; ++s) {
    f32x4 m = splat4(Ms[t][s]);
    y0 += m * *(const f32x4*)&xss[s][pg];
    y1 += m * *(const f32x4*)&xss[s][pg + 4];
  }
  for (int n = 0; n < 64; ++n) {
    f32x4 cn = splat4(Cs[t][n]);
    a0 += cn * *(const f32x4*)&Hss[n][pg];
    a1 += cn * *(const f32x4*)&Hss[n][pg + 4];
  }
  f32x4 cd = splat4(expf(lcds[t]));
  y0 += cd * a0; y1 += cd * a1;
  float* yp = y + (size_t)(t0 + t) * DINNER + h * 32 + pg;
  *(f32x4*)yp = y0; *(f32x4*)(yp + 4) = y1;
}

// ---------------- gate + RMSNorm ----------------
__global__ __launch_bounds__(256) void gatenorm_kernel(
    const float* __restrict__ y_ssm, const float* __restrict__ xBC,
    const float* __restrict__ zxbcdt, const float* __restrict__ Dv,
    const float* __restrict__ norm_w, float* __restrict__ out) {
  int l = blockIdx.x, tid = threadIdx.x;
  float vals[4];
  float ss = 0.f;
#pragma unroll
  for (int i = 0; i < 4; ++i) {
    int d = tid + i * 256;
    int h = d >> 5;
    float v = y_ssm[(size_t)l * DINNER + d] + Dv[h] * xBC[(size_t)l * CONVCH + d];
    float z = zxbcdt[(size_t)l * INDIMP + d];
    v *= z / (1.f + expf(-z));
    vals[i] = v;
    ss += v * v;
  }
#pragma unroll
  for (int off = 32; off > 0; off >>= 1) ss += __shfl_xor(ss, off);
  __shared__ float sred[4];
  if ((tid & 63) == 0) sred[tid >> 6] = ss;
  __syncthreads();
  float tot = sred[0] + sred[1] + sred[2] + sred[3];
  float scale = rsqrtf(tot * (1.f / 1024.f) + 1e-5f);
#pragma unroll
  for (int i = 0; i < 4; ++i) {
    int d = tid + i * 256;
    out[(size_t)l * DINNER + d] = vals[i] * scale * norm_w[d];
  }
}

// ---------------- per-row top-64 radix select (LDS-staged keys) ----------------
// Keys converted & staged in LDS once; all 6 passes scan LDS instead of
// re-reading the global row (removes ~5x repeated global sweeps).
__global__ __launch_bounds__(256) void topk_kernel(
    const float* __restrict__ scores, int* __restrict__ out_idx) {
  int l = blockIdx.x, tid = threadIdx.x;
  if (l < 64) {
    if (tid < 64) out_idx[l * 64 + tid] = tid;
    return;
  }
  int n = l + 1;
  const float* row = scores + (size_t)l * L;
  __shared__ unsigned keys[2048];
  __shared__ int hist[256];
  __shared__ unsigned sel_prefix;
  __shared__ int sel_remaining;
  __shared__ int cnt_g, cnt_e;
  __shared__ int eq_list[128];
  if (tid == 0) { cnt_g = 0; cnt_e = 0; }
  for (int j = tid; j < n; j += 256) {
    unsigned u = __float_as_uint(row[j]);
    keys[j] = (u & 0x80000000u) ? ~u : (u | 0x80000000u);
  }
  unsigned prefix = 0;
  int remaining = 64;
  for (int pass = 0; pass < 4; ++pass) {
    int shift = 24 - 8 * pass;
    unsigned himask = (pass == 0) ? 0u : (0xFFFFFFFFu << (shift + 8));
    hist[tid] = 0;
    __syncthreads();   // covers key staging on pass 0, hist reset on all
    for (int j = tid; j < n; j += 256) {
      unsigned key = keys[j];
      if (((key ^ prefix) & himask) == 0)
        atomicAdd(&hist[(key >> shift) & 255], 1);
    }
    __syncthreads();
    if (tid == 0) {
      int cum = 0, b = 255;
      for (; b >= 0; --b) {
        cum += hist[b];
        if (cum >= remaining) break;
      }
      sel_prefix = prefix | ((unsigned)b << shift);
      sel_remaining = remaining - (cum - hist[b]);
    }
    __syncthreads();
    prefix = sel_prefix;
    remaining = sel_remaining;
    __syncthreads();
  }
  unsigned T = prefix;
  for (int j = tid; j < n; j += 256) {
    unsigned key = keys[j];
    if (key > T) {
      int p = atomicAdd(&cnt_g, 1);
      out_idx[l * 64 + p] = j;
    } else if (key == T) {
      int p = atomicAdd(&cnt_e, 1);
      if (p < 128) eq_list[p] = j;
    }
  }
  __syncthreads();
  if (tid == 0) {
    int G = cnt_g;
    int E = remaining;
    int m = cnt_e < 128 ? cnt_e : 128;
    for (int e = 0; e < E; ++e) {
      int best = 0, bj = 0x7fffffff;
      for (int i = 0; i < m; ++i)
        if (eq_list[i] < bj) { bj = eq_list[i]; best = i; }
      out_idx[l * 64 + G + e] = bj;
      eq_list[best] = 0x7fffffff;
    }
  }
}

// ---------------- RoPE + pack q_final/k_final (fused-buffer strides) ----------------
__global__ __launch_bounds__(128) void rope_pack_kernel(
    const float* __restrict__ qbuf, const float* __restrict__ kv,
    const float* __restrict__ c3,
    float* __restrict__ q_final, float* __restrict__ k_final) {
  int l = blockIdx.x, tid = threadIdx.x;
  __shared__ float s_s[16], s_c[16];
  if (tid < 16) {
    float inv = powf(10000.f, -(float)tid / 16.f);
    float ang = (float)l * inv;
    s_s[tid] = sinf(ang);
    s_c[tid] = cosf(ang);
  }
  __syncthreads();
  const float* qrow = qbuf + (size_t)l * 1536;
  const float* krow = c3 + (size_t)l * 384 + 256;
  for (int e = tid; e < NH * 96; e += 128) {
    int hh = e / 96, d = e - hh * 96;
    float qv, kvv;
    if (d < 64) {
      qv  = qrow[hh * 64 + d];
      kvv = kv[(size_t)l * 2048 + hh * 64 + d];
    } else {
      int r = d - 64;
      if (r < 16) {
        float q1 = qrow[1024 + hh * 32 + r];
        float q2 = qrow[1024 + hh * 32 + 16 + r];
        qv = q1 * s_c[r] - q2 * s_s[r];
        float k1 = krow[r];
        float k2 = krow[16 + r];
        kvv = k1 * s_c[r] - k2 * s_s[r];
      } else {
        int rr = r - 16;
        float q1 = qrow[1024 + hh * 32 + rr];
        float q2 = qrow[1024 + hh * 32 + 16 + rr];
        qv = q1 * s_s[rr] + q2 * s_c[rr];
        float k1 = krow[rr];
        float k2 = krow[16 + rr];
        kvv = k1 * s_s[rr] + k2 * s_c[rr];
      }
    }
    q_final[(size_t)l * 1536 + e] = qv;
    k_final[(size_t)l * 1536 + e] = kvv;
  }
}

// ---------------- sparse attention (coalesced, one block per row) ----------------
__global__ __launch_bounds__(256) void attn_kernel(
    const float* __restrict__ q_final, const float* __restrict__ k_final,
    const float* __restrict__ kv, const int* __restrict__ idx,
    unsigned short* __restrict__ attn_aug) {
  int l = blockIdx.x;
  int tid = threadIdx.x;
  int h = tid >> 4;
  int s = tid & 15;
  __shared__ __align__(16) float lg[16][64];
  __shared__ int iks[64];

  if (tid < 64) iks[tid] = idx[l * 64 + tid];

  const float* qrow = q_final + (size_t)l * 1536 + h * 96 + s * 2;
  float q0 = qrow[0],  q1 = qrow[1];
  float q2 = qrow[32], q3 = qrow[33];
  float q4 = qrow[64], q5 = qrow[65];
  __syncthreads();

#pragma unroll 4
  for (int k = 0; k < 64; ++k) {
    const float* kr = k_final + (size_t)iks[k] * 1536 + h * 96 + s * 2;
    float2 a = *(const float2*)kr;
    float2 b = *(const float2*)(kr + 32);
    float2 c = *(const float2*)(kr + 64);
    float d = q0 * a.x + q1 * a.y + q2 * b.x + q3 * b.y + q4 * c.x + q5 * c.y;
    d += __shfl_xor(d, 1);
    d += __shfl_xor(d, 2);
    d += __shfl_xor(d, 4);
    d += __shfl_xor(d, 8);
    if (s == 0) lg[h][k] = d * 0.10206207261596575f;
  }
  __syncthreads();

  f32x4 lv = *(const f32x4*)&lg[h][s * 4];
  float m = fmaxf(fmaxf(lv[0], lv[1]), fmaxf(lv[2], lv[3]));
#pragma unroll
  for (int off = 1; off < 16; off <<= 1) m = fmaxf(m, __shfl_xor(m, off));
  f32x4 ev;
  ev[0] = expf(lv[0] - m); ev[1] = expf(lv[1] - m);
  ev[2] = expf(lv[2] - m); ev[3] = expf(lv[3] - m);
  float ssum = ev[0] + ev[1] + ev[2] + ev[3];
#pragma unroll
  for (int off = 1; off < 16; off <<= 1) ssum += __shfl_xor(ssum, off);
  float inv = 1.f / ssum;
  lg[h][s * 4 + 0] = ev[0] * inv;
  lg[h][s * 4 + 1] = ev[1] * inv;
  lg[h][s * 4 + 2] = ev[2] * inv;
  lg[h][s * 4 + 3] = ev[3] * inv;
  __syncthreads();

  f32x4 acc = {};
#pragma unroll 4
  for (int k = 0; k < 64; ++k) {
    const float* vr = kv + (size_t)iks[k] * 2048 + 1024 + tid * 4;
    f32x4 v = *(const f32x4*)vr;
    acc += splat4(lg[h][k]) * v;
  }

#pragma unroll
  for (int i = 0; i < 4; ++i) {
    float a = acc[i];
    unsigned short hi = f2bf(a);
    unsigned short lo = f2bf(a - bf2f(hi));
    size_t o = ((size_t)l * 1024 + tid * 4 + i) * 3;
    attn_aug[o] = hi; attn_aug[o + 1] = lo; attn_aug[o + 2] = hi;
  }
}

// ---------------- host ----------------
extern "C" void kernel_launch(void* const* d_in, const int* in_sizes, int n_in,
                              void* d_out, int out_size, void* d_ws, size_t ws_size,
                              hipStream_t stream) {
  const float* x          = (const float*)d_in[0];
  const float* idx_in_w   = (const float*)d_in[1];
  const float* idx_conv_w = (const float*)d_in[2];
  const float* idx_conv_b = (const float*)d_in[3];
  const float* idx_dt_b   = (const float*)d_in[4];
  const float* idx_A_log  = (const float*)d_in[5];
  const float* idx_D      = (const float*)d_in[6];
  const float* idx_norm_w = (const float*)d_in[7];
  const float* idx_out_w  = (const float*)d_in[8];
  const float* idx_q_w    = (const float*)d_in[9];
  const float* idx_k_w    = (const float*)d_in[10];
  const float* q_down_w   = (const float*)d_in[11];
  const float* q_up_w     = (const float*)d_in[12];
  const float* q_rope_w   = (const float*)d_in[13];
  const float* kv_down_w  = (const float*)d_in[14];
  const float* kv_up_w    = (const float*)d_in[15];
  const float* k_rope_w   = (const float*)d_in[16];
  const float* out_w      = (const float*)d_in[17];
  float* out = (float*)d_out;

  float* p = (float*)d_ws;
  float* segA = p; p += 4718592;  // zxbcdt[2048x2304] | scores | qbuf
  float* segB = p; p += 2359296;  // xBC | {q_idx, k_idx, c3}
  float* dtb = p; p += 65536;
  float* logdA = p; p += 65536;   // (dead after dt/lcd fusion; slot retained)
  float* lcdb = p; p += 65536;
  int*   idxb = (int*)p; p += 131072;
  float* segD = p; p += 4194304;  // y_ssm+hstate | kvb
  float* segBig1 = p; p += 6291456;  // x_trip | w_outp_aug (after in_proj)
  float* segBig2 = p; p += 7077888;  // w_in_trip | {y_norm|x_aug|q_final}@0, attn_aug@3145728
  float* segH = p; p += 3145728;     // {out_w_T,qwpad,Wq} | k_final
  unsigned short* w_3down_aug = (unsigned short*)p; p += 589824;
  unsigned short* w_qups_aug  = (unsigned short*)p; p += 294912;
  unsigned short* w_kvup_aug  = (unsigned short*)p; p += 393216;
  unsigned short* c_q_aug     = (unsigned short*)p; p += 393216;
  unsigned short* c_kv_aug    = (unsigned short*)p; p += 393216;
  float* Gbuf = p; p += 131072;
  (void)logdA;

  float* zxbcdt = segA;
  float* scores = segA;
  float* qbuf   = segA;
  float* xBC    = segB;
  float* q_idx  = segB;
  float* k_idx  = segB + 131072;
  float* c3     = segB + 262144;
  float* y_ssm  = segD;
  float* hstate = segD + 2097152;
  float* kvb    = segD;
  unsigned short* x_trip     = (unsigned short*)segBig1;  // dead after in_proj
  unsigned short* w_outp_aug = (unsigned short*)segBig1;  // written after in_proj
  unsigned short* w_in_trip  = (unsigned short*)segBig2;  // dead after in_proj
  float* y_norm  = segBig2;                               // gatenorm..q_idx gemm
  unsigned short* x_aug = (unsigned short*)segBig2;       // after topk..down-proj
  float* q_final = segBig2;                               // rope_pack..attn
  unsigned short* attn_aug = (unsigned short*)(segBig2 + 3145728);
  float* out_w_T = segH;
  float* qwpad   = segH + 1048576;
  float* Wq      = segH + 1179648;
  float* k_final = segH;                                  // after q_idx gemm

  dim3 blk(256);
  auto cdiv = [](int a, int b) { return (a + b - 1) / b; };
  auto gemmf3 = [&](const float* A, const float* W, float* C, int M, int N, int K, int S) {
    dim3 grid(cdiv(N, 128), M / 128, S);
    hipLaunchKernelGGL(gemm_f32_v3, grid, blk, 0, stream, A, W, C, M, N, K);
  };
  auto gemmb = [&](const unsigned short* A, const unsigned short* W, float* C,
                   int M, int N, int K, int lda, int ldb, int ldc, int S) {
    dim3 grid(N / 128, M / 128, S);
    hipLaunchKernelGGL(gemm_bf16_kernel, grid, blk, 0, stream, A, W, C, M, N, K, lda, ldb, ldc);
  };
  auto caugA = [&](const float* s, unsigned short* d, int total, int K, int sld) {
    hipLaunchKernelGGL(conv_augA_kernel, dim3(cdiv(total, 256)), blk, 0, stream, s, d, total, K, sld);
  };
  auto caugW = [&](const float* s, unsigned short* d, int rows, int total, int K, int sld) {
    hipLaunchKernelGGL(conv_augW_kernel, dim3(cdiv(total, 256)), blk, 0, stream, s, d, rows, total, K, sld);
  };

  // ---- weight precomputes ----
  hipLaunchKernelGGL(transpose1024_kernel, dim3(1024), blk, 0, stream, idx_out_w, out_w_T);
  hipMemsetAsync(qwpad, 0, 131072 * 4, stream);
  hipMemcpyAsync(qwpad, idx_q_w, (size_t)64 * 1024 * 4, hipMemcpyDeviceToDevice, stream);
  hipMemsetAsync(Wq, 0, 131072 * 4, stream);
  gemmf3(qwpad, out_w_T, Wq, 128, 1024, 1024, 8);
  hipLaunchKernelGGL(conv_tripA_kernel, dim3(cdiv(2048 * 1024, 256)), blk, 0, stream,
                     x, x_trip, 2048 * 1024, 1024);
  hipLaunchKernelGGL(conv_tripW_kernel, dim3(cdiv(2304 * 1024, 256)), blk, 0, stream,
                     idx_in_w, w_in_trip, 2208, 2304 * 1024, 1024);
  caugW(q_down_w,  w_3down_aug,                    128, 128 * 1024, 1024, 1024);
  caugW(kv_down_w, w_3down_aug + 128 * 1024 * 3,   128, 128 * 1024, 1024, 1024);
  caugW(k_rope_w,  w_3down_aug + 256 * 1024 * 3,    32, 128 * 1024, 1024, 1024);
  caugW(q_up_w,    w_qups_aug,                    1024, 1024 * 128, 128, 128);
  caugW(q_rope_w,  w_qups_aug + 1024 * 128 * 3,    512, 512 * 128, 128, 128);
  caugW(kv_up_w,   w_kvup_aug, 2048, 2048 * 128, 128, 128);

  // ---- mamba branch: in_proj via triple-split MFMA (fp32-accurate) ----
  hipMemsetAsync(zxbcdt, 0, (size_t)L * INDIMP * 4, stream);
  gemmb(x_trip, w_in_trip, zxbcdt, 2048, 2304, 6144, 6144, 6144, INDIMP, 4);
  // x_trip dead -> write out-proj weights into segBig1
  caugW(out_w, w_outp_aug, 1024, 1024 * 1024, 1024, 1024);
  hipLaunchKernelGGL(conv_silu_kernel, dim3(cdiv(L * (CONVCH / 4), 256)), blk, 0, stream,
                     zxbcdt, idx_conv_w, idx_conv_b, xBC);
  hipLaunchKernelGGL(dtlcd_kernel, dim3(4), blk, 0, stream,
                     zxbcdt, idx_dt_b, idx_A_log, dtb, lcdb);
  hipLaunchKernelGGL(chunk_G_kernel, dim3(NCH), blk, 0, stream, xBC, Gbuf);
  hipLaunchKernelGGL(scan_local_kernel, dim3(NCH * MNH), blk, 0, stream,
                     xBC, dtb, lcdb, hstate);
  hipLaunchKernelGGL(scan_combine_kernel, dim3(256), blk, 0, stream, hstate, lcdb);
  hipLaunchKernelGGL(scan_y_kernel, dim3(NCH * MNH), blk, 0, stream,
                     xBC, Gbuf, dtb, lcdb, hstate, y_ssm);
  // y_norm -> segBig2 (w_in_trip dead)
  hipLaunchKernelGGL(gatenorm_kernel, dim3(L), blk, 0, stream,
                     y_ssm, xBC, zxbcdt, idx_D, idx_norm_w, y_norm);

  // ---- index scores + topk (out-proj folded into Wq) ----
  hipMemsetAsync(q_idx, 0, 131072 * 4, stream);
  hipMemsetAsync(k_idx, 0, 131072 * 4, stream);
  gemmf3(y_norm, Wq, q_idx, 2048, 64, 1024, 16);
  gemmf3(x, idx_k_w, k_idx, 2048, 64, 1024, 16);
  gemmf3(q_idx, k_idx, scores, 2048, 2048, 64, 1);
  hipLaunchKernelGGL(topk_kernel, dim3(L), blk, 0, stream, scores, idxb);

  // ---- attention value path (aug split-bf16 MFMA) ----
  caugA(x, x_aug, 2048 * 1024, 1024, 1024);  // segBig2@0 (y_norm dead)
  hipMemsetAsync(c3, 0, 786432 * 4, stream);
  gemmb(x_aug, w_3down_aug, c3, 2048, 384, 3072, 3072, 3072, 384, 8);
  caugA(c3, c_q_aug, 2048 * 128, 128, 384);
  caugA(c3 + 128, c_kv_aug, 2048 * 128, 128, 384);
  gemmb(c_q_aug, w_qups_aug, qbuf, 2048, 1536, 384, 384, 384, 1536, 1);
  gemmb(c_kv_aug, w_kvup_aug, kvb, 2048, 2048, 384, 384, 384, 2048, 1);
  hipLaunchKernelGGL(rope_pack_kernel, dim3(L), dim3(128), 0, stream,
                     qbuf, kvb, c3, q_final, k_final);

  // ---- sparse attention + output projection ----
  hipLaunchKernelGGL(attn_kernel, dim3(L), blk, 0, stream,
                     q_final, k_final, kvb, idxb, attn_aug);
  hipMemsetAsync(out, 0, (size_t)out_size * 4, stream);
  gemmb(attn_aug, w_outp_aug, out, 2048, 1024, 3072, 3072, 3072, 1024, 2);
}

// Round 6
// 709.752 us; speedup vs baseline: 1.0351x; 1.0351x over previous
//
#include <hip/hip_runtime.h>
#include <math.h>

// ---------------- constants ----------------
constexpr int L      = 2048;
constexpr int NH     = 16;
constexpr int DINNER = 1024;
constexpr int MNH    = 32;
constexpr int CONVCH = 1152;
constexpr int INDIMP = 2304;   // padded stride for zxbcdt (2208 -> 2304, N%128)
constexpr int CHUNK  = 64;
constexpr int NCH    = 32;

using bf16x8 = __attribute__((ext_vector_type(8))) short;
using f32x4  = __attribute__((ext_vector_type(4))) float;

__device__ __forceinline__ f32x4 splat4(float x) { return (f32x4){x, x, x, x}; }

__device__ __forceinline__ unsigned short f2bf(float f) {
  unsigned u = __float_as_uint(f);
  return (unsigned short)((u + 0x7fffu + ((u >> 16) & 1u)) >> 16);
}
__device__ __forceinline__ float bf2f(unsigned short h) {
  return __uint_as_float((unsigned)h << 16);
}

// ---------------- fp32 GEMM v3 (small index-critical shapes) ----------------
__global__ __launch_bounds__(256) void gemm_f32_v3(
    const float* __restrict__ A, const float* __restrict__ W,
    float* __restrict__ C, int M, int N, int K) {
  __shared__ float As[16][132];
  __shared__ float Ws[16][132];
  int tid = threadIdx.x;
  int bm = blockIdx.y * 128, bn = blockIdx.x * 128;
  int kper = K / gridDim.z;
  int kb = blockIdx.z * kper, ke = kb + kper;
  int lr = tid >> 1;
  int lh = (tid & 1) * 8;
  int tx = tid & 15, ty = tid >> 4;
  bool wok = (bn + lr < N);
  const float* arow = A + (size_t)(bm + lr) * K + lh;
  const float* wrow = W + (size_t)(bn + lr) * K + lh;
  float4 a0, a1, w0, w1;
  auto gload = [&](int k0) {
    a0 = *(const float4*)(arow + k0);
    a1 = *(const float4*)(arow + k0 + 4);
    w0 = make_float4(0.f, 0.f, 0.f, 0.f); w1 = w0;
    if (wok) {
      w0 = *(const float4*)(wrow + k0);
      w1 = *(const float4*)(wrow + k0 + 4);
    }
  };
  f32x4 acc0[8] = {}, acc1[8] = {};
  gload(kb);
  for (int k0 = kb; k0 < ke; k0 += 16) {
    __syncthreads();
    As[lh+0][lr]=a0.x; As[lh+1][lr]=a0.y; As[lh+2][lr]=a0.z; As[lh+3][lr]=a0.w;
    As[lh+4][lr]=a1.x; As[lh+5][lr]=a1.y; As[lh+6][lr]=a1.z; As[lh+7][lr]=a1.w;
    Ws[lh+0][lr]=w0.x; Ws[lh+1][lr]=w0.y; Ws[lh+2][lr]=w0.z; Ws[lh+3][lr]=w0.w;
    Ws[lh+4][lr]=w1.x; Ws[lh+5][lr]=w1.y; Ws[lh+6][lr]=w1.z; Ws[lh+7][lr]=w1.w;
    __syncthreads();
    if (k0 + 16 < ke) gload(k0 + 16);
#pragma unroll
    for (int kk = 0; kk < 16; ++kk) {
      f32x4 b0 = *(const f32x4*)&Ws[kk][tx * 4];
      f32x4 b1 = *(const f32x4*)&Ws[kk][64 + tx * 4];
      f32x4 al = *(const f32x4*)&As[kk][ty * 8];
      f32x4 ah = *(const f32x4*)&As[kk][ty * 8 + 4];
#pragma unroll
      for (int i = 0; i < 4; ++i) {
        acc0[i]     += splat4(al[i]) * b0;
        acc1[i]     += splat4(al[i]) * b1;
        acc0[i + 4] += splat4(ah[i]) * b0;
        acc1[i + 4] += splat4(ah[i]) * b1;
      }
    }
  }
  bool single = (gridDim.z == 1);
#pragma unroll
  for (int i = 0; i < 8; ++i) {
    int row = bm + ty * 8 + i;
    float* crow = C + (size_t)row * N;
    int c0 = bn + tx * 4, c1 = bn + 64 + tx * 4;
    if (c0 + 3 < N) {
      if (single) *(f32x4*)(crow + c0) = acc0[i];
      else {
        atomicAdd(crow + c0 + 0, acc0[i][0]); atomicAdd(crow + c0 + 1, acc0[i][1]);
        atomicAdd(crow + c0 + 2, acc0[i][2]); atomicAdd(crow + c0 + 3, acc0[i][3]);
      }
    }
    if (c1 + 3 < N) {
      if (single) *(f32x4*)(crow + c1) = acc1[i];
      else {
        atomicAdd(crow + c1 + 0, acc1[i][0]); atomicAdd(crow + c1 + 1, acc1[i][1]);
        atomicAdd(crow + c1 + 2, acc1[i][2]); atomicAdd(crow + c1 + 3, acc1[i][3]);
      }
    }
  }
}

// ---------------- 1024x1024 transpose ----------------
__global__ __launch_bounds__(256) void transpose1024_kernel(
    const float* __restrict__ src, float* __restrict__ dst) {
  __shared__ float t[32][33];
  int bx = blockIdx.x & 31, by = blockIdx.x >> 5;
  int tx = threadIdx.x & 31, ty8 = threadIdx.x >> 5;
  for (int r = ty8; r < 32; r += 8)
    t[r][tx] = src[(size_t)(by * 32 + r) * 1024 + bx * 32 + tx];
  __syncthreads();
  for (int r = ty8; r < 32; r += 8)
    dst[(size_t)(bx * 32 + r) * 1024 + by * 32 + tx] = t[tx][r];
}

// ---------------- bf16 MFMA GEMM (double-buffered LDS: stage(t+1) || compute(t)) ----------------
// T1: XCD-aware (x,y) tile swizzle (identity fallback when nwg%8!=0).
// T3-min: 2-deep pipeline (structure-bound at ~445 TF for the 2048-class shapes).
__global__ __launch_bounds__(256) void gemm_bf16_kernel(
    const unsigned short* __restrict__ A, const unsigned short* __restrict__ W,
    float* __restrict__ C, int M, int N, int K, int lda, int ldb, int ldc) {
  __shared__ unsigned short As[2][128 * 64];
  __shared__ unsigned short Ws[2][128 * 64];
  int tid = threadIdx.x;
  int bx = blockIdx.x, by = blockIdx.y;
  int nxy = gridDim.x * gridDim.y;
  if ((nxy & 7) == 0) {
    int lin = by * gridDim.x + bx;
    int cpx = nxy >> 3;
    int swz = (lin & 7) * cpx + (lin >> 3);
    bx = swz % gridDim.x;
    by = swz / gridDim.x;
  }
  int bm = by * 128, bn = bx * 128;
  int kper = K / gridDim.z;
  int k_begin = blockIdx.z * kper;
  int k_end = k_begin + kper;
  int wv = tid >> 6, lane = tid & 63;
  int wrow = (wv >> 1) * 64, wcol = (wv & 1) * 64;
  int lrow = lane & 15, quad = lane >> 4;

  f32x4 acc[4][4] = {};

  auto stage = [&](int b, int k0) {
#pragma unroll
    for (int it = 0; it < 4; ++it) {
      int s = it * 256 + tid;
      int r = s >> 3;
      int q = (s & 7) ^ (r & 7);
      const unsigned short* ga = A + (size_t)(bm + r) * lda + k0 + q * 8;
      const unsigned short* gw = W + (size_t)(bn + r) * ldb + k0 + q * 8;
      __builtin_amdgcn_global_load_lds((const __attribute__((address_space(1))) void*)ga,
                                       (__attribute__((address_space(3))) void*)&As[b][s * 8], 16, 0, 0);
      __builtin_amdgcn_global_load_lds((const __attribute__((address_space(1))) void*)gw,
                                       (__attribute__((address_space(3))) void*)&Ws[b][s * 8], 16, 0, 0);
    }
  };

  stage(0, k_begin);
  int cur = 0;
  for (int k0 = k_begin; k0 < k_end; k0 += 64) {
    __syncthreads();
    if (k0 + 64 < k_end) stage(cur ^ 1, k0 + 64);
#pragma unroll
    for (int ks = 0; ks < 2; ++ks) {
      bf16x8 af[4], wf[4];
#pragma unroll
      for (int i = 0; i < 4; ++i) {
        int ra = wrow + i * 16 + lrow;
        int qa = (ks * 4 + quad) ^ (ra & 7);
        af[i] = *(const bf16x8*)&As[cur][(ra * 8 + qa) * 8];
        int rw = wcol + i * 16 + lrow;
        int qw = (ks * 4 + quad) ^ (rw & 7);
        wf[i] = *(const bf16x8*)&Ws[cur][(rw * 8 + qw) * 8];
      }
#pragma unroll
      for (int i = 0; i < 4; ++i)
#pragma unroll
        for (int j = 0; j < 4; ++j)
          acc[i][j] = __builtin_amdgcn_mfma_f32_16x16x32_bf16(af[i], wf[j], acc[i][j], 0, 0, 0);
    }
    cur ^= 1;
  }
  bool single = (gridDim.z == 1);
#pragma unroll
  for (int i = 0; i < 4; ++i)
#pragma unroll
    for (int j = 0; j < 4; ++j)
#pragma unroll
      for (int r = 0; r < 4; ++r) {
        int row = bm + wrow + i * 16 + quad * 4 + r;
        int col = bn + wcol + j * 16 + lrow;
        float v = acc[i][j][r];
        if (single) C[(size_t)row * ldc + col] = v;
        else atomicAdd(&C[(size_t)row * ldc + col], v);
      }
}

// ---------------- conversions ----------------
// 3-slot aug (value path): A=[h,l,h], W=[h,h,l]
__global__ __launch_bounds__(256) void conv_augA_kernel(
    const float* __restrict__ src, unsigned short* __restrict__ dst,
    int total, int K, int sld) {
  int i = blockIdx.x * 256 + threadIdx.x;
  if (i >= total) return;
  int m = i / K, k = i - m * K;
  float f = src[(size_t)m * sld + k];
  unsigned short hi = f2bf(f);
  unsigned short lo = f2bf(f - bf2f(hi));
  size_t o = ((size_t)m * K + k) * 3;
  dst[o] = hi; dst[o + 1] = lo; dst[o + 2] = hi;
}
__global__ __launch_bounds__(256) void conv_augW_kernel(
    const float* __restrict__ src, unsigned short* __restrict__ dst,
    int rows, int total, int K, int sld) {
  int i = blockIdx.x * 256 + threadIdx.x;
  if (i >= total) return;
  int n = i / K, k = i - n * K;
  unsigned short hi = 0, lo = 0;
  if (n < rows) {
    float f = src[(size_t)n * sld + k];
    hi = f2bf(f);
    lo = f2bf(f - bf2f(hi));
  }
  size_t o = ((size_t)n * K + k) * 3;
  dst[o] = hi; dst[o + 1] = hi; dst[o + 2] = lo;
}
// 6-slot triple split (index path): A=[h,m,l,h,m,h], W=[h,h,h,m,m,l]
__global__ __launch_bounds__(256) void conv_tripA_kernel(
    const float* __restrict__ src, unsigned short* __restrict__ dst,
    int total, int K) {
  int i = blockIdx.x * 256 + threadIdx.x;
  if (i >= total) return;
  float f = src[i];
  unsigned short h = f2bf(f);
  float r1 = f - bf2f(h);
  unsigned short m = f2bf(r1);
  unsigned short l = f2bf(r1 - bf2f(m));
  size_t o = (size_t)i * 6;
  dst[o] = h; dst[o + 1] = m; dst[o + 2] = l;
  dst[o + 3] = h; dst[o + 4] = m; dst[o + 5] = h;
}
__global__ __launch_bounds__(256) void conv_tripW_kernel(
    const float* __restrict__ src, unsigned short* __restrict__ dst,
    int rows, int total, int K) {
  int i = blockIdx.x * 256 + threadIdx.x;
  if (i >= total) return;
  int n = i / K, k = i - n * K;
  unsigned short h = 0, m = 0, l = 0;
  if (n < rows) {
    float f = src[(size_t)n * K + k];
    h = f2bf(f);
    float r1 = f - bf2f(h);
    m = f2bf(r1);
    l = f2bf(r1 - bf2f(m));
  }
  size_t o = (size_t)i * 6;
  dst[o] = h; dst[o + 1] = h; dst[o + 2] = h;
  dst[o + 3] = m; dst[o + 4] = m; dst[o + 5] = l;
}

// ---------------- conv1d(4-tap, causal) + SiLU (scalar, R4-verified) ----------------
__global__ __launch_bounds__(256) void conv_silu_kernel(
    const float* __restrict__ zxbcdt, const float* __restrict__ conv_w,
    const float* __restrict__ conv_b, float* __restrict__ xBC) {
  int idx = blockIdx.x * 256 + threadIdx.x;
  if (idx >= L * CONVCH) return;
  int l = idx / CONVCH, c = idx - l * CONVCH;
  float acc = conv_b[c];
#pragma unroll
  for (int k = 0; k < 4; ++k) {
    int ls = l - 3 + k;
    if (ls >= 0) acc += zxbcdt[(size_t)ls * INDIMP + DINNER + c] * conv_w[c * 4 + k];
  }
  xBC[idx] = acc / (1.f + expf(-acc));
}

// ---------------- dt / logdA (dt cols at 2176..2207) ----------------
__global__ __launch_bounds__(256) void dt_kernel(
    const float* __restrict__ zxbcdt, const float* __restrict__ dt_bias,
    const float* __restrict__ A_log, float* __restrict__ dt, float* __restrict__ logdA) {
  int idx = blockIdx.x * 256 + threadIdx.x;
  int l = idx >> 5, h = idx & 31;
  float xv = zxbcdt[(size_t)l * INDIMP + 2176 + h] + dt_bias[h];
  float sp = fmaxf(xv, 0.f) + log1pf(expf(-fabsf(xv)));
  dt[idx] = sp;
  logdA[idx] = sp * -expf(A_log[h]);
}

// ---------------- lcd ----------------
__global__ __launch_bounds__(256) void lcd_kernel(
    const float* __restrict__ logdA, float* __restrict__ lcd) {
  int i = blockIdx.x * 256 + threadIdx.x;
  if (i >= NCH * MNH) return;
  int c = i >> 5, h = i & 31;
  float s = 0.f;
  for (int t = 0; t < CHUNK; ++t) {
    s += logdA[(c * CHUNK + t) * MNH + h];
    lcd[(size_t)i * CHUNK + t] = s;
  }
}

// ---------------- G[c][t][s] = C_t . B_s ----------------
__global__ __launch_bounds__(256) void chunk_G_kernel(
    const float* __restrict__ xBC, float* __restrict__ G) {
  int c = blockIdx.x, tid = threadIdx.x;
  __shared__ float BsT[64][68];
  __shared__ float Cs[64][65];
  int t = tid >> 2, q = tid & 3;
  const float* row = xBC + (size_t)(c * 64 + t) * CONVCH + DINNER;
#pragma unroll
  for (int j = 0; j < 16; j += 4) {
    float4 b = *(const float4*)(row + q * 16 + j);
    BsT[q * 16 + j + 0][t] = b.x; BsT[q * 16 + j + 1][t] = b.y;
    BsT[q * 16 + j + 2][t] = b.z; BsT[q * 16 + j + 3][t] = b.w;
    float4 cv = *(const float4*)(row + 64 + q * 16 + j);
    Cs[t][q * 16 + j + 0] = cv.x; Cs[t][q * 16 + j + 1] = cv.y;
    Cs[t][q * 16 + j + 2] = cv.z; Cs[t][q * 16 + j + 3] = cv.w;
  }
  __syncthreads();
  int s0 = q * 16;
  f32x4 g0 = {}, g1 = {}, g2 = {}, g3 = {};
  for (int n = 0; n < 64; ++n) {
    f32x4 cv = splat4(Cs[t][n]);
    g0 += cv * *(const f32x4*)&BsT[n][s0];
    g1 += cv * *(const f32x4*)&BsT[n][s0 + 4];
    g2 += cv * *(const f32x4*)&BsT[n][s0 + 8];
    g3 += cv * *(const f32x4*)&BsT[n][s0 + 12];
  }
  float* gp = G + ((size_t)c * 64 + t) * 64 + s0;
  *(f32x4*)gp = g0; *(f32x4*)(gp + 4) = g1; *(f32x4*)(gp + 8) = g2; *(f32x4*)(gp + 12) = g3;
}

// ---------------- scan pass A ----------------
__global__ __launch_bounds__(256) void scan_local_kernel(
    const float* __restrict__ xBC, const float* __restrict__ dt,
    const float* __restrict__ lcd, float* __restrict__ hstate) {
  int c = blockIdx.x >> 5, h = blockIdx.x & 31;
  int tid = threadIdx.x;
  __shared__ float Bs[64][68];
  __shared__ float xss[64][36];
  __shared__ float w2s[64];
  int t0 = c * CHUNK;
  int t = tid >> 2, q = tid & 3;
  const float* row = xBC + (size_t)(t0 + t) * CONVCH;
#pragma unroll
  for (int j = 0; j < 16; j += 4)
    *(float4*)&Bs[t][q * 16 + j] = *(const float4*)(row + DINNER + q * 16 + j);
  if (q < 2) {
#pragma unroll
    for (int j = 0; j < 16; j += 4)
      *(float4*)&xss[t][q * 16 + j] = *(const float4*)(row + h * 32 + q * 16 + j);
  }
  if (tid < 64) {
    const float* lc = lcd + ((size_t)c * 32 + h) * CHUNK;
    w2s[tid] = expf(lc[63] - lc[tid]) * dt[(t0 + tid) * MNH + h];
  }
  __syncthreads();
  int n = tid >> 2, pg = (tid & 3) * 8;
  f32x4 h0 = {}, h1 = {};
  for (int s = 0; s < 64; ++s) {
    f32x4 wb = splat4(w2s[s] * Bs[s][n]);
    h0 += wb * *(const f32x4*)&xss[s][pg];
    h1 += wb * *(const f32x4*)&xss[s][pg + 4];
  }
  float* hp = hstate + ((size_t)c * 32 + h) * 2048 + n * 32 + pg;
  *(f32x4*)hp = h0; *(f32x4*)(hp + 4) = h1;
}

// ---------------- scan pass B ----------------
__global__ __launch_bounds__(256) void scan_combine_kernel(
    float* __restrict__ hstate, const float* __restrict__ lcd) {
  int i = blockIdx.x * 256 + threadIdx.x;
  int h = i >> 11;
  float H = 0.f;
  for (int c = 0; c < NCH; ++c) {
    float hl = hstate[(size_t)c * 65536 + i];
    hstate[(size_t)c * 65536 + i] = H;
    float P = expf(lcd[((size_t)c * 32 + h) * CHUNK + CHUNK - 1]);
    H = H * P + hl;
  }
}

// ---------------- scan pass C ----------------
__global__ __launch_bounds__(256) void scan_y_kernel(
    const float* __restrict__ xBC, const float* __restrict__ G,
    const float* __restrict__ dt, const float* __restrict__ lcd,
    const float* __restrict__ hstate, float* __restrict__ y) {
  int c = blockIdx.x >> 5, h = blockIdx.x & 31;
  int tid = threadIdx.x;
  __shared__ float Ms[64][65];
  __shared__ float Cs[64][65];
  __shared__ float xss[64][36];
  __shared__ float Hss[64][36];
  __shared__ float lcds[64], dts[64];
  int t0 = c * CHUNK;
  int t = tid >> 2, q = tid & 3;
  const float* row = xBC + (size_t)(t0 + t) * CONVCH;
#pragma unroll
  for (int j = 0; j < 16; j += 4) {
    float4 cv = *(const float4*)(row + DINNER + 64 + q * 16 + j);
    Cs[t][q * 16 + j + 0] = cv.x; Cs[t][q * 16 + j + 1] = cv.y;
    Cs[t][q * 16 + j + 2] = cv.z; Cs[t][q * 16 + j + 3] = cv.w;
  }
  if (q < 2) {
#pragma unroll
    for (int j = 0; j < 16; j += 4)
      *(float4*)&xss[t][q * 16 + j] = *(const float4*)(row + h * 32 + q * 16 + j);
  }
  {
    const float* gp = G + ((size_t)c * 64 + t) * 64 + q * 16;
#pragma unroll
    for (int j = 0; j < 16; j += 4) {
      float4 g = *(const float4*)(gp + j);
      Ms[t][q * 16 + j + 0] = g.x; Ms[t][q * 16 + j + 1] = g.y;
      Ms[t][q * 16 + j + 2] = g.z; Ms[t][q * 16 + j + 3] = g.w;
    }
  }
  {
    const float* hp = hstate + ((size_t)c * 32 + h) * 2048 + tid * 8;
    int n = tid >> 2, p0 = (tid & 3) * 8;
    *(float4*)&Hss[n][p0]     = *(const float4*)hp;
    *(float4*)&Hss[n][p0 + 4] = *(const float4*)(hp + 4);
  }
  if (tid < 64) {
    lcds[tid] = lcd[((size_t)c * 32 + h) * CHUNK + tid];
    dts[tid]  = dt[(t0 + tid) * MNH + h];
  }
  __syncthreads();
  {
    int s0 = q * 16;
#pragma unroll
    for (int j = 0; j < 16; ++j) {
      int s = s0 + j;
      float m = (s <= t) ? expf(lcds[t] - lcds[s]) * dts[s] * Ms[t][s] : 0.f;
      Ms[t][s] = m;
    }
  }
  __syncthreads();
  int pg = q * 8;
  f32x4 y0 = {}, y1 = {}, a0 = {}, a1 = {};
  for (int s = 0; s < 64; ++s) {
    f32x4 m = splat4(Ms[t][s]);
    y0 += m * *(const f32x4*)&xss[s][pg];
    y1 += m * *(const f32x4*)&xss[s][pg + 4];
  }
  for (int n = 0; n < 64; ++n) {
    f32x4 cn = splat4(Cs[t][n]);
    a0 += cn * *(const f32x4*)&Hss[n][pg];
    a1 += cn * *(const f32x4*)&Hss[n][pg + 4];
  }
  f32x4 cd = splat4(expf(lcds[t]));
  y0 += cd * a0; y1 += cd * a1;
  float* yp = y + (size_t)(t0 + t) * DINNER + h * 32 + pg;
  *(f32x4*)yp = y0; *(f32x4*)(yp + 4) = y1;
}

// ---------------- gate + RMSNorm ----------------
__global__ __launch_bounds__(256) void gatenorm_kernel(
    const float* __restrict__ y_ssm, const float* __restrict__ xBC,
    const float* __restrict__ zxbcdt, const float* __restrict__ Dv,
    const float* __restrict__ norm_w, float* __restrict__ out) {
  int l = blockIdx.x, tid = threadIdx.x;
  float vals[4];
  float ss = 0.f;
#pragma unroll
  for (int i = 0; i < 4; ++i) {
    int d = tid + i * 256;
    int h = d >> 5;
    float v = y_ssm[(size_t)l * DINNER + d] + Dv[h] * xBC[(size_t)l * CONVCH + d];
    float z = zxbcdt[(size_t)l * INDIMP + d];
    v *= z / (1.f + expf(-z));
    vals[i] = v;
    ss += v * v;
  }
#pragma unroll
  for (int off = 32; off > 0; off >>= 1) ss += __shfl_xor(ss, off);
  __shared__ float sred[4];
  if ((tid & 63) == 0) sred[tid >> 6] = ss;
  __syncthreads();
  float tot = sred[0] + sred[1] + sred[2] + sred[3];
  float scale = rsqrtf(tot * (1.f / 1024.f) + 1e-5f);
#pragma unroll
  for (int i = 0; i < 4; ++i) {
    int d = tid + i * 256;
    out[(size_t)l * DINNER + d] = vals[i] * scale * norm_w[d];
  }
}

// ---------------- per-row top-64 radix select (R4-verified global-scan) ----------------
__global__ __launch_bounds__(256) void topk_kernel(
    const float* __restrict__ scores, int* __restrict__ out_idx) {
  int l = blockIdx.x, tid = threadIdx.x;
  if (l < 64) {
    if (tid < 64) out_idx[l * 64 + tid] = tid;
    return;
  }
  int n = l + 1;
  const float* row = scores + (size_t)l * L;
  __shared__ int hist[256];
  __shared__ unsigned sel_prefix;
  __shared__ int sel_remaining;
  __shared__ int cnt_g, cnt_e;
  __shared__ int eq_list[128];
  if (tid == 0) { cnt_g = 0; cnt_e = 0; }
  unsigned prefix = 0;
  int remaining = 64;
  for (int pass = 0; pass < 4; ++pass) {
    int shift = 24 - 8 * pass;
    unsigned himask = (pass == 0) ? 0u : (0xFFFFFFFFu << (shift + 8));
    hist[tid] = 0;
    __syncthreads();
    for (int j = tid; j < n; j += 256) {
      unsigned u = __float_as_uint(row[j]);
      unsigned key = (u & 0x80000000u) ? ~u : (u | 0x80000000u);
      if (((key ^ prefix) & himask) == 0)
        atomicAdd(&hist[(key >> shift) & 255], 1);
    }
    __syncthreads();
    if (tid == 0) {
      int cum = 0, b = 255;
      for (; b >= 0; --b) {
        cum += hist[b];
        if (cum >= remaining) break;
      }
      sel_prefix = prefix | ((unsigned)b << shift);
      sel_remaining = remaining - (cum - hist[b]);
    }
    __syncthreads();
    prefix = sel_prefix;
    remaining = sel_remaining;
    __syncthreads();
  }
  unsigned T = prefix;
  for (int j = tid; j < n; j += 256) {
    unsigned u = __float_as_uint(row[j]);
    unsigned key = (u & 0x80000000u) ? ~u : (u | 0x80000000u);
    if (key > T) {
      int p = atomicAdd(&cnt_g, 1);
      out_idx[l * 64 + p] = j;
    } else if (key == T) {
      int p = atomicAdd(&cnt_e, 1);
      if (p < 128) eq_list[p] = j;
    }
  }
  __syncthreads();
  if (tid == 0) {
    int G = cnt_g;
    int E = remaining;
    int m = cnt_e < 128 ? cnt_e : 128;
    for (int e = 0; e < E; ++e) {
      int best = 0, bj = 0x7fffffff;
      for (int i = 0; i < m; ++i)
        if (eq_list[i] < bj) { bj = eq_list[i]; best = i; }
      out_idx[l * 64 + G + e] = bj;
      eq_list[best] = 0x7fffffff;
    }
  }
}

// ---------------- RoPE + pack q_final/k_final (fused-buffer strides) ----------------
__global__ __launch_bounds__(128) void rope_pack_kernel(
    const float* __restrict__ qbuf, const float* __restrict__ kv,
    const float* __restrict__ c3,
    float* __restrict__ q_final, float* __restrict__ k_final) {
  int l = blockIdx.x, tid = threadIdx.x;
  __shared__ float s_s[16], s_c[16];
  if (tid < 16) {
    float inv = powf(10000.f, -(float)tid / 16.f);
    float ang = (float)l * inv;
    s_s[tid] = sinf(ang);
    s_c[tid] = cosf(ang);
  }
  __syncthreads();
  const float* qrow = qbuf + (size_t)l * 1536;
  const float* krow = c3 + (size_t)l * 384 + 256;
  for (int e = tid; e < NH * 96; e += 128) {
    int hh = e / 96, d = e - hh * 96;
    float qv, kvv;
    if (d < 64) {
      qv  = qrow[hh * 64 + d];
      kvv = kv[(size_t)l * 2048 + hh * 64 + d];
    } else {
      int r = d - 64;
      if (r < 16) {
        float q1 = qrow[1024 + hh * 32 + r];
        float q2 = qrow[1024 + hh * 32 + 16 + r];
        qv = q1 * s_c[r] - q2 * s_s[r];
        float k1 = krow[r];
        float k2 = krow[16 + r];
        kvv = k1 * s_c[r] - k2 * s_s[r];
      } else {
        int rr = r - 16;
        float q1 = qrow[1024 + hh * 32 + rr];
        float q2 = qrow[1024 + hh * 32 + 16 + rr];
        qv = q1 * s_s[rr] + q2 * s_c[rr];
        float k1 = krow[rr];
        float k2 = krow[16 + rr];
        kvv = k1 * s_s[rr] + k2 * s_c[rr];
      }
    }
    q_final[(size_t)l * 1536 + e] = qv;
    k_final[(size_t)l * 1536 + e] = kvv;
  }
}

// ---------------- sparse attention (coalesced, one block per row) ----------------
__global__ __launch_bounds__(256) void attn_kernel(
    const float* __restrict__ q_final, const float* __restrict__ k_final,
    const float* __restrict__ kv, const int* __restrict__ idx,
    unsigned short* __restrict__ attn_aug) {
  int l = blockIdx.x;
  int tid = threadIdx.x;
  int h = tid >> 4;
  int s = tid & 15;
  __shared__ __align__(16) float lg[16][64];
  __shared__ int iks[64];

  if (tid < 64) iks[tid] = idx[l * 64 + tid];

  const float* qrow = q_final + (size_t)l * 1536 + h * 96 + s * 2;
  float q0 = qrow[0],  q1 = qrow[1];
  float q2 = qrow[32], q3 = qrow[33];
  float q4 = qrow[64], q5 = qrow[65];
  __syncthreads();

#pragma unroll 4
  for (int k = 0; k < 64; ++k) {
    const float* kr = k_final + (size_t)iks[k] * 1536 + h * 96 + s * 2;
    float2 a = *(const float2*)kr;
    float2 b = *(const float2*)(kr + 32);
    float2 c = *(const float2*)(kr + 64);
    float d = q0 * a.x + q1 * a.y + q2 * b.x + q3 * b.y + q4 * c.x + q5 * c.y;
    d += __shfl_xor(d, 1);
    d += __shfl_xor(d, 2);
    d += __shfl_xor(d, 4);
    d += __shfl_xor(d, 8);
    if (s == 0) lg[h][k] = d * 0.10206207261596575f;
  }
  __syncthreads();

  f32x4 lv = *(const f32x4*)&lg[h][s * 4];
  float m = fmaxf(fmaxf(lv[0], lv[1]), fmaxf(lv[2], lv[3]));
#pragma unroll
  for (int off = 1; off < 16; off <<= 1) m = fmaxf(m, __shfl_xor(m, off));
  f32x4 ev;
  ev[0] = expf(lv[0] - m); ev[1] = expf(lv[1] - m);
  ev[2] = expf(lv[2] - m); ev[3] = expf(lv[3] - m);
  float ssum = ev[0] + ev[1] + ev[2] + ev[3];
#pragma unroll
  for (int off = 1; off < 16; off <<= 1) ssum += __shfl_xor(ssum, off);
  float inv = 1.f / ssum;
  lg[h][s * 4 + 0] = ev[0] * inv;
  lg[h][s * 4 + 1] = ev[1] * inv;
  lg[h][s * 4 + 2] = ev[2] * inv;
  lg[h][s * 4 + 3] = ev[3] * inv;
  __syncthreads();

  f32x4 acc = {};
#pragma unroll 4
  for (int k = 0; k < 64; ++k) {
    const float* vr = kv + (size_t)iks[k] * 2048 + 1024 + tid * 4;
    f32x4 v = *(const f32x4*)vr;
    acc += splat4(lg[h][k]) * v;
  }

#pragma unroll
  for (int i = 0; i < 4; ++i) {
    float a = acc[i];
    unsigned short hi = f2bf(a);
    unsigned short lo = f2bf(a - bf2f(hi));
    size_t o = ((size_t)l * 1024 + tid * 4 + i) * 3;
    attn_aug[o] = hi; attn_aug[o + 1] = lo; attn_aug[o + 2] = hi;
  }
}

// ---------------- host ----------------
extern "C" void kernel_launch(void* const* d_in, const int* in_sizes, int n_in,
                              void* d_out, int out_size, void* d_ws, size_t ws_size,
                              hipStream_t stream) {
  const float* x          = (const float*)d_in[0];
  const float* idx_in_w   = (const float*)d_in[1];
  const float* idx_conv_w = (const float*)d_in[2];
  const float* idx_conv_b = (const float*)d_in[3];
  const float* idx_dt_b   = (const float*)d_in[4];
  const float* idx_A_log  = (const float*)d_in[5];
  const float* idx_D      = (const float*)d_in[6];
  const float* idx_norm_w = (const float*)d_in[7];
  const float* idx_out_w  = (const float*)d_in[8];
  const float* idx_q_w    = (const float*)d_in[9];
  const float* idx_k_w    = (const float*)d_in[10];
  const float* q_down_w   = (const float*)d_in[11];
  const float* q_up_w     = (const float*)d_in[12];
  const float* q_rope_w   = (const float*)d_in[13];
  const float* kv_down_w  = (const float*)d_in[14];
  const float* kv_up_w    = (const float*)d_in[15];
  const float* k_rope_w   = (const float*)d_in[16];
  const float* out_w      = (const float*)d_in[17];
  float* out = (float*)d_out;

  float* p = (float*)d_ws;
  float* segA = p; p += 4718592;  // zxbcdt[2048x2304] | scores | qbuf
  float* segB = p; p += 2359296;  // xBC | {q_idx, k_idx, c3}
  float* dtb = p; p += 65536;
  float* logdA = p; p += 65536;
  float* lcdb = p; p += 65536;
  int*   idxb = (int*)p; p += 131072;
  float* segD = p; p += 4194304;  // y_ssm+hstate | kvb
  float* segBig1 = p; p += 6291456;  // x_trip | w_outp_aug (after in_proj)
  float* segBig2 = p; p += 7077888;  // w_in_trip | {y_norm|x_aug|q_final}@0, attn_aug@3145728
  float* segH = p; p += 3145728;     // {out_w_T,qwpad,Wq} | k_final
  unsigned short* w_3down_aug = (unsigned short*)p; p += 589824;
  unsigned short* w_qups_aug  = (unsigned short*)p; p += 294912;
  unsigned short* w_kvup_aug  = (unsigned short*)p; p += 393216;
  unsigned short* c_q_aug     = (unsigned short*)p; p += 393216;
  unsigned short* c_kv_aug    = (unsigned short*)p; p += 393216;
  float* Gbuf = p; p += 131072;

  float* zxbcdt = segA;
  float* scores = segA;
  float* qbuf   = segA;
  float* xBC    = segB;
  float* q_idx  = segB;
  float* k_idx  = segB + 131072;
  float* c3     = segB + 262144;
  float* y_ssm  = segD;
  float* hstate = segD + 2097152;
  float* kvb    = segD;
  unsigned short* x_trip     = (unsigned short*)segBig1;  // dead after in_proj
  unsigned short* w_outp_aug = (unsigned short*)segBig1;  // written after in_proj
  unsigned short* w_in_trip  = (unsigned short*)segBig2;  // dead after in_proj
  float* y_norm  = segBig2;                               // gatenorm..q_idx gemm
  unsigned short* x_aug = (unsigned short*)segBig2;       // after topk..down-proj
  float* q_final = segBig2;                               // rope_pack..attn
  unsigned short* attn_aug = (unsigned short*)(segBig2 + 3145728);
  float* out_w_T = segH;
  float* qwpad   = segH + 1048576;
  float* Wq      = segH + 1179648;
  float* k_final = segH;                                  // after q_idx gemm

  dim3 blk(256);
  auto cdiv = [](int a, int b) { return (a + b - 1) / b; };
  auto gemmf3 = [&](const float* A, const float* W, float* C, int M, int N, int K, int S) {
    dim3 grid(cdiv(N, 128), M / 128, S);
    hipLaunchKernelGGL(gemm_f32_v3, grid, blk, 0, stream, A, W, C, M, N, K);
  };
  auto gemmb = [&](const unsigned short* A, const unsigned short* W, float* C,
                   int M, int N, int K, int lda, int ldb, int ldc, int S) {
    dim3 grid(N / 128, M / 128, S);
    hipLaunchKernelGGL(gemm_bf16_kernel, grid, blk, 0, stream, A, W, C, M, N, K, lda, ldb, ldc);
  };
  auto caugA = [&](const float* s, unsigned short* d, int total, int K, int sld) {
    hipLaunchKernelGGL(conv_augA_kernel, dim3(cdiv(total, 256)), blk, 0, stream, s, d, total, K, sld);
  };
  auto caugW = [&](const float* s, unsigned short* d, int rows, int total, int K, int sld) {
    hipLaunchKernelGGL(conv_augW_kernel, dim3(cdiv(total, 256)), blk, 0, stream, s, d, rows, total, K, sld);
  };

  // ---- weight precomputes ----
  hipLaunchKernelGGL(transpose1024_kernel, dim3(1024), blk, 0, stream, idx_out_w, out_w_T);
  hipMemsetAsync(qwpad, 0, 131072 * 4, stream);
  hipMemcpyAsync(qwpad, idx_q_w, (size_t)64 * 1024 * 4, hipMemcpyDeviceToDevice, stream);
  hipMemsetAsync(Wq, 0, 131072 * 4, stream);
  gemmf3(qwpad, out_w_T, Wq, 128, 1024, 1024, 8);
  hipLaunchKernelGGL(conv_tripA_kernel, dim3(cdiv(2048 * 1024, 256)), blk, 0, stream,
                     x, x_trip, 2048 * 1024, 1024);
  hipLaunchKernelGGL(conv_tripW_kernel, dim3(cdiv(2304 * 1024, 256)), blk, 0, stream,
                     idx_in_w, w_in_trip, 2208, 2304 * 1024, 1024);
  caugW(q_down_w,  w_3down_aug,                    128, 128 * 1024, 1024, 1024);
  caugW(kv_down_w, w_3down_aug + 128 * 1024 * 3,   128, 128 * 1024, 1024, 1024);
  caugW(k_rope_w,  w_3down_aug + 256 * 1024 * 3,    32, 128 * 1024, 1024, 1024);
  caugW(q_up_w,    w_qups_aug,                    1024, 1024 * 128, 128, 128);
  caugW(q_rope_w,  w_qups_aug + 1024 * 128 * 3,    512, 512 * 128, 128, 128);
  caugW(kv_up_w,   w_kvup_aug, 2048, 2048 * 128, 128, 128);

  // ---- mamba branch: in_proj via triple-split MFMA (fp32-accurate) ----
  hipMemsetAsync(zxbcdt, 0, (size_t)L * INDIMP * 4, stream);
  gemmb(x_trip, w_in_trip, zxbcdt, 2048, 2304, 6144, 6144, 6144, INDIMP, 4);
  // x_trip dead -> write out-proj weights into segBig1
  caugW(out_w, w_outp_aug, 1024, 1024 * 1024, 1024, 1024);
  hipLaunchKernelGGL(conv_silu_kernel, dim3(cdiv(L * CONVCH, 256)), blk, 0, stream,
                     zxbcdt, idx_conv_w, idx_conv_b, xBC);
  hipLaunchKernelGGL(dt_kernel, dim3(L * MNH / 256), blk, 0, stream,
                     zxbcdt, idx_dt_b, idx_A_log, dtb, logdA);
  hipLaunchKernelGGL(lcd_kernel, dim3(4), blk, 0, stream, logdA, lcdb);
  hipLaunchKernelGGL(chunk_G_kernel, dim3(NCH), blk, 0, stream, xBC, Gbuf);
  hipLaunchKernelGGL(scan_local_kernel, dim3(NCH * MNH), blk, 0, stream,
                     xBC, dtb, lcdb, hstate);
  hipLaunchKernelGGL(scan_combine_kernel, dim3(256), blk, 0, stream, hstate, lcdb);
  hipLaunchKernelGGL(scan_y_kernel, dim3(NCH * MNH), blk, 0, stream,
                     xBC, Gbuf, dtb, lcdb, hstate, y_ssm);
  // y_norm -> segBig2 (w_in_trip dead)
  hipLaunchKernelGGL(gatenorm_kernel, dim3(L), blk, 0, stream,
                     y_ssm, xBC, zxbcdt, idx_D, idx_norm_w, y_norm);

  // ---- index scores + topk (out-proj folded into Wq) ----
  hipMemsetAsync(q_idx, 0, 131072 * 4, stream);
  hipMemsetAsync(k_idx, 0, 131072 * 4, stream);
  gemmf3(y_norm, Wq, q_idx, 2048, 64, 1024, 16);
  gemmf3(x, idx_k_w, k_idx, 2048, 64, 1024, 16);
  gemmf3(q_idx, k_idx, scores, 2048, 2048, 64, 1);
  hipLaunchKernelGGL(topk_kernel, dim3(L), blk, 0, stream, scores, idxb);

  // ---- attention value path (aug split-bf16 MFMA) ----
  caugA(x, x_aug, 2048 * 1024, 1024, 1024);  // segBig2@0 (y_norm dead)
  hipMemsetAsync(c3, 0, 786432 * 4, stream);
  gemmb(x_aug, w_3down_aug, c3, 2048, 384, 3072, 3072, 3072, 384, 8);
  caugA(c3, c_q_aug, 2048 * 128, 128, 384);
  caugA(c3 + 128, c_kv_aug, 2048 * 128, 128, 384);
  gemmb(c_q_aug, w_qups_aug, qbuf, 2048, 1536, 384, 384, 384, 1536, 1);
  gemmb(c_kv_aug, w_kvup_aug, kvb, 2048, 2048, 384, 384, 384, 2048, 1);
  hipLaunchKernelGGL(rope_pack_kernel, dim3(L), dim3(128), 0, stream,
                     qbuf, kvb, c3, q_final, k_final);

  // ---- sparse attention + output projection ----
  hipLaunchKernelGGL(attn_kernel, dim3(L), blk, 0, stream,
                     q_final, k_final, kvb, idxb, attn_aug);
  hipMemsetAsync(out, 0, (size_t)out_size * 4, stream);
  // Isolated change vs R4: S=2 -> 4. 512 blocks = the 2-block/CU LDS cap
  // (out already memset + already atomic at S=2, so no enabler cost).
  gemmb(attn_aug, w_outp_aug, out, 2048, 1024, 3072, 3072, 3072, 1024, 4);
}

// Round 7
// 691.617 us; speedup vs baseline: 1.0623x; 1.0262x over previous
//
#include <hip/hip_runtime.h>
#include <math.h>

// ---------------- constants ----------------
constexpr int L      = 2048;
constexpr int NH     = 16;
constexpr int DINNER = 1024;
constexpr int MNH    = 32;
constexpr int CONVCH = 1152;
constexpr int INDIMP = 2304;   // padded stride for zxbcdt (2208 -> 2304, N%128)
constexpr int CHUNK  = 64;
constexpr int NCH    = 32;

using bf16x8 = __attribute__((ext_vector_type(8))) short;
using f32x4  = __attribute__((ext_vector_type(4))) float;

__device__ __forceinline__ f32x4 splat4(float x) { return (f32x4){x, x, x, x}; }

__device__ __forceinline__ unsigned short f2bf(float f) {
  unsigned u = __float_as_uint(f);
  return (unsigned short)((u + 0x7fffu + ((u >> 16) & 1u)) >> 16);
}
__device__ __forceinline__ float bf2f(unsigned short h) {
  return __uint_as_float((unsigned)h << 16);
}

// ---------------- fp32 GEMM v3 (small index-critical shapes) ----------------
// tri=1: skip blocks fully above the causal diagonal (outputs never read by topk).
__global__ __launch_bounds__(256) void gemm_f32_v3(
    const float* __restrict__ A, const float* __restrict__ W,
    float* __restrict__ C, int M, int N, int K, int tri) {
  __shared__ float As[16][132];
  __shared__ float Ws[16][132];
  int tid = threadIdx.x;
  int bm = blockIdx.y * 128, bn = blockIdx.x * 128;
  if (tri && bn > bm + 127) return;
  int kper = K / gridDim.z;
  int kb = blockIdx.z * kper, ke = kb + kper;
  int lr = tid >> 1;
  int lh = (tid & 1) * 8;
  int tx = tid & 15, ty = tid >> 4;
  bool wok = (bn + lr < N);
  const float* arow = A + (size_t)(bm + lr) * K + lh;
  const float* wrow = W + (size_t)(bn + lr) * K + lh;
  float4 a0, a1, w0, w1;
  auto gload = [&](int k0) {
    a0 = *(const float4*)(arow + k0);
    a1 = *(const float4*)(arow + k0 + 4);
    w0 = make_float4(0.f, 0.f, 0.f, 0.f); w1 = w0;
    if (wok) {
      w0 = *(const float4*)(wrow + k0);
      w1 = *(const float4*)(wrow + k0 + 4);
    }
  };
  f32x4 acc0[8] = {}, acc1[8] = {};
  gload(kb);
  for (int k0 = kb; k0 < ke; k0 += 16) {
    __syncthreads();
    As[lh+0][lr]=a0.x; As[lh+1][lr]=a0.y; As[lh+2][lr]=a0.z; As[lh+3][lr]=a0.w;
    As[lh+4][lr]=a1.x; As[lh+5][lr]=a1.y; As[lh+6][lr]=a1.z; As[lh+7][lr]=a1.w;
    Ws[lh+0][lr]=w0.x; Ws[lh+1][lr]=w0.y; Ws[lh+2][lr]=w0.z; Ws[lh+3][lr]=w0.w;
    Ws[lh+4][lr]=w1.x; Ws[lh+5][lr]=w1.y; Ws[lh+6][lr]=w1.z; Ws[lh+7][lr]=w1.w;
    __syncthreads();
    if (k0 + 16 < ke) gload(k0 + 16);
#pragma unroll
    for (int kk = 0; kk < 16; ++kk) {
      f32x4 b0 = *(const f32x4*)&Ws[kk][tx * 4];
      f32x4 b1 = *(const f32x4*)&Ws[kk][64 + tx * 4];
      f32x4 al = *(const f32x4*)&As[kk][ty * 8];
      f32x4 ah = *(const f32x4*)&As[kk][ty * 8 + 4];
#pragma unroll
      for (int i = 0; i < 4; ++i) {
        acc0[i]     += splat4(al[i]) * b0;
        acc1[i]     += splat4(al[i]) * b1;
        acc0[i + 4] += splat4(ah[i]) * b0;
        acc1[i + 4] += splat4(ah[i]) * b1;
      }
    }
  }
  bool single = (gridDim.z == 1);
#pragma unroll
  for (int i = 0; i < 8; ++i) {
    int row = bm + ty * 8 + i;
    float* crow = C + (size_t)row * N;
    int c0 = bn + tx * 4, c1 = bn + 64 + tx * 4;
    if (c0 + 3 < N) {
      if (single) *(f32x4*)(crow + c0) = acc0[i];
      else {
        atomicAdd(crow + c0 + 0, acc0[i][0]); atomicAdd(crow + c0 + 1, acc0[i][1]);
        atomicAdd(crow + c0 + 2, acc0[i][2]); atomicAdd(crow + c0 + 3, acc0[i][3]);
      }
    }
    if (c1 + 3 < N) {
      if (single) *(f32x4*)(crow + c1) = acc1[i];
      else {
        atomicAdd(crow + c1 + 0, acc1[i][0]); atomicAdd(crow + c1 + 1, acc1[i][1]);
        atomicAdd(crow + c1 + 2, acc1[i][2]); atomicAdd(crow + c1 + 3, acc1[i][3]);
      }
    }
  }
}

// ---------------- dual fp32 GEMM: two independent same-shape GEMMs in one grid ----------------
// gridDim.z = 2*S; z < S -> (A0,W0,C0), else (A1,W1,C1). Always atomic path (outputs memset).
__global__ __launch_bounds__(256) void gemm_f32_dual(
    const float* __restrict__ A0, const float* __restrict__ W0, float* __restrict__ C0,
    const float* __restrict__ A1, const float* __restrict__ W1, float* __restrict__ C1,
    int M, int N, int K, int S) {
  __shared__ float As[16][132];
  __shared__ float Ws[16][132];
  int tid = threadIdx.x;
  int bm = blockIdx.y * 128, bn = blockIdx.x * 128;
  int pair = (int)blockIdx.z >= S;
  int zi = blockIdx.z - pair * S;
  const float* A = pair ? A1 : A0;
  const float* W = pair ? W1 : W0;
  float* C = pair ? C1 : C0;
  int kper = K / S;
  int kb = zi * kper, ke = kb + kper;
  int lr = tid >> 1;
  int lh = (tid & 1) * 8;
  int tx = tid & 15, ty = tid >> 4;
  bool wok = (bn + lr < N);
  const float* arow = A + (size_t)(bm + lr) * K + lh;
  const float* wrow = W + (size_t)(bn + lr) * K + lh;
  float4 a0, a1, w0, w1;
  auto gload = [&](int k0) {
    a0 = *(const float4*)(arow + k0);
    a1 = *(const float4*)(arow + k0 + 4);
    w0 = make_float4(0.f, 0.f, 0.f, 0.f); w1 = w0;
    if (wok) {
      w0 = *(const float4*)(wrow + k0);
      w1 = *(const float4*)(wrow + k0 + 4);
    }
  };
  f32x4 acc0[8] = {}, acc1[8] = {};
  gload(kb);
  for (int k0 = kb; k0 < ke; k0 += 16) {
    __syncthreads();
    As[lh+0][lr]=a0.x; As[lh+1][lr]=a0.y; As[lh+2][lr]=a0.z; As[lh+3][lr]=a0.w;
    As[lh+4][lr]=a1.x; As[lh+5][lr]=a1.y; As[lh+6][lr]=a1.z; As[lh+7][lr]=a1.w;
    Ws[lh+0][lr]=w0.x; Ws[lh+1][lr]=w0.y; Ws[lh+2][lr]=w0.z; Ws[lh+3][lr]=w0.w;
    Ws[lh+4][lr]=w1.x; Ws[lh+5][lr]=w1.y; Ws[lh+6][lr]=w1.z; Ws[lh+7][lr]=w1.w;
    __syncthreads();
    if (k0 + 16 < ke) gload(k0 + 16);
#pragma unroll
    for (int kk = 0; kk < 16; ++kk) {
      f32x4 b0 = *(const f32x4*)&Ws[kk][tx * 4];
      f32x4 b1 = *(const f32x4*)&Ws[kk][64 + tx * 4];
      f32x4 al = *(const f32x4*)&As[kk][ty * 8];
      f32x4 ah = *(const f32x4*)&As[kk][ty * 8 + 4];
#pragma unroll
      for (int i = 0; i < 4; ++i) {
        acc0[i]     += splat4(al[i]) * b0;
        acc1[i]     += splat4(al[i]) * b1;
        acc0[i + 4] += splat4(ah[i]) * b0;
        acc1[i + 4] += splat4(ah[i]) * b1;
      }
    }
  }
#pragma unroll
  for (int i = 0; i < 8; ++i) {
    int row = bm + ty * 8 + i;
    float* crow = C + (size_t)row * N;
    int c0 = bn + tx * 4, c1 = bn + 64 + tx * 4;
    if (c0 + 3 < N) {
      atomicAdd(crow + c0 + 0, acc0[i][0]); atomicAdd(crow + c0 + 1, acc0[i][1]);
      atomicAdd(crow + c0 + 2, acc0[i][2]); atomicAdd(crow + c0 + 3, acc0[i][3]);
    }
    if (c1 + 3 < N) {
      atomicAdd(crow + c1 + 0, acc1[i][0]); atomicAdd(crow + c1 + 1, acc1[i][1]);
      atomicAdd(crow + c1 + 2, acc1[i][2]); atomicAdd(crow + c1 + 3, acc1[i][3]);
    }
  }
}

// ---------------- 1024x1024 transpose ----------------
__global__ __launch_bounds__(256) void transpose1024_kernel(
    const float* __restrict__ src, float* __restrict__ dst) {
  __shared__ float t[32][33];
  int bx = blockIdx.x & 31, by = blockIdx.x >> 5;
  int tx = threadIdx.x & 31, ty8 = threadIdx.x >> 5;
  for (int r = ty8; r < 32; r += 8)
    t[r][tx] = src[(size_t)(by * 32 + r) * 1024 + bx * 32 + tx];
  __syncthreads();
  for (int r = ty8; r < 32; r += 8)
    dst[(size_t)(bx * 32 + r) * 1024 + by * 32 + tx] = t[tx][r];
}

// ---------------- bf16 MFMA GEMM (double-buffered LDS: stage(t+1) || compute(t)) ----------------
// T1: XCD-aware (x,y) tile swizzle (identity fallback when nwg%8!=0).
// T3-min: 2-deep pipeline (structure-bound at ~445 TF for the 2048-class shapes).
__global__ __launch_bounds__(256) void gemm_bf16_kernel(
    const unsigned short* __restrict__ A, const unsigned short* __restrict__ W,
    float* __restrict__ C, int M, int N, int K, int lda, int ldb, int ldc) {
  __shared__ unsigned short As[2][128 * 64];
  __shared__ unsigned short Ws[2][128 * 64];
  int tid = threadIdx.x;
  int bx = blockIdx.x, by = blockIdx.y;
  int nxy = gridDim.x * gridDim.y;
  if ((nxy & 7) == 0) {
    int lin = by * gridDim.x + bx;
    int cpx = nxy >> 3;
    int swz = (lin & 7) * cpx + (lin >> 3);
    bx = swz % gridDim.x;
    by = swz / gridDim.x;
  }
  int bm = by * 128, bn = bx * 128;
  int kper = K / gridDim.z;
  int k_begin = blockIdx.z * kper;
  int k_end = k_begin + kper;
  int wv = tid >> 6, lane = tid & 63;
  int wrow = (wv >> 1) * 64, wcol = (wv & 1) * 64;
  int lrow = lane & 15, quad = lane >> 4;

  f32x4 acc[4][4] = {};

  auto stage = [&](int b, int k0) {
#pragma unroll
    for (int it = 0; it < 4; ++it) {
      int s = it * 256 + tid;
      int r = s >> 3;
      int q = (s & 7) ^ (r & 7);
      const unsigned short* ga = A + (size_t)(bm + r) * lda + k0 + q * 8;
      const unsigned short* gw = W + (size_t)(bn + r) * ldb + k0 + q * 8;
      __builtin_amdgcn_global_load_lds((const __attribute__((address_space(1))) void*)ga,
                                       (__attribute__((address_space(3))) void*)&As[b][s * 8], 16, 0, 0);
      __builtin_amdgcn_global_load_lds((const __attribute__((address_space(1))) void*)gw,
                                       (__attribute__((address_space(3))) void*)&Ws[b][s * 8], 16, 0, 0);
    }
  };

  stage(0, k_begin);
  int cur = 0;
  for (int k0 = k_begin; k0 < k_end; k0 += 64) {
    __syncthreads();
    if (k0 + 64 < k_end) stage(cur ^ 1, k0 + 64);
#pragma unroll
    for (int ks = 0; ks < 2; ++ks) {
      bf16x8 af[4], wf[4];
#pragma unroll
      for (int i = 0; i < 4; ++i) {
        int ra = wrow + i * 16 + lrow;
        int qa = (ks * 4 + quad) ^ (ra & 7);
        af[i] = *(const bf16x8*)&As[cur][(ra * 8 + qa) * 8];
        int rw = wcol + i * 16 + lrow;
        int qw = (ks * 4 + quad) ^ (rw & 7);
        wf[i] = *(const bf16x8*)&Ws[cur][(rw * 8 + qw) * 8];
      }
#pragma unroll
      for (int i = 0; i < 4; ++i)
#pragma unroll
        for (int j = 0; j < 4; ++j)
          acc[i][j] = __builtin_amdgcn_mfma_f32_16x16x32_bf16(af[i], wf[j], acc[i][j], 0, 0, 0);
    }
    cur ^= 1;
  }
  bool single = (gridDim.z == 1);
#pragma unroll
  for (int i = 0; i < 4; ++i)
#pragma unroll
    for (int j = 0; j < 4; ++j)
#pragma unroll
      for (int r = 0; r < 4; ++r) {
        int row = bm + wrow + i * 16 + quad * 4 + r;
        int col = bn + wcol + j * 16 + lrow;
        float v = acc[i][j][r];
        if (single) C[(size_t)row * ldc + col] = v;
        else atomicAdd(&C[(size_t)row * ldc + col], v);
      }
}

// ---------------- conversions ----------------
// 3-slot aug (value path): A=[h,l,h], W=[h,h,l]
__global__ __launch_bounds__(256) void conv_augA_kernel(
    const float* __restrict__ src, unsigned short* __restrict__ dst,
    int total, int K, int sld) {
  int i = blockIdx.x * 256 + threadIdx.x;
  if (i >= total) return;
  int m = i / K, k = i - m * K;
  float f = src[(size_t)m * sld + k];
  unsigned short hi = f2bf(f);
  unsigned short lo = f2bf(f - bf2f(hi));
  size_t o = ((size_t)m * K + k) * 3;
  dst[o] = hi; dst[o + 1] = lo; dst[o + 2] = hi;
}
// fused c3 -> c_q_aug (cols 0..127) + c_kv_aug (cols 128..255), one read of c3
__global__ __launch_bounds__(256) void conv_augA2_kernel(
    const float* __restrict__ c3, unsigned short* __restrict__ dq,
    unsigned short* __restrict__ dkv) {
  int i = blockIdx.x * 256 + threadIdx.x;
  if (i >= 2048 * 256) return;
  int m = i >> 8, k = i & 255;
  float f = c3[(size_t)m * 384 + k];
  unsigned short hi = f2bf(f);
  unsigned short lo = f2bf(f - bf2f(hi));
  if (k < 128) {
    size_t o = ((size_t)m * 128 + k) * 3;
    dq[o] = hi; dq[o + 1] = lo; dq[o + 2] = hi;
  } else {
    size_t o = ((size_t)m * 128 + (k - 128)) * 3;
    dkv[o] = hi; dkv[o + 1] = lo; dkv[o + 2] = hi;
  }
}
__global__ __launch_bounds__(256) void conv_augW_kernel(
    const float* __restrict__ src, unsigned short* __restrict__ dst,
    int rows, int total, int K, int sld) {
  int i = blockIdx.x * 256 + threadIdx.x;
  if (i >= total) return;
  int n = i / K, k = i - n * K;
  unsigned short hi = 0, lo = 0;
  if (n < rows) {
    float f = src[(size_t)n * sld + k];
    hi = f2bf(f);
    lo = f2bf(f - bf2f(hi));
  }
  size_t o = ((size_t)n * K + k) * 3;
  dst[o] = hi; dst[o + 1] = hi; dst[o + 2] = lo;
}
// 6-slot triple split fused A+W (index path): A=[h,m,l,h,m,h], W=[h,h,h,m,m,l]
// First 2048*1024 threads: x -> x_trip. Next 2304*1024: idx_in_w -> w_in_trip.
__global__ __launch_bounds__(256) void conv_tripAW_kernel(
    const float* __restrict__ xsrc, unsigned short* __restrict__ dstA,
    const float* __restrict__ wsrc, unsigned short* __restrict__ dstW) {
  int i = blockIdx.x * 256 + threadIdx.x;
  if (i < 2048 * 1024) {
    float f = xsrc[i];
    unsigned short h = f2bf(f);
    float r1 = f - bf2f(h);
    unsigned short m = f2bf(r1);
    unsigned short l = f2bf(r1 - bf2f(m));
    size_t o = (size_t)i * 6;
    dstA[o] = h; dstA[o + 1] = m; dstA[o + 2] = l;
    dstA[o + 3] = h; dstA[o + 4] = m; dstA[o + 5] = h;
  } else {
    int j = i - 2048 * 1024;
    if (j >= 2304 * 1024) return;
    int n = j >> 10, k = j & 1023;
    unsigned short h = 0, m = 0, l = 0;
    if (n < 2208) {
      float f = wsrc[(size_t)n * 1024 + k];
      h = f2bf(f);
      float r1 = f - bf2f(h);
      m = f2bf(r1);
      l = f2bf(r1 - bf2f(m));
    }
    size_t o = (size_t)j * 6;
    dstW[o] = h; dstW[o + 1] = h; dstW[o + 2] = h;
    dstW[o + 3] = m; dstW[o + 4] = m; dstW[o + 5] = l;
  }
}

// ---------------- conv1d(4-tap, causal) + SiLU (scalar, R4-verified) ----------------
__global__ __launch_bounds__(256) void conv_silu_kernel(
    const float* __restrict__ zxbcdt, const float* __restrict__ conv_w,
    const float* __restrict__ conv_b, float* __restrict__ xBC) {
  int idx = blockIdx.x * 256 + threadIdx.x;
  if (idx >= L * CONVCH) return;
  int l = idx / CONVCH, c = idx - l * CONVCH;
  float acc = conv_b[c];
#pragma unroll
  for (int k = 0; k < 4; ++k) {
    int ls = l - 3 + k;
    if (ls >= 0) acc += zxbcdt[(size_t)ls * INDIMP + DINNER + c] * conv_w[c * 4 + k];
  }
  xBC[idx] = acc / (1.f + expf(-acc));
}

// ---------------- dt / logdA (dt cols at 2176..2207) ----------------
__global__ __launch_bounds__(256) void dt_kernel(
    const float* __restrict__ zxbcdt, const float* __restrict__ dt_bias,
    const float* __restrict__ A_log, float* __restrict__ dt, float* __restrict__ logdA) {
  int idx = blockIdx.x * 256 + threadIdx.x;
  int l = idx >> 5, h = idx & 31;
  float xv = zxbcdt[(size_t)l * INDIMP + 2176 + h] + dt_bias[h];
  float sp = fmaxf(xv, 0.f) + log1pf(expf(-fabsf(xv)));
  dt[idx] = sp;
  logdA[idx] = sp * -expf(A_log[h]);
}

// ---------------- lcd ----------------
__global__ __launch_bounds__(256) void lcd_kernel(
    const float* __restrict__ logdA, float* __restrict__ lcd) {
  int i = blockIdx.x * 256 + threadIdx.x;
  if (i >= NCH * MNH) return;
  int c = i >> 5, h = i & 31;
  float s = 0.f;
  for (int t = 0; t < CHUNK; ++t) {
    s += logdA[(c * CHUNK + t) * MNH + h];
    lcd[(size_t)i * CHUNK + t] = s;
  }
}

// ---------------- G[c][t][s] = C_t . B_s ----------------
__global__ __launch_bounds__(256) void chunk_G_kernel(
    const float* __restrict__ xBC, float* __restrict__ G) {
  int c = blockIdx.x, tid = threadIdx.x;
  __shared__ float BsT[64][68];
  __shared__ float Cs[64][65];
  int t = tid >> 2, q = tid & 3;
  const float* row = xBC + (size_t)(c * 64 + t) * CONVCH + DINNER;
#pragma unroll
  for (int j = 0; j < 16; j += 4) {
    float4 b = *(const float4*)(row + q * 16 + j);
    BsT[q * 16 + j + 0][t] = b.x; BsT[q * 16 + j + 1][t] = b.y;
    BsT[q * 16 + j + 2][t] = b.z; BsT[q * 16 + j + 3][t] = b.w;
    float4 cv = *(const float4*)(row + 64 + q * 16 + j);
    Cs[t][q * 16 + j + 0] = cv.x; Cs[t][q * 16 + j + 1] = cv.y;
    Cs[t][q * 16 + j + 2] = cv.z; Cs[t][q * 16 + j + 3] = cv.w;
  }
  __syncthreads();
  int s0 = q * 16;
  f32x4 g0 = {}, g1 = {}, g2 = {}, g3 = {};
  for (int n = 0; n < 64; ++n) {
    f32x4 cv = splat4(Cs[t][n]);
    g0 += cv * *(const f32x4*)&BsT[n][s0];
    g1 += cv * *(const f32x4*)&BsT[n][s0 + 4];
    g2 += cv * *(const f32x4*)&BsT[n][s0 + 8];
    g3 += cv * *(const f32x4*)&BsT[n][s0 + 12];
  }
  float* gp = G + ((size_t)c * 64 + t) * 64 + s0;
  *(f32x4*)gp = g0; *(f32x4*)(gp + 4) = g1; *(f32x4*)(gp + 8) = g2; *(f32x4*)(gp + 12) = g3;
}

// ---------------- scan pass A ----------------
__global__ __launch_bounds__(256) void scan_local_kernel(
    const float* __restrict__ xBC, const float* __restrict__ dt,
    const float* __restrict__ lcd, float* __restrict__ hstate) {
  int c = blockIdx.x >> 5, h = blockIdx.x & 31;
  int tid = threadIdx.x;
  __shared__ float Bs[64][68];
  __shared__ float xss[64][36];
  __shared__ float w2s[64];
  int t0 = c * CHUNK;
  int t = tid >> 2, q = tid & 3;
  const float* row = xBC + (size_t)(t0 + t) * CONVCH;
#pragma unroll
  for (int j = 0; j < 16; j += 4)
    *(float4*)&Bs[t][q * 16 + j] = *(const float4*)(row + DINNER + q * 16 + j);
  if (q < 2) {
#pragma unroll
    for (int j = 0; j < 16; j += 4)
      *(float4*)&xss[t][q * 16 + j] = *(const float4*)(row + h * 32 + q * 16 + j);
  }
  if (tid < 64) {
    const float* lc = lcd + ((size_t)c * 32 + h) * CHUNK;
    w2s[tid] = expf(lc[63] - lc[tid]) * dt[(t0 + tid) * MNH + h];
  }
  __syncthreads();
  int n = tid >> 2, pg = (tid & 3) * 8;
  f32x4 h0 = {}, h1 = {};
  for (int s = 0; s < 64; ++s) {
    f32x4 wb = splat4(w2s[s] * Bs[s][n]);
    h0 += wb * *(const f32x4*)&xss[s][pg];
    h1 += wb * *(const f32x4*)&xss[s][pg + 4];
  }
  float* hp = hstate + ((size_t)c * 32 + h) * 2048 + n * 32 + pg;
  *(f32x4*)hp = h0; *(f32x4*)(hp + 4) = h1;
}

// ---------------- scan pass B ----------------
__global__ __launch_bounds__(256) void scan_combine_kernel(
    float* __restrict__ hstate, const float* __restrict__ lcd) {
  int i = blockIdx.x * 256 + threadIdx.x;
  int h = i >> 11;
  float H = 0.f;
  for (int c = 0; c < NCH; ++c) {
    float hl = hstate[(size_t)c * 65536 + i];
    hstate[(size_t)c * 65536 + i] = H;
    float P = expf(lcd[((size_t)c * 32 + h) * CHUNK + CHUNK - 1]);
    H = H * P + hl;
  }
}

// ---------------- scan pass C ----------------
__global__ __launch_bounds__(256) void scan_y_kernel(
    const float* __restrict__ xBC, const float* __restrict__ G,
    const float* __restrict__ dt, const float* __restrict__ lcd,
    const float* __restrict__ hstate, float* __restrict__ y) {
  int c = blockIdx.x >> 5, h = blockIdx.x & 31;
  int tid = threadIdx.x;
  __shared__ float Ms[64][65];
  __shared__ float Cs[64][65];
  __shared__ float xss[64][36];
  __shared__ float Hss[64][36];
  __shared__ float lcds[64], dts[64];
  int t0 = c * CHUNK;
  int t = tid >> 2, q = tid & 3;
  const float* row = xBC + (size_t)(t0 + t) * CONVCH;
#pragma unroll
  for (int j = 0; j < 16; j += 4) {
    float4 cv = *(const float4*)(row + DINNER + 64 + q * 16 + j);
    Cs[t][q * 16 + j + 0] = cv.x; Cs[t][q * 16 + j + 1] = cv.y;
    Cs[t][q * 16 + j + 2] = cv.z; Cs[t][q * 16 + j + 3] = cv.w;
  }
  if (q < 2) {
#pragma unroll
    for (int j = 0; j < 16; j += 4)
      *(float4*)&xss[t][q * 16 + j] = *(const float4*)(row + h * 32 + q * 16 + j);
  }
  {
    const float* gp = G + ((size_t)c * 64 + t) * 64 + q * 16;
#pragma unroll
    for (int j = 0; j < 16; j += 4) {
      float4 g = *(const float4*)(gp + j);
      Ms[t][q * 16 + j + 0] = g.x; Ms[t][q * 16 + j + 1] = g.y;
      Ms[t][q * 16 + j + 2] = g.z; Ms[t][q * 16 + j + 3] = g.w;
    }
  }
  {
    const float* hp = hstate + ((size_t)c * 32 + h) * 2048 + tid * 8;
    int n = tid >> 2, p0 = (tid & 3) * 8;
    *(float4*)&Hss[n][p0]     = *(const float4*)hp;
    *(float4*)&Hss[n][p0 + 4] = *(const float4*)(hp + 4);
  }
  if (tid < 64) {
    lcds[tid] = lcd[((size_t)c * 32 + h) * CHUNK + tid];
    dts[tid]  = dt[(t0 + tid) * MNH + h];
  }
  __syncthreads();
  {
    int s0 = q * 16;
#pragma unroll
    for (int j = 0; j < 16; ++j) {
      int s = s0 + j;
      float m = (s <= t) ? expf(lcds[t] - lcds[s]) * dts[s] * Ms[t][s] : 0.f;
      Ms[t][s] = m;
    }
  }
  __syncthreads();
  int pg = q * 8;
  f32x4 y0 = {}, y1 = {}, a0 = {}, a1 = {};
  for (int s = 0; s < 64; ++s) {
    f32x4 m = splat4(Ms[t][s]);
    y0 += m * *(const f32x4*)&xss[s][pg];
    y1 += m * *(const f32x4*)&xss[s][pg + 4];
  }
  for (int n = 0; n < 64; ++n) {
    f32x4 cn = splat4(Cs[t][n]);
    a0 += cn * *(const f32x4*)&Hss[n][pg];
    a1 += cn * *(const f32x4*)&Hss[n][pg + 4];
  }
  f32x4 cd = splat4(expf(lcds[t]));
  y0 += cd * a0; y1 += cd * a1;
  float* yp = y + (size_t)(t0 + t) * DINNER + h * 32 + pg;
  *(f32x4*)yp = y0; *(f32x4*)(yp + 4) = y1;
}

// ---------------- gate + RMSNorm ----------------
__global__ __launch_bounds__(256) void gatenorm_kernel(
    const float* __restrict__ y_ssm, const float* __restrict__ xBC,
    const float* __restrict__ zxbcdt, const float* __restrict__ Dv,
    const float* __restrict__ norm_w, float* __restrict__ out) {
  int l = blockIdx.x, tid = threadIdx.x;
  float vals[4];
  float ss = 0.f;
#pragma unroll
  for (int i = 0; i < 4; ++i) {
    int d = tid + i * 256;
    int h = d >> 5;
    float v = y_ssm[(size_t)l * DINNER + d] + Dv[h] * xBC[(size_t)l * CONVCH + d];
    float z = zxbcdt[(size_t)l * INDIMP + d];
    v *= z / (1.f + expf(-z));
    vals[i] = v;
    ss += v * v;
  }
#pragma unroll
  for (int off = 32; off > 0; off >>= 1) ss += __shfl_xor(ss, off);
  __shared__ float sred[4];
  if ((tid & 63) == 0) sred[tid >> 6] = ss;
  __syncthreads();
  float tot = sred[0] + sred[1] + sred[2] + sred[3];
  float scale = rsqrtf(tot * (1.f / 1024.f) + 1e-5f);
#pragma unroll
  for (int i = 0; i < 4; ++i) {
    int d = tid + i * 256;
    out[(size_t)l * DINNER + d] = vals[i] * scale * norm_w[d];
  }
}

// ---------------- per-row top-64 radix select (R4-verified global-scan) ----------------
__global__ __launch_bounds__(256) void topk_kernel(
    const float* __restrict__ scores, int* __restrict__ out_idx) {
  int l = blockIdx.x, tid = threadIdx.x;
  if (l < 64) {
    if (tid < 64) out_idx[l * 64 + tid] = tid;
    return;
  }
  int n = l + 1;
  const float* row = scores + (size_t)l * L;
  __shared__ int hist[256];
  __shared__ unsigned sel_prefix;
  __shared__ int sel_remaining;
  __shared__ int cnt_g, cnt_e;
  __shared__ int eq_list[128];
  if (tid == 0) { cnt_g = 0; cnt_e = 0; }
  unsigned prefix = 0;
  int remaining = 64;
  for (int pass = 0; pass < 4; ++pass) {
    int shift = 24 - 8 * pass;
    unsigned himask = (pass == 0) ? 0u : (0xFFFFFFFFu << (shift + 8));
    hist[tid] = 0;
    __syncthreads();
    for (int j = tid; j < n; j += 256) {
      unsigned u = __float_as_uint(row[j]);
      unsigned key = (u & 0x80000000u) ? ~u : (u | 0x80000000u);
      if (((key ^ prefix) & himask) == 0)
        atomicAdd(&hist[(key >> shift) & 255], 1);
    }
    __syncthreads();
    if (tid == 0) {
      int cum = 0, b = 255;
      for (; b >= 0; --b) {
        cum += hist[b];
        if (cum >= remaining) break;
      }
      sel_prefix = prefix | ((unsigned)b << shift);
      sel_remaining = remaining - (cum - hist[b]);
    }
    __syncthreads();
    prefix = sel_prefix;
    remaining = sel_remaining;
    __syncthreads();
  }
  unsigned T = prefix;
  for (int j = tid; j < n; j += 256) {
    unsigned u = __float_as_uint(row[j]);
    unsigned key = (u & 0x80000000u) ? ~u : (u | 0x80000000u);
    if (key > T) {
      int p = atomicAdd(&cnt_g, 1);
      out_idx[l * 64 + p] = j;
    } else if (key == T) {
      int p = atomicAdd(&cnt_e, 1);
      if (p < 128) eq_list[p] = j;
    }
  }
  __syncthreads();
  if (tid == 0) {
    int G = cnt_g;
    int E = remaining;
    int m = cnt_e < 128 ? cnt_e : 128;
    for (int e = 0; e < E; ++e) {
      int best = 0, bj = 0x7fffffff;
      for (int i = 0; i < m; ++i)
        if (eq_list[i] < bj) { bj = eq_list[i]; best = i; }
      out_idx[l * 64 + G + e] = bj;
      eq_list[best] = 0x7fffffff;
    }
  }
}

// ---------------- RoPE + pack q_final/k_final (fused-buffer strides) ----------------
__global__ __launch_bounds__(128) void rope_pack_kernel(
    const float* __restrict__ qbuf, const float* __restrict__ kv,
    const float* __restrict__ c3,
    float* __restrict__ q_final, float* __restrict__ k_final) {
  int l = blockIdx.x, tid = threadIdx.x;
  __shared__ float s_s[16], s_c[16];
  if (tid < 16) {
    float inv = powf(10000.f, -(float)tid / 16.f);
    float ang = (float)l * inv;
    s_s[tid] = sinf(ang);
    s_c[tid] = cosf(ang);
  }
  __syncthreads();
  const float* qrow = qbuf + (size_t)l * 1536;
  const float* krow = c3 + (size_t)l * 384 + 256;
  for (int e = tid; e < NH * 96; e += 128) {
    int hh = e / 96, d = e - hh * 96;
    float qv, kvv;
    if (d < 64) {
      qv  = qrow[hh * 64 + d];
      kvv = kv[(size_t)l * 2048 + hh * 64 + d];
    } else {
      int r = d - 64;
      if (r < 16) {
        float q1 = qrow[1024 + hh * 32 + r];
        float q2 = qrow[1024 + hh * 32 + 16 + r];
        qv = q1 * s_c[r] - q2 * s_s[r];
        float k1 = krow[r];
        float k2 = krow[16 + r];
        kvv = k1 * s_c[r] - k2 * s_s[r];
      } else {
        int rr = r - 16;
        float q1 = qrow[1024 + hh * 32 + rr];
        float q2 = qrow[1024 + hh * 32 + 16 + rr];
        qv = q1 * s_s[rr] + q2 * s_c[rr];
        float k1 = krow[rr];
        float k2 = krow[16 + rr];
        kvv = k1 * s_s[rr] + k2 * s_c[rr];
      }
    }
    q_final[(size_t)l * 1536 + e] = qv;
    k_final[(size_t)l * 1536 + e] = kvv;
  }
}

// ---------------- sparse attention (coalesced, one block per row) ----------------
__global__ __launch_bounds__(256) void attn_kernel(
    const float* __restrict__ q_final, const float* __restrict__ k_final,
    const float* __restrict__ kv, const int* __restrict__ idx,
    unsigned short* __restrict__ attn_aug) {
  int l = blockIdx.x;
  int tid = threadIdx.x;
  int h = tid >> 4;
  int s = tid & 15;
  __shared__ __align__(16) float lg[16][64];
  __shared__ int iks[64];

  if (tid < 64) iks[tid] = idx[l * 64 + tid];

  const float* qrow = q_final + (size_t)l * 1536 + h * 96 + s * 2;
  float q0 = qrow[0],  q1 = qrow[1];
  float q2 = qrow[32], q3 = qrow[33];
  float q4 = qrow[64], q5 = qrow[65];
  __syncthreads();

#pragma unroll 4
  for (int k = 0; k < 64; ++k) {
    const float* kr = k_final + (size_t)iks[k] * 1536 + h * 96 + s * 2;
    float2 a = *(const float2*)kr;
    float2 b = *(const float2*)(kr + 32);
    float2 c = *(const float2*)(kr + 64);
    float d = q0 * a.x + q1 * a.y + q2 * b.x + q3 * b.y + q4 * c.x + q5 * c.y;
    d += __shfl_xor(d, 1);
    d += __shfl_xor(d, 2);
    d += __shfl_xor(d, 4);
    d += __shfl_xor(d, 8);
    if (s == 0) lg[h][k] = d * 0.10206207261596575f;
  }
  __syncthreads();

  f32x4 lv = *(const f32x4*)&lg[h][s * 4];
  float m = fmaxf(fmaxf(lv[0], lv[1]), fmaxf(lv[2], lv[3]));
#pragma unroll
  for (int off = 1; off < 16; off <<= 1) m = fmaxf(m, __shfl_xor(m, off));
  f32x4 ev;
  ev[0] = expf(lv[0] - m); ev[1] = expf(lv[1] - m);
  ev[2] = expf(lv[2] - m); ev[3] = expf(lv[3] - m);
  float ssum = ev[0] + ev[1] + ev[2] + ev[3];
#pragma unroll
  for (int off = 1; off < 16; off <<= 1) ssum += __shfl_xor(ssum, off);
  float inv = 1.f / ssum;
  lg[h][s * 4 + 0] = ev[0] * inv;
  lg[h][s * 4 + 1] = ev[1] * inv;
  lg[h][s * 4 + 2] = ev[2] * inv;
  lg[h][s * 4 + 3] = ev[3] * inv;
  __syncthreads();

  f32x4 acc = {};
#pragma unroll 4
  for (int k = 0; k < 64; ++k) {
    const float* vr = kv + (size_t)iks[k] * 2048 + 1024 + tid * 4;
    f32x4 v = *(const f32x4*)vr;
    acc += splat4(lg[h][k]) * v;
  }

#pragma unroll
  for (int i = 0; i < 4; ++i) {
    float a = acc[i];
    unsigned short hi = f2bf(a);
    unsigned short lo = f2bf(a - bf2f(hi));
    size_t o = ((size_t)l * 1024 + tid * 4 + i) * 3;
    attn_aug[o] = hi; attn_aug[o + 1] = lo; attn_aug[o + 2] = hi;
  }
}

// ---------------- host ----------------
extern "C" void kernel_launch(void* const* d_in, const int* in_sizes, int n_in,
                              void* d_out, int out_size, void* d_ws, size_t ws_size,
                              hipStream_t stream) {
  const float* x          = (const float*)d_in[0];
  const float* idx_in_w   = (const float*)d_in[1];
  const float* idx_conv_w = (const float*)d_in[2];
  const float* idx_conv_b = (const float*)d_in[3];
  const float* idx_dt_b   = (const float*)d_in[4];
  const float* idx_A_log  = (const float*)d_in[5];
  const float* idx_D      = (const float*)d_in[6];
  const float* idx_norm_w = (const float*)d_in[7];
  const float* idx_out_w  = (const float*)d_in[8];
  const float* idx_q_w    = (const float*)d_in[9];
  const float* idx_k_w    = (const float*)d_in[10];
  const float* q_down_w   = (const float*)d_in[11];
  const float* q_up_w     = (const float*)d_in[12];
  const float* q_rope_w   = (const float*)d_in[13];
  const float* kv_down_w  = (const float*)d_in[14];
  const float* kv_up_w    = (const float*)d_in[15];
  const float* k_rope_w   = (const float*)d_in[16];
  const float* out_w      = (const float*)d_in[17];
  float* out = (float*)d_out;

  float* p = (float*)d_ws;
  float* segA = p; p += 4718592;  // zxbcdt[2048x2304] | scores | qbuf
  float* segB = p; p += 2359296;  // xBC | {q_idx, k_idx, c3}
  float* dtb = p; p += 65536;
  float* logdA = p; p += 65536;
  float* lcdb = p; p += 65536;
  int*   idxb = (int*)p; p += 131072;
  float* segD = p; p += 4194304;  // y_ssm+hstate | kvb
  float* segBig1 = p; p += 6291456;  // x_trip | w_outp_aug (after in_proj)
  float* segBig2 = p; p += 7077888;  // w_in_trip | {y_norm|x_aug|q_final}@0, attn_aug@3145728
  float* segH = p; p += 3145728;     // {out_w_T,qwpad,Wq} | k_final
  unsigned short* w_3down_aug = (unsigned short*)p; p += 589824;
  unsigned short* w_qups_aug  = (unsigned short*)p; p += 294912;
  unsigned short* w_kvup_aug  = (unsigned short*)p; p += 393216;
  unsigned short* c_q_aug     = (unsigned short*)p; p += 393216;
  unsigned short* c_kv_aug    = (unsigned short*)p; p += 393216;
  float* Gbuf = p; p += 131072;

  float* zxbcdt = segA;
  float* scores = segA;
  float* qbuf   = segA;
  float* xBC    = segB;
  float* q_idx  = segB;
  float* k_idx  = segB + 131072;
  float* c3     = segB + 262144;
  float* y_ssm  = segD;
  float* hstate = segD + 2097152;
  float* kvb    = segD;
  unsigned short* x_trip     = (unsigned short*)segBig1;  // dead after in_proj
  unsigned short* w_outp_aug = (unsigned short*)segBig1;  // written after in_proj
  unsigned short* w_in_trip  = (unsigned short*)segBig2;  // dead after in_proj
  float* y_norm  = segBig2;                               // gatenorm..q_idx gemm
  unsigned short* x_aug = (unsigned short*)segBig2;       // after topk..down-proj
  float* q_final = segBig2;                               // rope_pack..attn
  unsigned short* attn_aug = (unsigned short*)(segBig2 + 3145728);
  float* out_w_T = segH;
  float* qwpad   = segH + 1048576;
  float* Wq      = segH + 1179648;
  float* k_final = segH;                                  // after q_idx gemm

  dim3 blk(256);
  auto cdiv = [](int a, int b) { return (a + b - 1) / b; };
  auto gemmf3 = [&](const float* A, const float* W, float* C, int M, int N, int K, int S, int tri) {
    dim3 grid(cdiv(N, 128), M / 128, S);
    hipLaunchKernelGGL(gemm_f32_v3, grid, blk, 0, stream, A, W, C, M, N, K, tri);
  };
  auto gemmb = [&](const unsigned short* A, const unsigned short* W, float* C,
                   int M, int N, int K, int lda, int ldb, int ldc, int S) {
    dim3 grid(N / 128, M / 128, S);
    hipLaunchKernelGGL(gemm_bf16_kernel, grid, blk, 0, stream, A, W, C, M, N, K, lda, ldb, ldc);
  };
  auto caugA = [&](const float* s, unsigned short* d, int total, int K, int sld) {
    hipLaunchKernelGGL(conv_augA_kernel, dim3(cdiv(total, 256)), blk, 0, stream, s, d, total, K, sld);
  };
  auto caugW = [&](const float* s, unsigned short* d, int rows, int total, int K, int sld) {
    hipLaunchKernelGGL(conv_augW_kernel, dim3(cdiv(total, 256)), blk, 0, stream, s, d, rows, total, K, sld);
  };

  // ---- weight precomputes ----
  hipLaunchKernelGGL(transpose1024_kernel, dim3(1024), blk, 0, stream, idx_out_w, out_w_T);
  hipMemsetAsync(qwpad, 0, 131072 * 4, stream);
  hipMemcpyAsync(qwpad, idx_q_w, (size_t)64 * 1024 * 4, hipMemcpyDeviceToDevice, stream);
  hipMemsetAsync(Wq, 0, 131072 * 4, stream);
  gemmf3(qwpad, out_w_T, Wq, 128, 1024, 1024, 8, 0);
  // fused x-trip + w-trip expansion (independent, one launch)
  hipLaunchKernelGGL(conv_tripAW_kernel, dim3(cdiv((2048 + 2304) * 1024, 256)), blk, 0, stream,
                     x, x_trip, idx_in_w, w_in_trip);
  caugW(q_down_w,  w_3down_aug,                    128, 128 * 1024, 1024, 1024);
  caugW(kv_down_w, w_3down_aug + 128 * 1024 * 3,   128, 128 * 1024, 1024, 1024);
  caugW(k_rope_w,  w_3down_aug + 256 * 1024 * 3,    32, 128 * 1024, 1024, 1024);
  caugW(q_up_w,    w_qups_aug,                    1024, 1024 * 128, 128, 128);
  caugW(q_rope_w,  w_qups_aug + 1024 * 128 * 3,    512, 512 * 128, 128, 128);
  caugW(kv_up_w,   w_kvup_aug, 2048, 2048 * 128, 128, 128);

  // ---- mamba branch: in_proj via triple-split MFMA (fp32-accurate) ----
  hipMemsetAsync(zxbcdt, 0, (size_t)L * INDIMP * 4, stream);
  gemmb(x_trip, w_in_trip, zxbcdt, 2048, 2304, 6144, 6144, 6144, INDIMP, 4);
  // x_trip dead -> write out-proj weights into segBig1
  caugW(out_w, w_outp_aug, 1024, 1024 * 1024, 1024, 1024);
  hipLaunchKernelGGL(conv_silu_kernel, dim3(cdiv(L * CONVCH, 256)), blk, 0, stream,
                     zxbcdt, idx_conv_w, idx_conv_b, xBC);
  hipLaunchKernelGGL(dt_kernel, dim3(L * MNH / 256), blk, 0, stream,
                     zxbcdt, idx_dt_b, idx_A_log, dtb, logdA);
  hipLaunchKernelGGL(lcd_kernel, dim3(4), blk, 0, stream, logdA, lcdb);
  hipLaunchKernelGGL(chunk_G_kernel, dim3(NCH), blk, 0, stream, xBC, Gbuf);
  hipLaunchKernelGGL(scan_local_kernel, dim3(NCH * MNH), blk, 0, stream,
                     xBC, dtb, lcdb, hstate);
  hipLaunchKernelGGL(scan_combine_kernel, dim3(256), blk, 0, stream, hstate, lcdb);
  hipLaunchKernelGGL(scan_y_kernel, dim3(NCH * MNH), blk, 0, stream,
                     xBC, Gbuf, dtb, lcdb, hstate, y_ssm);
  // y_norm -> segBig2 (w_in_trip dead)
  hipLaunchKernelGGL(gatenorm_kernel, dim3(L), blk, 0, stream,
                     y_ssm, xBC, zxbcdt, idx_D, idx_norm_w, y_norm);

  // ---- index scores + topk (out-proj folded into Wq) ----
  hipMemsetAsync(q_idx, 0, 131072 * 4, stream);
  hipMemsetAsync(k_idx, 0, 131072 * 4, stream);
  // q_idx and k_idx batched into one launch (independent, same shape)
  {
    dim3 grid(1, 16, 32);  // 2 pairs x S=16
    hipLaunchKernelGGL(gemm_f32_dual, grid, blk, 0, stream,
                       y_norm, Wq, q_idx, x, idx_k_w, k_idx, 2048, 64, 1024, 16);
  }
  // scores: tri=1 skips blocks fully above the causal diagonal (never read by topk)
  gemmf3(q_idx, k_idx, scores, 2048, 2048, 64, 1, 1);
  hipLaunchKernelGGL(topk_kernel, dim3(L), blk, 0, stream, scores, idxb);

  // ---- attention value path (aug split-bf16 MFMA) ----
  caugA(x, x_aug, 2048 * 1024, 1024, 1024);  // segBig2@0 (y_norm dead)
  hipMemsetAsync(c3, 0, 786432 * 4, stream);
  gemmb(x_aug, w_3down_aug, c3, 2048, 384, 3072, 3072, 3072, 384, 8);
  // fused c3 -> c_q_aug + c_kv_aug (one launch, one read of c3)
  hipLaunchKernelGGL(conv_augA2_kernel, dim3(cdiv(2048 * 256, 256)), blk, 0, stream,
                     c3, c_q_aug, c_kv_aug);
  gemmb(c_q_aug, w_qups_aug, qbuf, 2048, 1536, 384, 384, 384, 1536, 1);
  gemmb(c_kv_aug, w_kvup_aug, kvb, 2048, 2048, 384, 384, 384, 2048, 1);
  hipLaunchKernelGGL(rope_pack_kernel, dim3(L), dim3(128), 0, stream,
                     qbuf, kvb, c3, q_final, k_final);

  // ---- sparse attention + output projection ----
  hipLaunchKernelGGL(attn_kernel, dim3(L), blk, 0, stream,
                     q_final, k_final, kvb, idxb, attn_aug);
  hipMemsetAsync(out, 0, (size_t)out_size * 4, stream);
  gemmb(attn_aug, w_outp_aug, out, 2048, 1024, 3072, 3072, 3072, 1024, 4);
}

// Round 8
// 661.462 us; speedup vs baseline: 1.1107x; 1.0456x over previous
//
#include <hip/hip_runtime.h>
#include <math.h>

// ---------------- constants ----------------
constexpr int L      = 2048;
constexpr int NH     = 16;
constexpr int DINNER = 1024;
constexpr int MNH    = 32;
constexpr int CONVCH = 1152;
constexpr int INDIMP = 2304;   // padded stride for zxbcdt (2208 -> 2304, N%128)
constexpr int CHUNK  = 64;
constexpr int NCH    = 32;

using bf16x8 = __attribute__((ext_vector_type(8))) short;
using f32x4  = __attribute__((ext_vector_type(4))) float;

__device__ __forceinline__ f32x4 splat4(float x) { return (f32x4){x, x, x, x}; }

__device__ __forceinline__ unsigned short f2bf(float f) {
  unsigned u = __float_as_uint(f);
  return (unsigned short)((u + 0x7fffu + ((u >> 16) & 1u)) >> 16);
}
__device__ __forceinline__ float bf2f(unsigned short h) {
  return __uint_as_float((unsigned)h << 16);
}

// ---------------- fp32 GEMM v3 (small index-critical shapes) ----------------
// tri=1: skip blocks fully above the causal diagonal (outputs never read by topk).
__global__ __launch_bounds__(256) void gemm_f32_v3(
    const float* __restrict__ A, const float* __restrict__ W,
    float* __restrict__ C, int M, int N, int K, int tri) {
  __shared__ float As[16][132];
  __shared__ float Ws[16][132];
  int tid = threadIdx.x;
  int bm = blockIdx.y * 128, bn = blockIdx.x * 128;
  if (tri && bn > bm + 127) return;
  int kper = K / gridDim.z;
  int kb = blockIdx.z * kper, ke = kb + kper;
  int lr = tid >> 1;
  int lh = (tid & 1) * 8;
  int tx = tid & 15, ty = tid >> 4;
  bool wok = (bn + lr < N);
  const float* arow = A + (size_t)(bm + lr) * K + lh;
  const float* wrow = W + (size_t)(bn + lr) * K + lh;
  float4 a0, a1, w0, w1;
  auto gload = [&](int k0) {
    a0 = *(const float4*)(arow + k0);
    a1 = *(const float4*)(arow + k0 + 4);
    w0 = make_float4(0.f, 0.f, 0.f, 0.f); w1 = w0;
    if (wok) {
      w0 = *(const float4*)(wrow + k0);
      w1 = *(const float4*)(wrow + k0 + 4);
    }
  };
  f32x4 acc0[8] = {}, acc1[8] = {};
  gload(kb);
  for (int k0 = kb; k0 < ke; k0 += 16) {
    __syncthreads();
    As[lh+0][lr]=a0.x; As[lh+1][lr]=a0.y; As[lh+2][lr]=a0.z; As[lh+3][lr]=a0.w;
    As[lh+4][lr]=a1.x; As[lh+5][lr]=a1.y; As[lh+6][lr]=a1.z; As[lh+7][lr]=a1.w;
    Ws[lh+0][lr]=w0.x; Ws[lh+1][lr]=w0.y; Ws[lh+2][lr]=w0.z; Ws[lh+3][lr]=w0.w;
    Ws[lh+4][lr]=w1.x; Ws[lh+5][lr]=w1.y; Ws[lh+6][lr]=w1.z; Ws[lh+7][lr]=w1.w;
    __syncthreads();
    if (k0 + 16 < ke) gload(k0 + 16);
#pragma unroll
    for (int kk = 0; kk < 16; ++kk) {
      f32x4 b0 = *(const f32x4*)&Ws[kk][tx * 4];
      f32x4 b1 = *(const f32x4*)&Ws[kk][64 + tx * 4];
      f32x4 al = *(const f32x4*)&As[kk][ty * 8];
      f32x4 ah = *(const f32x4*)&As[kk][ty * 8 + 4];
#pragma unroll
      for (int i = 0; i < 4; ++i) {
        acc0[i]     += splat4(al[i]) * b0;
        acc1[i]     += splat4(al[i]) * b1;
        acc0[i + 4] += splat4(ah[i]) * b0;
        acc1[i + 4] += splat4(ah[i]) * b1;
      }
    }
  }
  bool single = (gridDim.z == 1);
#pragma unroll
  for (int i = 0; i < 8; ++i) {
    int row = bm + ty * 8 + i;
    float* crow = C + (size_t)row * N;
    int c0 = bn + tx * 4, c1 = bn + 64 + tx * 4;
    if (c0 + 3 < N) {
      if (single) *(f32x4*)(crow + c0) = acc0[i];
      else {
        atomicAdd(crow + c0 + 0, acc0[i][0]); atomicAdd(crow + c0 + 1, acc0[i][1]);
        atomicAdd(crow + c0 + 2, acc0[i][2]); atomicAdd(crow + c0 + 3, acc0[i][3]);
      }
    }
    if (c1 + 3 < N) {
      if (single) *(f32x4*)(crow + c1) = acc1[i];
      else {
        atomicAdd(crow + c1 + 0, acc1[i][0]); atomicAdd(crow + c1 + 1, acc1[i][1]);
        atomicAdd(crow + c1 + 2, acc1[i][2]); atomicAdd(crow + c1 + 3, acc1[i][3]);
      }
    }
  }
}

// ---------------- dual fp32 GEMM: two independent same-shape GEMMs in one grid ----------------
__global__ __launch_bounds__(256) void gemm_f32_dual(
    const float* __restrict__ A0, const float* __restrict__ W0, float* __restrict__ C0,
    const float* __restrict__ A1, const float* __restrict__ W1, float* __restrict__ C1,
    int M, int N, int K, int S) {
  __shared__ float As[16][132];
  __shared__ float Ws[16][132];
  int tid = threadIdx.x;
  int bm = blockIdx.y * 128, bn = blockIdx.x * 128;
  int pair = (int)blockIdx.z >= S;
  int zi = blockIdx.z - pair * S;
  const float* A = pair ? A1 : A0;
  const float* W = pair ? W1 : W0;
  float* C = pair ? C1 : C0;
  int kper = K / S;
  int kb = zi * kper, ke = kb + kper;
  int lr = tid >> 1;
  int lh = (tid & 1) * 8;
  int tx = tid & 15, ty = tid >> 4;
  bool wok = (bn + lr < N);
  const float* arow = A + (size_t)(bm + lr) * K + lh;
  const float* wrow = W + (size_t)(bn + lr) * K + lh;
  float4 a0, a1, w0, w1;
  auto gload = [&](int k0) {
    a0 = *(const float4*)(arow + k0);
    a1 = *(const float4*)(arow + k0 + 4);
    w0 = make_float4(0.f, 0.f, 0.f, 0.f); w1 = w0;
    if (wok) {
      w0 = *(const float4*)(wrow + k0);
      w1 = *(const float4*)(wrow + k0 + 4);
    }
  };
  f32x4 acc0[8] = {}, acc1[8] = {};
  gload(kb);
  for (int k0 = kb; k0 < ke; k0 += 16) {
    __syncthreads();
    As[lh+0][lr]=a0.x; As[lh+1][lr]=a0.y; As[lh+2][lr]=a0.z; As[lh+3][lr]=a0.w;
    As[lh+4][lr]=a1.x; As[lh+5][lr]=a1.y; As[lh+6][lr]=a1.z; As[lh+7][lr]=a1.w;
    Ws[lh+0][lr]=w0.x; Ws[lh+1][lr]=w0.y; Ws[lh+2][lr]=w0.z; Ws[lh+3][lr]=w0.w;
    Ws[lh+4][lr]=w1.x; Ws[lh+5][lr]=w1.y; Ws[lh+6][lr]=w1.z; Ws[lh+7][lr]=w1.w;
    __syncthreads();
    if (k0 + 16 < ke) gload(k0 + 16);
#pragma unroll
    for (int kk = 0; kk < 16; ++kk) {
      f32x4 b0 = *(const f32x4*)&Ws[kk][tx * 4];
      f32x4 b1 = *(const f32x4*)&Ws[kk][64 + tx * 4];
      f32x4 al = *(const f32x4*)&As[kk][ty * 8];
      f32x4 ah = *(const f32x4*)&As[kk][ty * 8 + 4];
#pragma unroll
      for (int i = 0; i < 4; ++i) {
        acc0[i]     += splat4(al[i]) * b0;
        acc1[i]     += splat4(al[i]) * b1;
        acc0[i + 4] += splat4(ah[i]) * b0;
        acc1[i + 4] += splat4(ah[i]) * b1;
      }
    }
  }
#pragma unroll
  for (int i = 0; i < 8; ++i) {
    int row = bm + ty * 8 + i;
    float* crow = C + (size_t)row * N;
    int c0 = bn + tx * 4, c1 = bn + 64 + tx * 4;
    if (c0 + 3 < N) {
      atomicAdd(crow + c0 + 0, acc0[i][0]); atomicAdd(crow + c0 + 1, acc0[i][1]);
      atomicAdd(crow + c0 + 2, acc0[i][2]); atomicAdd(crow + c0 + 3, acc0[i][3]);
    }
    if (c1 + 3 < N) {
      atomicAdd(crow + c1 + 0, acc1[i][0]); atomicAdd(crow + c1 + 1, acc1[i][1]);
      atomicAdd(crow + c1 + 2, acc1[i][2]); atomicAdd(crow + c1 + 3, acc1[i][3]);
    }
  }
}

// ---------------- 1024x1024 transpose ----------------
__global__ __launch_bounds__(256) void transpose1024_kernel(
    const float* __restrict__ src, float* __restrict__ dst) {
  __shared__ float t[32][33];
  int bx = blockIdx.x & 31, by = blockIdx.x >> 5;
  int tx = threadIdx.x & 31, ty8 = threadIdx.x >> 5;
  for (int r = ty8; r < 32; r += 8)
    t[r][tx] = src[(size_t)(by * 32 + r) * 1024 + bx * 32 + tx];
  __syncthreads();
  for (int r = ty8; r < 32; r += 8)
    dst[(size_t)(bx * 32 + r) * 1024 + by * 32 + tx] = t[tx][r];
}

// ---------------- bf16 MFMA GEMM (double-buffered LDS: stage(t+1) || compute(t)) ----------------
// T1: XCD-aware (x,y) tile swizzle (identity fallback when nwg%8!=0).
// T3-min: 2-deep pipeline (structure-bound at ~445 TF for the 2048-class shapes).
__global__ __launch_bounds__(256) void gemm_bf16_kernel(
    const unsigned short* __restrict__ A, const unsigned short* __restrict__ W,
    float* __restrict__ C, int M, int N, int K, int lda, int ldb, int ldc) {
  __shared__ unsigned short As[2][128 * 64];
  __shared__ unsigned short Ws[2][128 * 64];
  int tid = threadIdx.x;
  int bx = blockIdx.x, by = blockIdx.y;
  int nxy = gridDim.x * gridDim.y;
  if ((nxy & 7) == 0) {
    int lin = by * gridDim.x + bx;
    int cpx = nxy >> 3;
    int swz = (lin & 7) * cpx + (lin >> 3);
    bx = swz % gridDim.x;
    by = swz / gridDim.x;
  }
  int bm = by * 128, bn = bx * 128;
  int kper = K / gridDim.z;
  int k_begin = blockIdx.z * kper;
  int k_end = k_begin + kper;
  int wv = tid >> 6, lane = tid & 63;
  int wrow = (wv >> 1) * 64, wcol = (wv & 1) * 64;
  int lrow = lane & 15, quad = lane >> 4;

  f32x4 acc[4][4] = {};

  auto stage = [&](int b, int k0) {
#pragma unroll
    for (int it = 0; it < 4; ++it) {
      int s = it * 256 + tid;
      int r = s >> 3;
      int q = (s & 7) ^ (r & 7);
      const unsigned short* ga = A + (size_t)(bm + r) * lda + k0 + q * 8;
      const unsigned short* gw = W + (size_t)(bn + r) * ldb + k0 + q * 8;
      __builtin_amdgcn_global_load_lds((const __attribute__((address_space(1))) void*)ga,
                                       (__attribute__((address_space(3))) void*)&As[b][s * 8], 16, 0, 0);
      __builtin_amdgcn_global_load_lds((const __attribute__((address_space(1))) void*)gw,
                                       (__attribute__((address_space(3))) void*)&Ws[b][s * 8], 16, 0, 0);
    }
  };

  stage(0, k_begin);
  int cur = 0;
  for (int k0 = k_begin; k0 < k_end; k0 += 64) {
    __syncthreads();
    if (k0 + 64 < k_end) stage(cur ^ 1, k0 + 64);
#pragma unroll
    for (int ks = 0; ks < 2; ++ks) {
      bf16x8 af[4], wf[4];
#pragma unroll
      for (int i = 0; i < 4; ++i) {
        int ra = wrow + i * 16 + lrow;
        int qa = (ks * 4 + quad) ^ (ra & 7);
        af[i] = *(const bf16x8*)&As[cur][(ra * 8 + qa) * 8];
        int rw = wcol + i * 16 + lrow;
        int qw = (ks * 4 + quad) ^ (rw & 7);
        wf[i] = *(const bf16x8*)&Ws[cur][(rw * 8 + qw) * 8];
      }
#pragma unroll
      for (int i = 0; i < 4; ++i)
#pragma unroll
        for (int j = 0; j < 4; ++j)
          acc[i][j] = __builtin_amdgcn_mfma_f32_16x16x32_bf16(af[i], wf[j], acc[i][j], 0, 0, 0);
    }
    cur ^= 1;
  }
  bool single = (gridDim.z == 1);
#pragma unroll
  for (int i = 0; i < 4; ++i)
#pragma unroll
    for (int j = 0; j < 4; ++j)
#pragma unroll
      for (int r = 0; r < 4; ++r) {
        int row = bm + wrow + i * 16 + quad * 4 + r;
        int col = bn + wcol + j * 16 + lrow;
        float v = acc[i][j][r];
        if (single) C[(size_t)row * ldc + col] = v;
        else atomicAdd(&C[(size_t)row * ldc + col], v);
      }
}

// ---------------- dual bf16 MFMA GEMM: q_up + kv_up in one launch ----------------
// Same M=2048, K, lda=ldb=ld for both; different N/ldc. bx < nx0 -> pair 0.
// Single-store epilogue (no split-K). Grid: x = nx0 + nx1, y = M/128.
__global__ __launch_bounds__(256) void gemm_bf16_dual(
    const unsigned short* __restrict__ A0, const unsigned short* __restrict__ W0,
    float* __restrict__ C0,
    const unsigned short* __restrict__ A1, const unsigned short* __restrict__ W1,
    float* __restrict__ C1,
    int nx0, int ldc0, int ldc1, int K, int ld) {
  __shared__ unsigned short As[2][128 * 64];
  __shared__ unsigned short Ws[2][128 * 64];
  int tid = threadIdx.x;
  int bx = blockIdx.x, by = blockIdx.y;
  int pair = bx >= nx0;
  int bxl = pair ? bx - nx0 : bx;
  const unsigned short* A = pair ? A1 : A0;
  const unsigned short* W = pair ? W1 : W0;
  float* C = pair ? C1 : C0;
  int ldc = pair ? ldc1 : ldc0;
  int bm = by * 128, bn = bxl * 128;
  int wv = tid >> 6, lane = tid & 63;
  int wrow = (wv >> 1) * 64, wcol = (wv & 1) * 64;
  int lrow = lane & 15, quad = lane >> 4;

  f32x4 acc[4][4] = {};

  auto stage = [&](int b, int k0) {
#pragma unroll
    for (int it = 0; it < 4; ++it) {
      int s = it * 256 + tid;
      int r = s >> 3;
      int q = (s & 7) ^ (r & 7);
      const unsigned short* ga = A + (size_t)(bm + r) * ld + k0 + q * 8;
      const unsigned short* gw = W + (size_t)(bn + r) * ld + k0 + q * 8;
      __builtin_amdgcn_global_load_lds((const __attribute__((address_space(1))) void*)ga,
                                       (__attribute__((address_space(3))) void*)&As[b][s * 8], 16, 0, 0);
      __builtin_amdgcn_global_load_lds((const __attribute__((address_space(1))) void*)gw,
                                       (__attribute__((address_space(3))) void*)&Ws[b][s * 8], 16, 0, 0);
    }
  };

  stage(0, 0);
  int cur = 0;
  for (int k0 = 0; k0 < K; k0 += 64) {
    __syncthreads();
    if (k0 + 64 < K) stage(cur ^ 1, k0 + 64);
#pragma unroll
    for (int ks = 0; ks < 2; ++ks) {
      bf16x8 af[4], wf[4];
#pragma unroll
      for (int i = 0; i < 4; ++i) {
        int ra = wrow + i * 16 + lrow;
        int qa = (ks * 4 + quad) ^ (ra & 7);
        af[i] = *(const bf16x8*)&As[cur][(ra * 8 + qa) * 8];
        int rw = wcol + i * 16 + lrow;
        int qw = (ks * 4 + quad) ^ (rw & 7);
        wf[i] = *(const bf16x8*)&Ws[cur][(rw * 8 + qw) * 8];
      }
#pragma unroll
      for (int i = 0; i < 4; ++i)
#pragma unroll
        for (int j = 0; j < 4; ++j)
          acc[i][j] = __builtin_amdgcn_mfma_f32_16x16x32_bf16(af[i], wf[j], acc[i][j], 0, 0, 0);
    }
    cur ^= 1;
  }
#pragma unroll
  for (int i = 0; i < 4; ++i)
#pragma unroll
    for (int j = 0; j < 4; ++j)
#pragma unroll
      for (int r = 0; r < 4; ++r) {
        int row = bm + wrow + i * 16 + quad * 4 + r;
        int col = bn + wcol + j * 16 + lrow;
        C[(size_t)row * ldc + col] = acc[i][j][r];
      }
}

// ---------------- fused weight-prep: tripA(x) + tripW(idx_in_w) + 6x caugW ----------------
// Linear index space; each region's per-element math identical to the R7 kernels.
// T0=2097152 tripA | T1=4456448 tripW | +393216 3down | +131072 q_up
// | +65536 q_rope | +262144 kv_up  (total 5308416 = 20736 blocks exactly)
__global__ __launch_bounds__(256) void prep_weights_kernel(
    const float* __restrict__ x, unsigned short* __restrict__ x_trip,
    const float* __restrict__ idx_in_w, unsigned short* __restrict__ w_in_trip,
    const float* __restrict__ q_down_w, const float* __restrict__ kv_down_w,
    const float* __restrict__ k_rope_w, unsigned short* __restrict__ w3down,
    const float* __restrict__ q_up_w, const float* __restrict__ q_rope_w,
    unsigned short* __restrict__ wqups,
    const float* __restrict__ kv_up_w, unsigned short* __restrict__ wkvup) {
  int i = blockIdx.x * 256 + threadIdx.x;
  if (i < 2097152) {
    // tripA: A=[h,m,l,h,m,h]
    float f = x[i];
    unsigned short h = f2bf(f);
    float r1 = f - bf2f(h);
    unsigned short m = f2bf(r1);
    unsigned short l = f2bf(r1 - bf2f(m));
    size_t o = (size_t)i * 6;
    x_trip[o] = h; x_trip[o + 1] = m; x_trip[o + 2] = l;
    x_trip[o + 3] = h; x_trip[o + 4] = m; x_trip[o + 5] = h;
  } else if (i < 4456448) {
    // tripW: W=[h,h,h,m,m,l], 2304 padded rows (2208 real)
    int j = i - 2097152;
    int n = j >> 10, k = j & 1023;
    unsigned short h = 0, m = 0, l = 0;
    if (n < 2208) {
      float f = idx_in_w[(size_t)n * 1024 + k];
      h = f2bf(f);
      float r1 = f - bf2f(h);
      m = f2bf(r1);
      l = f2bf(r1 - bf2f(m));
    }
    size_t o = (size_t)j * 6;
    w_in_trip[o] = h; w_in_trip[o + 1] = h; w_in_trip[o + 2] = h;
    w_in_trip[o + 3] = m; w_in_trip[o + 4] = m; w_in_trip[o + 5] = l;
  } else {
    int j2 = i - 4456448;
    const float* src; unsigned short* dst; int rows, K; size_t obase; int idx;
    if (j2 < 393216) {
      int r = j2 >> 17;               // 131072 = 2^17
      idx = j2 & 131071;
      K = 1024;
      src = (r == 0) ? q_down_w : (r == 1) ? kv_down_w : k_rope_w;
      rows = (r == 2) ? 32 : 128;
      dst = w3down; obase = (size_t)(r * 131072 + idx) * 3;
    } else if (j2 < 524288) {
      idx = j2 - 393216; K = 128; src = q_up_w; rows = 1024;
      dst = wqups; obase = (size_t)idx * 3;
    } else if (j2 < 589824) {
      idx = j2 - 524288; K = 128; src = q_rope_w; rows = 512;
      dst = wqups; obase = (size_t)393216 + (size_t)idx * 3;
    } else {
      idx = j2 - 589824; K = 128; src = kv_up_w; rows = 2048;
      dst = wkvup; obase = (size_t)idx * 3;
    }
    int n = idx / K, k = idx - n * K;
    unsigned short hi = 0, lo = 0;
    if (n < rows) {
      float f = src[(size_t)n * K + k];
      hi = f2bf(f);
      lo = f2bf(f - bf2f(hi));
    }
    dst[obase] = hi; dst[obase + 1] = hi; dst[obase + 2] = lo;
  }
}

// ---------------- fused post-in_proj: caugW(out_w) + conv_silu + dt ----------------
// U0=1048576 out_w aug | U1=3407872 conv_silu | U2=3473408 dt  (13568 blocks exactly)
__global__ __launch_bounds__(256) void post_inproj_kernel(
    const float* __restrict__ out_w, unsigned short* __restrict__ w_outp,
    const float* __restrict__ zxbcdt, const float* __restrict__ conv_w,
    const float* __restrict__ conv_b, float* __restrict__ xBC,
    const float* __restrict__ dt_bias, const float* __restrict__ A_log,
    float* __restrict__ dt, float* __restrict__ logdA) {
  int i = blockIdx.x * 256 + threadIdx.x;
  if (i < 1048576) {
    // caugW out_w: rows=1024, K=1024, all valid; W=[h,h,l]
    float f = out_w[i];
    unsigned short hi = f2bf(f);
    unsigned short lo = f2bf(f - bf2f(hi));
    size_t o = (size_t)i * 3;
    w_outp[o] = hi; w_outp[o + 1] = hi; w_outp[o + 2] = lo;
  } else if (i < 3407872) {
    int idx = i - 1048576;
    int l = idx / CONVCH, c = idx - l * CONVCH;
    float acc = conv_b[c];
#pragma unroll
    for (int k = 0; k < 4; ++k) {
      int ls = l - 3 + k;
      if (ls >= 0) acc += zxbcdt[(size_t)ls * INDIMP + DINNER + c] * conv_w[c * 4 + k];
    }
    xBC[idx] = acc / (1.f + expf(-acc));
  } else {
    int idx = i - 3407872;   // < 65536
    int l = idx >> 5, h = idx & 31;
    float xv = zxbcdt[(size_t)l * INDIMP + 2176 + h] + dt_bias[h];
    float sp = fmaxf(xv, 0.f) + log1pf(expf(-fabsf(xv)));
    dt[idx] = sp;
    logdA[idx] = sp * -expf(A_log[h]);
  }
}

// ---------------- conversions ----------------
// 3-slot aug (value path): A=[h,l,h]
__global__ __launch_bounds__(256) void conv_augA_kernel(
    const float* __restrict__ src, unsigned short* __restrict__ dst,
    int total, int K, int sld) {
  int i = blockIdx.x * 256 + threadIdx.x;
  if (i >= total) return;
  int m = i / K, k = i - m * K;
  float f = src[(size_t)m * sld + k];
  unsigned short hi = f2bf(f);
  unsigned short lo = f2bf(f - bf2f(hi));
  size_t o = ((size_t)m * K + k) * 3;
  dst[o] = hi; dst[o + 1] = lo; dst[o + 2] = hi;
}
// fused c3 -> c_q_aug (cols 0..127) + c_kv_aug (cols 128..255), one read of c3
__global__ __launch_bounds__(256) void conv_augA2_kernel(
    const float* __restrict__ c3, unsigned short* __restrict__ dq,
    unsigned short* __restrict__ dkv) {
  int i = blockIdx.x * 256 + threadIdx.x;
  if (i >= 2048 * 256) return;
  int m = i >> 8, k = i & 255;
  float f = c3[(size_t)m * 384 + k];
  unsigned short hi = f2bf(f);
  unsigned short lo = f2bf(f - bf2f(hi));
  if (k < 128) {
    size_t o = ((size_t)m * 128 + k) * 3;
    dq[o] = hi; dq[o + 1] = lo; dq[o + 2] = hi;
  } else {
    size_t o = ((size_t)m * 128 + (k - 128)) * 3;
    dkv[o] = hi; dkv[o + 1] = lo; dkv[o + 2] = hi;
  }
}

// ---------------- lcd ----------------
__global__ __launch_bounds__(256) void lcd_kernel(
    const float* __restrict__ logdA, float* __restrict__ lcd) {
  int i = blockIdx.x * 256 + threadIdx.x;
  if (i >= NCH * MNH) return;
  int c = i >> 5, h = i & 31;
  float s = 0.f;
  for (int t = 0; t < CHUNK; ++t) {
    s += logdA[(c * CHUNK + t) * MNH + h];
    lcd[(size_t)i * CHUNK + t] = s;
  }
}

// ---------------- G[c][t][s] = C_t . B_s ----------------
__global__ __launch_bounds__(256) void chunk_G_kernel(
    const float* __restrict__ xBC, float* __restrict__ G) {
  int c = blockIdx.x, tid = threadIdx.x;
  __shared__ float BsT[64][68];
  __shared__ float Cs[64][65];
  int t = tid >> 2, q = tid & 3;
  const float* row = xBC + (size_t)(c * 64 + t) * CONVCH + DINNER;
#pragma unroll
  for (int j = 0; j < 16; j += 4) {
    float4 b = *(const float4*)(row + q * 16 + j);
    BsT[q * 16 + j + 0][t] = b.x; BsT[q * 16 + j + 1][t] = b.y;
    BsT[q * 16 + j + 2][t] = b.z; BsT[q * 16 + j + 3][t] = b.w;
    float4 cv = *(const float4*)(row + 64 + q * 16 + j);
    Cs[t][q * 16 + j + 0] = cv.x; Cs[t][q * 16 + j + 1] = cv.y;
    Cs[t][q * 16 + j + 2] = cv.z; Cs[t][q * 16 + j + 3] = cv.w;
  }
  __syncthreads();
  int s0 = q * 16;
  f32x4 g0 = {}, g1 = {}, g2 = {}, g3 = {};
  for (int n = 0; n < 64; ++n) {
    f32x4 cv = splat4(Cs[t][n]);
    g0 += cv * *(const f32x4*)&BsT[n][s0];
    g1 += cv * *(const f32x4*)&BsT[n][s0 + 4];
    g2 += cv * *(const f32x4*)&BsT[n][s0 + 8];
    g3 += cv * *(const f32x4*)&BsT[n][s0 + 12];
  }
  float* gp = G + ((size_t)c * 64 + t) * 64 + s0;
  *(f32x4*)gp = g0; *(f32x4*)(gp + 4) = g1; *(f32x4*)(gp + 8) = g2; *(f32x4*)(gp + 12) = g3;
}

// ---------------- scan pass A ----------------
__global__ __launch_bounds__(256) void scan_local_kernel(
    const float* __restrict__ xBC, const float* __restrict__ dt,
    const float* __restrict__ lcd, float* __restrict__ hstate) {
  int c = blockIdx.x >> 5, h = blockIdx.x & 31;
  int tid = threadIdx.x;
  __shared__ float Bs[64][68];
  __shared__ float xss[64][36];
  __shared__ float w2s[64];
  int t0 = c * CHUNK;
  int t = tid >> 2, q = tid & 3;
  const float* row = xBC + (size_t)(t0 + t) * CONVCH;
#pragma unroll
  for (int j = 0; j < 16; j += 4)
    *(float4*)&Bs[t][q * 16 + j] = *(const float4*)(row + DINNER + q * 16 + j);
  if (q < 2) {
#pragma unroll
    for (int j = 0; j < 16; j += 4)
      *(float4*)&xss[t][q * 16 + j] = *(const float4*)(row + h * 32 + q * 16 + j);
  }
  if (tid < 64) {
    const float* lc = lcd + ((size_t)c * 32 + h) * CHUNK;
    w2s[tid] = expf(lc[63] - lc[tid]) * dt[(t0 + tid) * MNH + h];
  }
  __syncthreads();
  int n = tid >> 2, pg = (tid & 3) * 8;
  f32x4 h0 = {}, h1 = {};
  for (int s = 0; s < 64; ++s) {
    f32x4 wb = splat4(w2s[s] * Bs[s][n]);
    h0 += wb * *(const f32x4*)&xss[s][pg];
    h1 += wb * *(const f32x4*)&xss[s][pg + 4];
  }
  float* hp = hstate + ((size_t)c * 32 + h) * 2048 + n * 32 + pg;
  *(f32x4*)hp = h0; *(f32x4*)(hp + 4) = h1;
}

// ---------------- scan pass B ----------------
__global__ __launch_bounds__(256) void scan_combine_kernel(
    float* __restrict__ hstate, const float* __restrict__ lcd) {
  int i = blockIdx.x * 256 + threadIdx.x;
  int h = i >> 11;
  float H = 0.f;
  for (int c = 0; c < NCH; ++c) {
    float hl = hstate[(size_t)c * 65536 + i];
    hstate[(size_t)c * 65536 + i] = H;
    float P = expf(lcd[((size_t)c * 32 + h) * CHUNK + CHUNK - 1]);
    H = H * P + hl;
  }
}

// ---------------- scan pass C ----------------
__global__ __launch_bounds__(256) void scan_y_kernel(
    const float* __restrict__ xBC, const float* __restrict__ G,
    const float* __restrict__ dt, const float* __restrict__ lcd,
    const float* __restrict__ hstate, float* __restrict__ y) {
  int c = blockIdx.x >> 5, h = blockIdx.x & 31;
  int tid = threadIdx.x;
  __shared__ float Ms[64][65];
  __shared__ float Cs[64][65];
  __shared__ float xss[64][36];
  __shared__ float Hss[64][36];
  __shared__ float lcds[64], dts[64];
  int t0 = c * CHUNK;
  int t = tid >> 2, q = tid & 3;
  const float* row = xBC + (size_t)(t0 + t) * CONVCH;
#pragma unroll
  for (int j = 0; j < 16; j += 4) {
    float4 cv = *(const float4*)(row + DINNER + 64 + q * 16 + j);
    Cs[t][q * 16 + j + 0] = cv.x; Cs[t][q * 16 + j + 1] = cv.y;
    Cs[t][q * 16 + j + 2] = cv.z; Cs[t][q * 16 + j + 3] = cv.w;
  }
  if (q < 2) {
#pragma unroll
    for (int j = 0; j < 16; j += 4)
      *(float4*)&xss[t][q * 16 + j] = *(const float4*)(row + h * 32 + q * 16 + j);
  }
  {
    const float* gp = G + ((size_t)c * 64 + t) * 64 + q * 16;
#pragma unroll
    for (int j = 0; j < 16; j += 4) {
      float4 g = *(const float4*)(gp + j);
      Ms[t][q * 16 + j + 0] = g.x; Ms[t][q * 16 + j + 1] = g.y;
      Ms[t][q * 16 + j + 2] = g.z; Ms[t][q * 16 + j + 3] = g.w;
    }
  }
  {
    const float* hp = hstate + ((size_t)c * 32 + h) * 2048 + tid * 8;
    int n = tid >> 2, p0 = (tid & 3) * 8;
    *(float4*)&Hss[n][p0]     = *(const float4*)hp;
    *(float4*)&Hss[n][p0 + 4] = *(const float4*)(hp + 4);
  }
  if (tid < 64) {
    lcds[tid] = lcd[((size_t)c * 32 + h) * CHUNK + tid];
    dts[tid]  = dt[(t0 + tid) * MNH + h];
  }
  __syncthreads();
  {
    int s0 = q * 16;
#pragma unroll
    for (int j = 0; j < 16; ++j) {
      int s = s0 + j;
      float m = (s <= t) ? expf(lcds[t] - lcds[s]) * dts[s] * Ms[t][s] : 0.f;
      Ms[t][s] = m;
    }
  }
  __syncthreads();
  int pg = q * 8;
  f32x4 y0 = {}, y1 = {}, a0 = {}, a1 = {};
  for (int s = 0; s < 64; ++s) {
    f32x4 m = splat4(Ms[t][s]);
    y0 += m * *(const f32x4*)&xss[s][pg];
    y1 += m * *(const f32x4*)&xss[s][pg + 4];
  }
  for (int n = 0; n < 64; ++n) {
    f32x4 cn = splat4(Cs[t][n]);
    a0 += cn * *(const f32x4*)&Hss[n][pg];
    a1 += cn * *(const f32x4*)&Hss[n][pg + 4];
  }
  f32x4 cd = splat4(expf(lcds[t]));
  y0 += cd * a0; y1 += cd * a1;
  float* yp = y + (size_t)(t0 + t) * DINNER + h * 32 + pg;
  *(f32x4*)yp = y0; *(f32x4*)(yp + 4) = y1;
}

// ---------------- gate + RMSNorm ----------------
__global__ __launch_bounds__(256) void gatenorm_kernel(
    const float* __restrict__ y_ssm, const float* __restrict__ xBC,
    const float* __restrict__ zxbcdt, const float* __restrict__ Dv,
    const float* __restrict__ norm_w, float* __restrict__ out) {
  int l = blockIdx.x, tid = threadIdx.x;
  float vals[4];
  float ss = 0.f;
#pragma unroll
  for (int i = 0; i < 4; ++i) {
    int d = tid + i * 256;
    int h = d >> 5;
    float v = y_ssm[(size_t)l * DINNER + d] + Dv[h] * xBC[(size_t)l * CONVCH + d];
    float z = zxbcdt[(size_t)l * INDIMP + d];
    v *= z / (1.f + expf(-z));
    vals[i] = v;
    ss += v * v;
  }
#pragma unroll
  for (int off = 32; off > 0; off >>= 1) ss += __shfl_xor(ss, off);
  __shared__ float sred[4];
  if ((tid & 63) == 0) sred[tid >> 6] = ss;
  __syncthreads();
  float tot = sred[0] + sred[1] + sred[2] + sred[3];
  float scale = rsqrtf(tot * (1.f / 1024.f) + 1e-5f);
#pragma unroll
  for (int i = 0; i < 4; ++i) {
    int d = tid + i * 256;
    out[(size_t)l * DINNER + d] = vals[i] * scale * norm_w[d];
  }
}

// ---------------- per-row top-64 radix select (R4-verified global-scan) ----------------
__global__ __launch_bounds__(256) void topk_kernel(
    const float* __restrict__ scores, int* __restrict__ out_idx) {
  int l = blockIdx.x, tid = threadIdx.x;
  if (l < 64) {
    if (tid < 64) out_idx[l * 64 + tid] = tid;
    return;
  }
  int n = l + 1;
  const float* row = scores + (size_t)l * L;
  __shared__ int hist[256];
  __shared__ unsigned sel_prefix;
  __shared__ int sel_remaining;
  __shared__ int cnt_g, cnt_e;
  __shared__ int eq_list[128];
  if (tid == 0) { cnt_g = 0; cnt_e = 0; }
  unsigned prefix = 0;
  int remaining = 64;
  for (int pass = 0; pass < 4; ++pass) {
    int shift = 24 - 8 * pass;
    unsigned himask = (pass == 0) ? 0u : (0xFFFFFFFFu << (shift + 8));
    hist[tid] = 0;
    __syncthreads();
    for (int j = tid; j < n; j += 256) {
      unsigned u = __float_as_uint(row[j]);
      unsigned key = (u & 0x80000000u) ? ~u : (u | 0x80000000u);
      if (((key ^ prefix) & himask) == 0)
        atomicAdd(&hist[(key >> shift) & 255], 1);
    }
    __syncthreads();
    if (tid == 0) {
      int cum = 0, b = 255;
      for (; b >= 0; --b) {
        cum += hist[b];
        if (cum >= remaining) break;
      }
      sel_prefix = prefix | ((unsigned)b << shift);
      sel_remaining = remaining - (cum - hist[b]);
    }
    __syncthreads();
    prefix = sel_prefix;
    remaining = sel_remaining;
    __syncthreads();
  }
  unsigned T = prefix;
  for (int j = tid; j < n; j += 256) {
    unsigned u = __float_as_uint(row[j]);
    unsigned key = (u & 0x80000000u) ? ~u : (u | 0x80000000u);
    if (key > T) {
      int p = atomicAdd(&cnt_g, 1);
      out_idx[l * 64 + p] = j;
    } else if (key == T) {
      int p = atomicAdd(&cnt_e, 1);
      if (p < 128) eq_list[p] = j;
    }
  }
  __syncthreads();
  if (tid == 0) {
    int G = cnt_g;
    int E = remaining;
    int m = cnt_e < 128 ? cnt_e : 128;
    for (int e = 0; e < E; ++e) {
      int best = 0, bj = 0x7fffffff;
      for (int i = 0; i < m; ++i)
        if (eq_list[i] < bj) { bj = eq_list[i]; best = i; }
      out_idx[l * 64 + G + e] = bj;
      eq_list[best] = 0x7fffffff;
    }
  }
}

// ---------------- RoPE + pack q_final/k_final (fused-buffer strides) ----------------
__global__ __launch_bounds__(128) void rope_pack_kernel(
    const float* __restrict__ qbuf, const float* __restrict__ kv,
    const float* __restrict__ c3,
    float* __restrict__ q_final, float* __restrict__ k_final) {
  int l = blockIdx.x, tid = threadIdx.x;
  __shared__ float s_s[16], s_c[16];
  if (tid < 16) {
    float inv = powf(10000.f, -(float)tid / 16.f);
    float ang = (float)l * inv;
    s_s[tid] = sinf(ang);
    s_c[tid] = cosf(ang);
  }
  __syncthreads();
  const float* qrow = qbuf + (size_t)l * 1536;
  const float* krow = c3 + (size_t)l * 384 + 256;
  for (int e = tid; e < NH * 96; e += 128) {
    int hh = e / 96, d = e - hh * 96;
    float qv, kvv;
    if (d < 64) {
      qv  = qrow[hh * 64 + d];
      kvv = kv[(size_t)l * 2048 + hh * 64 + d];
    } else {
      int r = d - 64;
      if (r < 16) {
        float q1 = qrow[1024 + hh * 32 + r];
        float q2 = qrow[1024 + hh * 32 + 16 + r];
        qv = q1 * s_c[r] - q2 * s_s[r];
        float k1 = krow[r];
        float k2 = krow[16 + r];
        kvv = k1 * s_c[r] - k2 * s_s[r];
      } else {
        int rr = r - 16;
        float q1 = qrow[1024 + hh * 32 + rr];
        float q2 = qrow[1024 + hh * 32 + 16 + rr];
        qv = q1 * s_s[rr] + q2 * s_c[rr];
        float k1 = krow[rr];
        float k2 = krow[16 + rr];
        kvv = k1 * s_s[rr] + k2 * s_c[rr];
      }
    }
    q_final[(size_t)l * 1536 + e] = qv;
    k_final[(size_t)l * 1536 + e] = kvv;
  }
}

// ---------------- sparse attention (coalesced, one block per row) ----------------
__global__ __launch_bounds__(256) void attn_kernel(
    const float* __restrict__ q_final, const float* __restrict__ k_final,
    const float* __restrict__ kv, const int* __restrict__ idx,
    unsigned short* __restrict__ attn_aug) {
  int l = blockIdx.x;
  int tid = threadIdx.x;
  int h = tid >> 4;
  int s = tid & 15;
  __shared__ __align__(16) float lg[16][64];
  __shared__ int iks[64];

  if (tid < 64) iks[tid] = idx[l * 64 + tid];

  const float* qrow = q_final + (size_t)l * 1536 + h * 96 + s * 2;
  float q0 = qrow[0],  q1 = qrow[1];
  float q2 = qrow[32], q3 = qrow[33];
  float q4 = qrow[64], q5 = qrow[65];
  __syncthreads();

#pragma unroll 4
  for (int k = 0; k < 64; ++k) {
    const float* kr = k_final + (size_t)iks[k] * 1536 + h * 96 + s * 2;
    float2 a = *(const float2*)kr;
    float2 b = *(const float2*)(kr + 32);
    float2 c = *(const float2*)(kr + 64);
    float d = q0 * a.x + q1 * a.y + q2 * b.x + q3 * b.y + q4 * c.x + q5 * c.y;
    d += __shfl_xor(d, 1);
    d += __shfl_xor(d, 2);
    d += __shfl_xor(d, 4);
    d += __shfl_xor(d, 8);
    if (s == 0) lg[h][k] = d * 0.10206207261596575f;
  }
  __syncthreads();

  f32x4 lv = *(const f32x4*)&lg[h][s * 4];
  float m = fmaxf(fmaxf(lv[0], lv[1]), fmaxf(lv[2], lv[3]));
#pragma unroll
  for (int off = 1; off < 16; off <<= 1) m = fmaxf(m, __shfl_xor(m, off));
  f32x4 ev;
  ev[0] = expf(lv[0] - m); ev[1] = expf(lv[1] - m);
  ev[2] = expf(lv[2] - m); ev[3] = expf(lv[3] - m);
  float ssum = ev[0] + ev[1] + ev[2] + ev[3];
#pragma unroll
  for (int off = 1; off < 16; off <<= 1) ssum += __shfl_xor(ssum, off);
  float inv = 1.f / ssum;
  lg[h][s * 4 + 0] = ev[0] * inv;
  lg[h][s * 4 + 1] = ev[1] * inv;
  lg[h][s * 4 + 2] = ev[2] * inv;
  lg[h][s * 4 + 3] = ev[3] * inv;
  __syncthreads();

  f32x4 acc = {};
#pragma unroll 4
  for (int k = 0; k < 64; ++k) {
    const float* vr = kv + (size_t)iks[k] * 2048 + 1024 + tid * 4;
    f32x4 v = *(const f32x4*)vr;
    acc += splat4(lg[h][k]) * v;
  }

#pragma unroll
  for (int i = 0; i < 4; ++i) {
    float a = acc[i];
    unsigned short hi = f2bf(a);
    unsigned short lo = f2bf(a - bf2f(hi));
    size_t o = ((size_t)l * 1024 + tid * 4 + i) * 3;
    attn_aug[o] = hi; attn_aug[o + 1] = lo; attn_aug[o + 2] = hi;
  }
}

// ---------------- host ----------------
extern "C" void kernel_launch(void* const* d_in, const int* in_sizes, int n_in,
                              void* d_out, int out_size, void* d_ws, size_t ws_size,
                              hipStream_t stream) {
  const float* x          = (const float*)d_in[0];
  const float* idx_in_w   = (const float*)d_in[1];
  const float* idx_conv_w = (const float*)d_in[2];
  const float* idx_conv_b = (const float*)d_in[3];
  const float* idx_dt_b   = (const float*)d_in[4];
  const float* idx_A_log  = (const float*)d_in[5];
  const float* idx_D      = (const float*)d_in[6];
  const float* idx_norm_w = (const float*)d_in[7];
  const float* idx_out_w  = (const float*)d_in[8];
  const float* idx_q_w    = (const float*)d_in[9];
  const float* idx_k_w    = (const float*)d_in[10];
  const float* q_down_w   = (const float*)d_in[11];
  const float* q_up_w     = (const float*)d_in[12];
  const float* q_rope_w   = (const float*)d_in[13];
  const float* kv_down_w  = (const float*)d_in[14];
  const float* kv_up_w    = (const float*)d_in[15];
  const float* k_rope_w   = (const float*)d_in[16];
  const float* out_w      = (const float*)d_in[17];
  float* out = (float*)d_out;

  float* p = (float*)d_ws;
  float* segA = p; p += 4718592;  // zxbcdt[2048x2304] | scores | qbuf
  float* segB = p; p += 2359296;  // xBC | {q_idx, k_idx, c3}
  float* dtb = p; p += 65536;
  float* logdA = p; p += 65536;
  float* lcdb = p; p += 65536;
  int*   idxb = (int*)p; p += 131072;
  float* segD = p; p += 4194304;  // y_ssm+hstate | kvb
  float* segBig1 = p; p += 6291456;  // x_trip | w_outp_aug (after in_proj)
  float* segBig2 = p; p += 7077888;  // w_in_trip | {y_norm|x_aug|q_final}@0, attn_aug@3145728
  float* segH = p; p += 3145728;     // {out_w_T,qwpad,Wq} | k_final
  unsigned short* w_3down_aug = (unsigned short*)p; p += 589824;
  unsigned short* w_qups_aug  = (unsigned short*)p; p += 294912;
  unsigned short* w_kvup_aug  = (unsigned short*)p; p += 393216;
  unsigned short* c_q_aug     = (unsigned short*)p; p += 393216;
  unsigned short* c_kv_aug    = (unsigned short*)p; p += 393216;
  float* Gbuf = p; p += 131072;

  float* zxbcdt = segA;
  float* scores = segA;
  float* qbuf   = segA;
  float* xBC    = segB;
  float* q_idx  = segB;
  float* k_idx  = segB + 131072;
  float* c3     = segB + 262144;
  float* y_ssm  = segD;
  float* hstate = segD + 2097152;
  float* kvb    = segD;
  unsigned short* x_trip     = (unsigned short*)segBig1;  // dead after in_proj
  unsigned short* w_outp_aug = (unsigned short*)segBig1;  // written after in_proj
  unsigned short* w_in_trip  = (unsigned short*)segBig2;  // dead after in_proj
  float* y_norm  = segBig2;                               // gatenorm..q_idx gemm
  unsigned short* x_aug = (unsigned short*)segBig2;       // after topk..down-proj
  float* q_final = segBig2;                               // rope_pack..attn
  unsigned short* attn_aug = (unsigned short*)(segBig2 + 3145728);
  float* out_w_T = segH;
  float* qwpad   = segH + 1048576;
  float* Wq      = segH + 1179648;
  float* k_final = segH;                                  // after q_idx gemm

  dim3 blk(256);
  auto cdiv = [](int a, int b) { return (a + b - 1) / b; };
  auto gemmf3 = [&](const float* A, const float* W, float* C, int M, int N, int K, int S, int tri) {
    dim3 grid(cdiv(N, 128), M / 128, S);
    hipLaunchKernelGGL(gemm_f32_v3, grid, blk, 0, stream, A, W, C, M, N, K, tri);
  };
  auto gemmb = [&](const unsigned short* A, const unsigned short* W, float* C,
                   int M, int N, int K, int lda, int ldb, int ldc, int S) {
    dim3 grid(N / 128, M / 128, S);
    hipLaunchKernelGGL(gemm_bf16_kernel, grid, blk, 0, stream, A, W, C, M, N, K, lda, ldb, ldc);
  };

  // ---- weight precomputes ----
  hipLaunchKernelGGL(transpose1024_kernel, dim3(1024), blk, 0, stream, idx_out_w, out_w_T);
  hipMemsetAsync(qwpad, 0, 262144 * 4, stream);   // qwpad + adjacent Wq in one memset
  hipMemcpyAsync(qwpad, idx_q_w, (size_t)64 * 1024 * 4, hipMemcpyDeviceToDevice, stream);
  gemmf3(qwpad, out_w_T, Wq, 128, 1024, 1024, 8, 0);
  // fused: tripA(x) + tripW(idx_in_w) + 6x caugW weight conversions, one launch
  hipLaunchKernelGGL(prep_weights_kernel, dim3(20736), blk, 0, stream,
                     x, x_trip, idx_in_w, w_in_trip,
                     q_down_w, kv_down_w, k_rope_w, w_3down_aug,
                     q_up_w, q_rope_w, w_qups_aug, kv_up_w, w_kvup_aug);

  // ---- mamba branch: in_proj via triple-split MFMA (fp32-accurate) ----
  hipMemsetAsync(zxbcdt, 0, (size_t)L * INDIMP * 4, stream);
  gemmb(x_trip, w_in_trip, zxbcdt, 2048, 2304, 6144, 6144, 6144, INDIMP, 4);
  // fused: caugW(out_w -> segBig1, x_trip dead) + conv_silu + dt, one launch
  hipLaunchKernelGGL(post_inproj_kernel, dim3(13568), blk, 0, stream,
                     out_w, w_outp_aug, zxbcdt, idx_conv_w, idx_conv_b, xBC,
                     idx_dt_b, idx_A_log, dtb, logdA);
  hipLaunchKernelGGL(lcd_kernel, dim3(4), blk, 0, stream, logdA, lcdb);
  hipLaunchKernelGGL(chunk_G_kernel, dim3(NCH), blk, 0, stream, xBC, Gbuf);
  hipLaunchKernelGGL(scan_local_kernel, dim3(NCH * MNH), blk, 0, stream,
                     xBC, dtb, lcdb, hstate);
  hipLaunchKernelGGL(scan_combine_kernel, dim3(256), blk, 0, stream, hstate, lcdb);
  hipLaunchKernelGGL(scan_y_kernel, dim3(NCH * MNH), blk, 0, stream,
                     xBC, Gbuf, dtb, lcdb, hstate, y_ssm);
  hipLaunchKernelGGL(gatenorm_kernel, dim3(L), blk, 0, stream,
                     y_ssm, xBC, zxbcdt, idx_D, idx_norm_w, y_norm);

  // ---- index scores + topk (out-proj folded into Wq) ----
  hipMemsetAsync(q_idx, 0, 262144 * 4, stream);   // q_idx + adjacent k_idx in one memset
  {
    dim3 grid(1, 16, 32);  // 2 pairs x S=16
    hipLaunchKernelGGL(gemm_f32_dual, grid, blk, 0, stream,
                       y_norm, Wq, q_idx, x, idx_k_w, k_idx, 2048, 64, 1024, 16);
  }
  gemmf3(q_idx, k_idx, scores, 2048, 2048, 64, 1, 1);
  hipLaunchKernelGGL(topk_kernel, dim3(L), blk, 0, stream, scores, idxb);

  // ---- attention value path (aug split-bf16 MFMA) ----
  hipLaunchKernelGGL(conv_augA_kernel, dim3(cdiv(2048 * 1024, 256)), blk, 0, stream,
                     x, x_aug, 2048 * 1024, 1024, 1024);  // segBig2@0 (y_norm dead)
  hipMemsetAsync(c3, 0, 786432 * 4, stream);
  gemmb(x_aug, w_3down_aug, c3, 2048, 384, 3072, 3072, 3072, 384, 8);
  hipLaunchKernelGGL(conv_augA2_kernel, dim3(cdiv(2048 * 256, 256)), blk, 0, stream,
                     c3, c_q_aug, c_kv_aug);
  // fused: q_up (N=1536) + kv_up (N=2048) in one 28x16 launch
  {
    dim3 grid(28, 16, 1);
    hipLaunchKernelGGL(gemm_bf16_dual, grid, blk, 0, stream,
                       c_q_aug, w_qups_aug, qbuf,
                       c_kv_aug, w_kvup_aug, kvb,
                       12, 1536, 2048, 384, 384);
  }
  hipLaunchKernelGGL(rope_pack_kernel, dim3(L), dim3(128), 0, stream,
                     qbuf, kvb, c3, q_final, k_final);

  // ---- sparse attention + output projection ----
  hipLaunchKernelGGL(attn_kernel, dim3(L), blk, 0, stream,
                     q_final, k_final, kvb, idxb, attn_aug);
  hipMemsetAsync(out, 0, (size_t)out_size * 4, stream);
  gemmb(attn_aug, w_outp_aug, out, 2048, 1024, 3072, 3072, 3072, 1024, 4);
}

// Round 9
// 645.767 us; speedup vs baseline: 1.1377x; 1.0243x over previous
//
#include <hip/hip_runtime.h>
#include <math.h>

// ---------------- constants ----------------
constexpr int L      = 2048;
constexpr int NH     = 16;
constexpr int DINNER = 1024;
constexpr int MNH    = 32;
constexpr int CONVCH = 1152;
constexpr int INDIMP = 2304;   // padded stride for zxbcdt (2208 -> 2304, N%128)
constexpr int CHUNK  = 64;
constexpr int NCH    = 32;

using bf16x8 = __attribute__((ext_vector_type(8))) short;
using f32x4  = __attribute__((ext_vector_type(4))) float;

__device__ __forceinline__ f32x4 splat4(float x) { return (f32x4){x, x, x, x}; }

__device__ __forceinline__ unsigned short f2bf(float f) {
  unsigned u = __float_as_uint(f);
  return (unsigned short)((u + 0x7fffu + ((u >> 16) & 1u)) >> 16);
}
__device__ __forceinline__ float bf2f(unsigned short h) {
  return __uint_as_float((unsigned)h << 16);
}

// ---------------- fp32 GEMM v3 (small index-critical shapes) ----------------
// tri=1: skip blocks fully above the causal diagonal (outputs never read by topk).
__global__ __launch_bounds__(256) void gemm_f32_v3(
    const float* __restrict__ A, const float* __restrict__ W,
    float* __restrict__ C, int M, int N, int K, int tri) {
  __shared__ float As[16][132];
  __shared__ float Ws[16][132];
  int tid = threadIdx.x;
  int bm = blockIdx.y * 128, bn = blockIdx.x * 128;
  if (tri && bn > bm + 127) return;
  int kper = K / gridDim.z;
  int kb = blockIdx.z * kper, ke = kb + kper;
  int lr = tid >> 1;
  int lh = (tid & 1) * 8;
  int tx = tid & 15, ty = tid >> 4;
  bool wok = (bn + lr < N);
  const float* arow = A + (size_t)(bm + lr) * K + lh;
  const float* wrow = W + (size_t)(bn + lr) * K + lh;
  float4 a0, a1, w0, w1;
  auto gload = [&](int k0) {
    a0 = *(const float4*)(arow + k0);
    a1 = *(const float4*)(arow + k0 + 4);
    w0 = make_float4(0.f, 0.f, 0.f, 0.f); w1 = w0;
    if (wok) {
      w0 = *(const float4*)(wrow + k0);
      w1 = *(const float4*)(wrow + k0 + 4);
    }
  };
  f32x4 acc0[8] = {}, acc1[8] = {};
  gload(kb);
  for (int k0 = kb; k0 < ke; k0 += 16) {
    __syncthreads();
    As[lh+0][lr]=a0.x; As[lh+1][lr]=a0.y; As[lh+2][lr]=a0.z; As[lh+3][lr]=a0.w;
    As[lh+4][lr]=a1.x; As[lh+5][lr]=a1.y; As[lh+6][lr]=a1.z; As[lh+7][lr]=a1.w;
    Ws[lh+0][lr]=w0.x; Ws[lh+1][lr]=w0.y; Ws[lh+2][lr]=w0.z; Ws[lh+3][lr]=w0.w;
    Ws[lh+4][lr]=w1.x; Ws[lh+5][lr]=w1.y; Ws[lh+6][lr]=w1.z; Ws[lh+7][lr]=w1.w;
    __syncthreads();
    if (k0 + 16 < ke) gload(k0 + 16);
#pragma unroll
    for (int kk = 0; kk < 16; ++kk) {
      f32x4 b0 = *(const f32x4*)&Ws[kk][tx * 4];
      f32x4 b1 = *(const f32x4*)&Ws[kk][64 + tx * 4];
      f32x4 al = *(const f32x4*)&As[kk][ty * 8];
      f32x4 ah = *(const f32x4*)&As[kk][ty * 8 + 4];
#pragma unroll
      for (int i = 0; i < 4; ++i) {
        acc0[i]     += splat4(al[i]) * b0;
        acc1[i]     += splat4(al[i]) * b1;
        acc0[i + 4] += splat4(ah[i]) * b0;
        acc1[i + 4] += splat4(ah[i]) * b1;
      }
    }
  }
  bool single = (gridDim.z == 1);
#pragma unroll
  for (int i = 0; i < 8; ++i) {
    int row = bm + ty * 8 + i;
    float* crow = C + (size_t)row * N;
    int c0 = bn + tx * 4, c1 = bn + 64 + tx * 4;
    if (c0 + 3 < N) {
      if (single) *(f32x4*)(crow + c0) = acc0[i];
      else {
        atomicAdd(crow + c0 + 0, acc0[i][0]); atomicAdd(crow + c0 + 1, acc0[i][1]);
        atomicAdd(crow + c0 + 2, acc0[i][2]); atomicAdd(crow + c0 + 3, acc0[i][3]);
      }
    }
    if (c1 + 3 < N) {
      if (single) *(f32x4*)(crow + c1) = acc1[i];
      else {
        atomicAdd(crow + c1 + 0, acc1[i][0]); atomicAdd(crow + c1 + 1, acc1[i][1]);
        atomicAdd(crow + c1 + 2, acc1[i][2]); atomicAdd(crow + c1 + 3, acc1[i][3]);
      }
    }
  }
}

// ---------------- dual fp32 GEMM: two independent same-shape GEMMs in one grid ----------------
__global__ __launch_bounds__(256) void gemm_f32_dual(
    const float* __restrict__ A0, const float* __restrict__ W0, float* __restrict__ C0,
    const float* __restrict__ A1, const float* __restrict__ W1, float* __restrict__ C1,
    int M, int N, int K, int S) {
  __shared__ float As[16][132];
  __shared__ float Ws[16][132];
  int tid = threadIdx.x;
  int bm = blockIdx.y * 128, bn = blockIdx.x * 128;
  int pair = (int)blockIdx.z >= S;
  int zi = blockIdx.z - pair * S;
  const float* A = pair ? A1 : A0;
  const float* W = pair ? W1 : W0;
  float* C = pair ? C1 : C0;
  int kper = K / S;
  int kb = zi * kper, ke = kb + kper;
  int lr = tid >> 1;
  int lh = (tid & 1) * 8;
  int tx = tid & 15, ty = tid >> 4;
  bool wok = (bn + lr < N);
  const float* arow = A + (size_t)(bm + lr) * K + lh;
  const float* wrow = W + (size_t)(bn + lr) * K + lh;
  float4 a0, a1, w0, w1;
  auto gload = [&](int k0) {
    a0 = *(const float4*)(arow + k0);
    a1 = *(const float4*)(arow + k0 + 4);
    w0 = make_float4(0.f, 0.f, 0.f, 0.f); w1 = w0;
    if (wok) {
      w0 = *(const float4*)(wrow + k0);
      w1 = *(const float4*)(wrow + k0 + 4);
    }
  };
  f32x4 acc0[8] = {}, acc1[8] = {};
  gload(kb);
  for (int k0 = kb; k0 < ke; k0 += 16) {
    __syncthreads();
    As[lh+0][lr]=a0.x; As[lh+1][lr]=a0.y; As[lh+2][lr]=a0.z; As[lh+3][lr]=a0.w;
    As[lh+4][lr]=a1.x; As[lh+5][lr]=a1.y; As[lh+6][lr]=a1.z; As[lh+7][lr]=a1.w;
    Ws[lh+0][lr]=w0.x; Ws[lh+1][lr]=w0.y; Ws[lh+2][lr]=w0.z; Ws[lh+3][lr]=w0.w;
    Ws[lh+4][lr]=w1.x; Ws[lh+5][lr]=w1.y; Ws[lh+6][lr]=w1.z; Ws[lh+7][lr]=w1.w;
    __syncthreads();
    if (k0 + 16 < ke) gload(k0 + 16);
#pragma unroll
    for (int kk = 0; kk < 16; ++kk) {
      f32x4 b0 = *(const f32x4*)&Ws[kk][tx * 4];
      f32x4 b1 = *(const f32x4*)&Ws[kk][64 + tx * 4];
      f32x4 al = *(const f32x4*)&As[kk][ty * 8];
      f32x4 ah = *(const f32x4*)&As[kk][ty * 8 + 4];
#pragma unroll
      for (int i = 0; i < 4; ++i) {
        acc0[i]     += splat4(al[i]) * b0;
        acc1[i]     += splat4(al[i]) * b1;
        acc0[i + 4] += splat4(ah[i]) * b0;
        acc1[i + 4] += splat4(ah[i]) * b1;
      }
    }
  }
#pragma unroll
  for (int i = 0; i < 8; ++i) {
    int row = bm + ty * 8 + i;
    float* crow = C + (size_t)row * N;
    int c0 = bn + tx * 4, c1 = bn + 64 + tx * 4;
    if (c0 + 3 < N) {
      atomicAdd(crow + c0 + 0, acc0[i][0]); atomicAdd(crow + c0 + 1, acc0[i][1]);
      atomicAdd(crow + c0 + 2, acc0[i][2]); atomicAdd(crow + c0 + 3, acc0[i][3]);
    }
    if (c1 + 3 < N) {
      atomicAdd(crow + c1 + 0, acc1[i][0]); atomicAdd(crow + c1 + 1, acc1[i][1]);
      atomicAdd(crow + c1 + 2, acc1[i][2]); atomicAdd(crow + c1 + 3, acc1[i][3]);
    }
  }
}

// ---------------- bf16 MFMA GEMM (double-buffered LDS: stage(t+1) || compute(t)) ----------------
// T1: XCD-aware (x,y) tile swizzle (identity fallback when nwg%8!=0).
// T3-min: 2-deep pipeline (structure-bound at ~445 TF for the 2048-class shapes).
__global__ __launch_bounds__(256) void gemm_bf16_kernel(
    const unsigned short* __restrict__ A, const unsigned short* __restrict__ W,
    float* __restrict__ C, int M, int N, int K, int lda, int ldb, int ldc) {
  __shared__ unsigned short As[2][128 * 64];
  __shared__ unsigned short Ws[2][128 * 64];
  int tid = threadIdx.x;
  int bx = blockIdx.x, by = blockIdx.y;
  int nxy = gridDim.x * gridDim.y;
  if ((nxy & 7) == 0) {
    int lin = by * gridDim.x + bx;
    int cpx = nxy >> 3;
    int swz = (lin & 7) * cpx + (lin >> 3);
    bx = swz % gridDim.x;
    by = swz / gridDim.x;
  }
  int bm = by * 128, bn = bx * 128;
  int kper = K / gridDim.z;
  int k_begin = blockIdx.z * kper;
  int k_end = k_begin + kper;
  int wv = tid >> 6, lane = tid & 63;
  int wrow = (wv >> 1) * 64, wcol = (wv & 1) * 64;
  int lrow = lane & 15, quad = lane >> 4;

  f32x4 acc[4][4] = {};

  auto stage = [&](int b, int k0) {
#pragma unroll
    for (int it = 0; it < 4; ++it) {
      int s = it * 256 + tid;
      int r = s >> 3;
      int q = (s & 7) ^ (r & 7);
      const unsigned short* ga = A + (size_t)(bm + r) * lda + k0 + q * 8;
      const unsigned short* gw = W + (size_t)(bn + r) * ldb + k0 + q * 8;
      __builtin_amdgcn_global_load_lds((const __attribute__((address_space(1))) void*)ga,
                                       (__attribute__((address_space(3))) void*)&As[b][s * 8], 16, 0, 0);
      __builtin_amdgcn_global_load_lds((const __attribute__((address_space(1))) void*)gw,
                                       (__attribute__((address_space(3))) void*)&Ws[b][s * 8], 16, 0, 0);
    }
  };

  stage(0, k_begin);
  int cur = 0;
  for (int k0 = k_begin; k0 < k_end; k0 += 64) {
    __syncthreads();
    if (k0 + 64 < k_end) stage(cur ^ 1, k0 + 64);
#pragma unroll
    for (int ks = 0; ks < 2; ++ks) {
      bf16x8 af[4], wf[4];
#pragma unroll
      for (int i = 0; i < 4; ++i) {
        int ra = wrow + i * 16 + lrow;
        int qa = (ks * 4 + quad) ^ (ra & 7);
        af[i] = *(const bf16x8*)&As[cur][(ra * 8 + qa) * 8];
        int rw = wcol + i * 16 + lrow;
        int qw = (ks * 4 + quad) ^ (rw & 7);
        wf[i] = *(const bf16x8*)&Ws[cur][(rw * 8 + qw) * 8];
      }
#pragma unroll
      for (int i = 0; i < 4; ++i)
#pragma unroll
        for (int j = 0; j < 4; ++j)
          acc[i][j] = __builtin_amdgcn_mfma_f32_16x16x32_bf16(af[i], wf[j], acc[i][j], 0, 0, 0);
    }
    cur ^= 1;
  }
  bool single = (gridDim.z == 1);
#pragma unroll
  for (int i = 0; i < 4; ++i)
#pragma unroll
    for (int j = 0; j < 4; ++j)
#pragma unroll
      for (int r = 0; r < 4; ++r) {
        int row = bm + wrow + i * 16 + quad * 4 + r;
        int col = bn + wcol + j * 16 + lrow;
        float v = acc[i][j][r];
        if (single) C[(size_t)row * ldc + col] = v;
        else atomicAdd(&C[(size_t)row * ldc + col], v);
      }
}

// ---------------- dual bf16 MFMA GEMM: q_up + kv_up in one launch ----------------
__global__ __launch_bounds__(256) void gemm_bf16_dual(
    const unsigned short* __restrict__ A0, const unsigned short* __restrict__ W0,
    float* __restrict__ C0,
    const unsigned short* __restrict__ A1, const unsigned short* __restrict__ W1,
    float* __restrict__ C1,
    int nx0, int ldc0, int ldc1, int K, int ld) {
  __shared__ unsigned short As[2][128 * 64];
  __shared__ unsigned short Ws[2][128 * 64];
  int tid = threadIdx.x;
  int bx = blockIdx.x, by = blockIdx.y;
  int pair = bx >= nx0;
  int bxl = pair ? bx - nx0 : bx;
  const unsigned short* A = pair ? A1 : A0;
  const unsigned short* W = pair ? W1 : W0;
  float* C = pair ? C1 : C0;
  int ldc = pair ? ldc1 : ldc0;
  int bm = by * 128, bn = bxl * 128;
  int wv = tid >> 6, lane = tid & 63;
  int wrow = (wv >> 1) * 64, wcol = (wv & 1) * 64;
  int lrow = lane & 15, quad = lane >> 4;

  f32x4 acc[4][4] = {};

  auto stage = [&](int b, int k0) {
#pragma unroll
    for (int it = 0; it < 4; ++it) {
      int s = it * 256 + tid;
      int r = s >> 3;
      int q = (s & 7) ^ (r & 7);
      const unsigned short* ga = A + (size_t)(bm + r) * ld + k0 + q * 8;
      const unsigned short* gw = W + (size_t)(bn + r) * ld + k0 + q * 8;
      __builtin_amdgcn_global_load_lds((const __attribute__((address_space(1))) void*)ga,
                                       (__attribute__((address_space(3))) void*)&As[b][s * 8], 16, 0, 0);
      __builtin_amdgcn_global_load_lds((const __attribute__((address_space(1))) void*)gw,
                                       (__attribute__((address_space(3))) void*)&Ws[b][s * 8], 16, 0, 0);
    }
  };

  stage(0, 0);
  int cur = 0;
  for (int k0 = 0; k0 < K; k0 += 64) {
    __syncthreads();
    if (k0 + 64 < K) stage(cur ^ 1, k0 + 64);
#pragma unroll
    for (int ks = 0; ks < 2; ++ks) {
      bf16x8 af[4], wf[4];
#pragma unroll
      for (int i = 0; i < 4; ++i) {
        int ra = wrow + i * 16 + lrow;
        int qa = (ks * 4 + quad) ^ (ra & 7);
        af[i] = *(const bf16x8*)&As[cur][(ra * 8 + qa) * 8];
        int rw = wcol + i * 16 + lrow;
        int qw = (ks * 4 + quad) ^ (rw & 7);
        wf[i] = *(const bf16x8*)&Ws[cur][(rw * 8 + qw) * 8];
      }
#pragma unroll
      for (int i = 0; i < 4; ++i)
#pragma unroll
        for (int j = 0; j < 4; ++j)
          acc[i][j] = __builtin_amdgcn_mfma_f32_16x16x32_bf16(af[i], wf[j], acc[i][j], 0, 0, 0);
    }
    cur ^= 1;
  }
#pragma unroll
  for (int i = 0; i < 4; ++i)
#pragma unroll
    for (int j = 0; j < 4; ++j)
#pragma unroll
      for (int r = 0; r < 4; ++r) {
        int row = bm + wrow + i * 16 + quad * 4 + r;
        int col = bn + wcol + j * 16 + lrow;
        C[(size_t)row * ldc + col] = acc[i][j][r];
      }
}

// ---------------- fused weight-prep: tripA + tripW + 6x caugW + transpose(idx_out_w) ----------------
// Elementwise regions in blocks [0, 20736); transpose region in blocks [20736, 21760).
__global__ __launch_bounds__(256) void prep_weights_kernel(
    const float* __restrict__ x, unsigned short* __restrict__ x_trip,
    const float* __restrict__ idx_in_w, unsigned short* __restrict__ w_in_trip,
    const float* __restrict__ q_down_w, const float* __restrict__ kv_down_w,
    const float* __restrict__ k_rope_w, unsigned short* __restrict__ w3down,
    const float* __restrict__ q_up_w, const float* __restrict__ q_rope_w,
    unsigned short* __restrict__ wqups,
    const float* __restrict__ kv_up_w, unsigned short* __restrict__ wkvup,
    const float* __restrict__ idx_out_w, float* __restrict__ out_w_T) {
  __shared__ float tsh[32][33];
  int bid = blockIdx.x;
  if (bid >= 20736) {
    int b = bid - 20736;
    int bx = b & 31, by = b >> 5;
    int tx = threadIdx.x & 31, ty8 = threadIdx.x >> 5;
    for (int r = ty8; r < 32; r += 8)
      tsh[r][tx] = idx_out_w[(size_t)(by * 32 + r) * 1024 + bx * 32 + tx];
    __syncthreads();
    for (int r = ty8; r < 32; r += 8)
      out_w_T[(size_t)(bx * 32 + r) * 1024 + by * 32 + tx] = tsh[tx][r];
    return;
  }
  int i = bid * 256 + threadIdx.x;
  if (i < 2097152) {
    // tripA: A=[h,m,l,h,m,h]
    float f = x[i];
    unsigned short h = f2bf(f);
    float r1 = f - bf2f(h);
    unsigned short m = f2bf(r1);
    unsigned short l = f2bf(r1 - bf2f(m));
    size_t o = (size_t)i * 6;
    x_trip[o] = h; x_trip[o + 1] = m; x_trip[o + 2] = l;
    x_trip[o + 3] = h; x_trip[o + 4] = m; x_trip[o + 5] = h;
  } else if (i < 4456448) {
    // tripW: W=[h,h,h,m,m,l], 2304 padded rows (2208 real)
    int j = i - 2097152;
    int n = j >> 10, k = j & 1023;
    unsigned short h = 0, m = 0, l = 0;
    if (n < 2208) {
      float f = idx_in_w[(size_t)n * 1024 + k];
      h = f2bf(f);
      float r1 = f - bf2f(h);
      m = f2bf(r1);
      l = f2bf(r1 - bf2f(m));
    }
    size_t o = (size_t)j * 6;
    w_in_trip[o] = h; w_in_trip[o + 1] = h; w_in_trip[o + 2] = h;
    w_in_trip[o + 3] = m; w_in_trip[o + 4] = m; w_in_trip[o + 5] = l;
  } else {
    int j2 = i - 4456448;
    const float* src; unsigned short* dst; int rows, K; size_t obase; int idx;
    if (j2 < 393216) {
      int r = j2 >> 17;               // 131072 = 2^17
      idx = j2 & 131071;
      K = 1024;
      src = (r == 0) ? q_down_w : (r == 1) ? kv_down_w : k_rope_w;
      rows = (r == 2) ? 32 : 128;
      dst = w3down; obase = (size_t)(r * 131072 + idx) * 3;
    } else if (j2 < 524288) {
      idx = j2 - 393216; K = 128; src = q_up_w; rows = 1024;
      dst = wqups; obase = (size_t)idx * 3;
    } else if (j2 < 589824) {
      idx = j2 - 524288; K = 128; src = q_rope_w; rows = 512;
      dst = wqups; obase = (size_t)393216 + (size_t)idx * 3;
    } else {
      idx = j2 - 589824; K = 128; src = kv_up_w; rows = 2048;
      dst = wkvup; obase = (size_t)idx * 3;
    }
    int n = idx / K, k = idx - n * K;
    unsigned short hi = 0, lo = 0;
    if (n < rows) {
      float f = src[(size_t)n * K + k];
      hi = f2bf(f);
      lo = f2bf(f - bf2f(hi));
    }
    dst[obase] = hi; dst[obase + 1] = hi; dst[obase + 2] = lo;
  }
}

// ---------------- fused post-in_proj: caugW(out_w) + conv_silu + dt ----------------
// U0=1048576 out_w aug | U1=3407872 conv_silu | U2=3473408 dt  (13568 blocks exactly)
__global__ __launch_bounds__(256) void post_inproj_kernel(
    const float* __restrict__ out_w, unsigned short* __restrict__ w_outp,
    const float* __restrict__ zxbcdt, const float* __restrict__ conv_w,
    const float* __restrict__ conv_b, float* __restrict__ xBC,
    const float* __restrict__ dt_bias, const float* __restrict__ A_log,
    float* __restrict__ dt, float* __restrict__ logdA) {
  int i = blockIdx.x * 256 + threadIdx.x;
  if (i < 1048576) {
    // caugW out_w: rows=1024, K=1024, all valid; W=[h,h,l]
    float f = out_w[i];
    unsigned short hi = f2bf(f);
    unsigned short lo = f2bf(f - bf2f(hi));
    size_t o = (size_t)i * 3;
    w_outp[o] = hi; w_outp[o + 1] = hi; w_outp[o + 2] = lo;
  } else if (i < 3407872) {
    int idx = i - 1048576;
    int l = idx / CONVCH, c = idx - l * CONVCH;
    float acc = conv_b[c];
#pragma unroll
    for (int k = 0; k < 4; ++k) {
      int ls = l - 3 + k;
      if (ls >= 0) acc += zxbcdt[(size_t)ls * INDIMP + DINNER + c] * conv_w[c * 4 + k];
    }
    xBC[idx] = acc / (1.f + expf(-acc));
  } else {
    int idx = i - 3407872;   // < 65536
    int l = idx >> 5, h = idx & 31;
    float xv = zxbcdt[(size_t)l * INDIMP + 2176 + h] + dt_bias[h];
    float sp = fmaxf(xv, 0.f) + log1pf(expf(-fabsf(xv)));
    dt[idx] = sp;
    logdA[idx] = sp * -expf(A_log[h]);
  }
}

// ---------------- conversions ----------------
// 3-slot aug (value path): A=[h,l,h]
__global__ __launch_bounds__(256) void conv_augA_kernel(
    const float* __restrict__ src, unsigned short* __restrict__ dst,
    int total, int K, int sld) {
  int i = blockIdx.x * 256 + threadIdx.x;
  if (i >= total) return;
  int m = i / K, k = i - m * K;
  float f = src[(size_t)m * sld + k];
  unsigned short hi = f2bf(f);
  unsigned short lo = f2bf(f - bf2f(hi));
  size_t o = ((size_t)m * K + k) * 3;
  dst[o] = hi; dst[o + 1] = lo; dst[o + 2] = hi;
}
// fused c3 -> c_q_aug (cols 0..127) + c_kv_aug (cols 128..255), one read of c3
__global__ __launch_bounds__(256) void conv_augA2_kernel(
    const float* __restrict__ c3, unsigned short* __restrict__ dq,
    unsigned short* __restrict__ dkv) {
  int i = blockIdx.x * 256 + threadIdx.x;
  if (i >= 2048 * 256) return;
  int m = i >> 8, k = i & 255;
  float f = c3[(size_t)m * 384 + k];
  unsigned short hi = f2bf(f);
  unsigned short lo = f2bf(f - bf2f(hi));
  if (k < 128) {
    size_t o = ((size_t)m * 128 + k) * 3;
    dq[o] = hi; dq[o + 1] = lo; dq[o + 2] = hi;
  } else {
    size_t o = ((size_t)m * 128 + (k - 128)) * 3;
    dkv[o] = hi; dkv[o + 1] = lo; dkv[o + 2] = hi;
  }
}

// ---------------- G[c][t][s] = C_t . B_s  (+ lcd region in blocks 32..35) ----------------
__global__ __launch_bounds__(256) void chunk_G_kernel(
    const float* __restrict__ xBC, float* __restrict__ G,
    const float* __restrict__ logdA, float* __restrict__ lcd) {
  int c = blockIdx.x, tid = threadIdx.x;
  if (c >= NCH) {
    // lcd: i in [0, 1024)
    int i = (c - NCH) * 256 + tid;
    int cc = i >> 5, h = i & 31;
    float s = 0.f;
    for (int t = 0; t < CHUNK; ++t) {
      s += logdA[(cc * CHUNK + t) * MNH + h];
      lcd[(size_t)i * CHUNK + t] = s;
    }
    return;
  }
  __shared__ float BsT[64][68];
  __shared__ float Cs[64][65];
  int t = tid >> 2, q = tid & 3;
  const float* row = xBC + (size_t)(c * 64 + t) * CONVCH + DINNER;
#pragma unroll
  for (int j = 0; j < 16; j += 4) {
    float4 b = *(const float4*)(row + q * 16 + j);
    BsT[q * 16 + j + 0][t] = b.x; BsT[q * 16 + j + 1][t] = b.y;
    BsT[q * 16 + j + 2][t] = b.z; BsT[q * 16 + j + 3][t] = b.w;
    float4 cv = *(const float4*)(row + 64 + q * 16 + j);
    Cs[t][q * 16 + j + 0] = cv.x; Cs[t][q * 16 + j + 1] = cv.y;
    Cs[t][q * 16 + j + 2] = cv.z; Cs[t][q * 16 + j + 3] = cv.w;
  }
  __syncthreads();
  int s0 = q * 16;
  f32x4 g0 = {}, g1 = {}, g2 = {}, g3 = {};
  for (int n = 0; n < 64; ++n) {
    f32x4 cv = splat4(Cs[t][n]);
    g0 += cv * *(const f32x4*)&BsT[n][s0];
    g1 += cv * *(const f32x4*)&BsT[n][s0 + 4];
    g2 += cv * *(const f32x4*)&BsT[n][s0 + 8];
    g3 += cv * *(const f32x4*)&BsT[n][s0 + 12];
  }
  float* gp = G + ((size_t)c * 64 + t) * 64 + s0;
  *(f32x4*)gp = g0; *(f32x4*)(gp + 4) = g1; *(f32x4*)(gp + 8) = g2; *(f32x4*)(gp + 12) = g3;
}

// ---------------- scan pass A ----------------
__global__ __launch_bounds__(256) void scan_local_kernel(
    const float* __restrict__ xBC, const float* __restrict__ dt,
    const float* __restrict__ lcd, float* __restrict__ hstate) {
  int c = blockIdx.x >> 5, h = blockIdx.x & 31;
  int tid = threadIdx.x;
  __shared__ float Bs[64][68];
  __shared__ float xss[64][36];
  __shared__ float w2s[64];
  int t0 = c * CHUNK;
  int t = tid >> 2, q = tid & 3;
  const float* row = xBC + (size_t)(t0 + t) * CONVCH;
#pragma unroll
  for (int j = 0; j < 16; j += 4)
    *(float4*)&Bs[t][q * 16 + j] = *(const float4*)(row + DINNER + q * 16 + j);
  if (q < 2) {
#pragma unroll
    for (int j = 0; j < 16; j += 4)
      *(float4*)&xss[t][q * 16 + j] = *(const float4*)(row + h * 32 + q * 16 + j);
  }
  if (tid < 64) {
    const float* lc = lcd + ((size_t)c * 32 + h) * CHUNK;
    w2s[tid] = expf(lc[63] - lc[tid]) * dt[(t0 + tid) * MNH + h];
  }
  __syncthreads();
  int n = tid >> 2, pg = (tid & 3) * 8;
  f32x4 h0 = {}, h1 = {};
  for (int s = 0; s < 64; ++s) {
    f32x4 wb = splat4(w2s[s] * Bs[s][n]);
    h0 += wb * *(const f32x4*)&xss[s][pg];
    h1 += wb * *(const f32x4*)&xss[s][pg + 4];
  }
  float* hp = hstate + ((size_t)c * 32 + h) * 2048 + n * 32 + pg;
  *(f32x4*)hp = h0; *(f32x4*)(hp + 4) = h1;
}

// ---------------- scan pass B ----------------
__global__ __launch_bounds__(256) void scan_combine_kernel(
    float* __restrict__ hstate, const float* __restrict__ lcd) {
  int i = blockIdx.x * 256 + threadIdx.x;
  int h = i >> 11;
  float H = 0.f;
  for (int c = 0; c < NCH; ++c) {
    float hl = hstate[(size_t)c * 65536 + i];
    hstate[(size_t)c * 65536 + i] = H;
    float P = expf(lcd[((size_t)c * 32 + h) * CHUNK + CHUNK - 1]);
    H = H * P + hl;
  }
}

// ---------------- scan pass C ----------------
__global__ __launch_bounds__(256) void scan_y_kernel(
    const float* __restrict__ xBC, const float* __restrict__ G,
    const float* __restrict__ dt, const float* __restrict__ lcd,
    const float* __restrict__ hstate, float* __restrict__ y) {
  int c = blockIdx.x >> 5, h = blockIdx.x & 31;
  int tid = threadIdx.x;
  __shared__ float Ms[64][65];
  __shared__ float Cs[64][65];
  __shared__ float xss[64][36];
  __shared__ float Hss[64][36];
  __shared__ float lcds[64], dts[64];
  int t0 = c * CHUNK;
  int t = tid >> 2, q = tid & 3;
  const float* row = xBC + (size_t)(t0 + t) * CONVCH;
#pragma unroll
  for (int j = 0; j < 16; j += 4) {
    float4 cv = *(const float4*)(row + DINNER + 64 + q * 16 + j);
    Cs[t][q * 16 + j + 0] = cv.x; Cs[t][q * 16 + j + 1] = cv.y;
    Cs[t][q * 16 + j + 2] = cv.z; Cs[t][q * 16 + j + 3] = cv.w;
  }
  if (q < 2) {
#pragma unroll
    for (int j = 0; j < 16; j += 4)
      *(float4*)&xss[t][q * 16 + j] = *(const float4*)(row + h * 32 + q * 16 + j);
  }
  {
    const float* gp = G + ((size_t)c * 64 + t) * 64 + q * 16;
#pragma unroll
    for (int j = 0; j < 16; j += 4) {
      float4 g = *(const float4*)(gp + j);
      Ms[t][q * 16 + j + 0] = g.x; Ms[t][q * 16 + j + 1] = g.y;
      Ms[t][q * 16 + j + 2] = g.z; Ms[t][q * 16 + j + 3] = g.w;
    }
  }
  {
    const float* hp = hstate + ((size_t)c * 32 + h) * 2048 + tid * 8;
    int n = tid >> 2, p0 = (tid & 3) * 8;
    *(float4*)&Hss[n][p0]     = *(const float4*)hp;
    *(float4*)&Hss[n][p0 + 4] = *(const float4*)(hp + 4);
  }
  if (tid < 64) {
    lcds[tid] = lcd[((size_t)c * 32 + h) * CHUNK + tid];
    dts[tid]  = dt[(t0 + tid) * MNH + h];
  }
  __syncthreads();
  {
    int s0 = q * 16;
#pragma unroll
    for (int j = 0; j < 16; ++j) {
      int s = s0 + j;
      float m = (s <= t) ? expf(lcds[t] - lcds[s]) * dts[s] * Ms[t][s] : 0.f;
      Ms[t][s] = m;
    }
  }
  __syncthreads();
  int pg = q * 8;
  f32x4 y0 = {}, y1 = {}, a0 = {}, a1 = {};
  for (int s = 0; s < 64; ++s) {
    f32x4 m = splat4(Ms[t][s]);
    y0 += m * *(const f32x4*)&xss[s][pg];
    y1 += m * *(const f32x4*)&xss[s][pg + 4];
  }
  for (int n = 0; n < 64; ++n) {
    f32x4 cn = splat4(Cs[t][n]);
    a0 += cn * *(const f32x4*)&Hss[n][pg];
    a1 += cn * *(const f32x4*)&Hss[n][pg + 4];
  }
  f32x4 cd = splat4(expf(lcds[t]));
  y0 += cd * a0; y1 += cd * a1;
  float* yp = y + (size_t)(t0 + t) * DINNER + h * 32 + pg;
  *(f32x4*)yp = y0; *(f32x4*)(yp + 4) = y1;
}

// ---------------- gate + RMSNorm ----------------
__global__ __launch_bounds__(256) void gatenorm_kernel(
    const float* __restrict__ y_ssm, const float* __restrict__ xBC,
    const float* __restrict__ zxbcdt, const float* __restrict__ Dv,
    const float* __restrict__ norm_w, float* __restrict__ out) {
  int l = blockIdx.x, tid = threadIdx.x;
  float vals[4];
  float ss = 0.f;
#pragma unroll
  for (int i = 0; i < 4; ++i) {
    int d = tid + i * 256;
    int h = d >> 5;
    float v = y_ssm[(size_t)l * DINNER + d] + Dv[h] * xBC[(size_t)l * CONVCH + d];
    float z = zxbcdt[(size_t)l * INDIMP + d];
    v *= z / (1.f + expf(-z));
    vals[i] = v;
    ss += v * v;
  }
#pragma unroll
  for (int off = 32; off > 0; off >>= 1) ss += __shfl_xor(ss, off);
  __shared__ float sred[4];
  if ((tid & 63) == 0) sred[tid >> 6] = ss;
  __syncthreads();
  float tot = sred[0] + sred[1] + sred[2] + sred[3];
  float scale = rsqrtf(tot * (1.f / 1024.f) + 1e-5f);
#pragma unroll
  for (int i = 0; i < 4; ++i) {
    int d = tid + i * 256;
    out[(size_t)l * DINNER + d] = vals[i] * scale * norm_w[d];
  }
}

// ---------------- per-row top-64 radix select (R4-verified global-scan) ----------------
__global__ __launch_bounds__(256) void topk_kernel(
    const float* __restrict__ scores, int* __restrict__ out_idx) {
  int l = blockIdx.x, tid = threadIdx.x;
  if (l < 64) {
    if (tid < 64) out_idx[l * 64 + tid] = tid;
    return;
  }
  int n = l + 1;
  const float* row = scores + (size_t)l * L;
  __shared__ int hist[256];
  __shared__ unsigned sel_prefix;
  __shared__ int sel_remaining;
  __shared__ int cnt_g, cnt_e;
  __shared__ int eq_list[128];
  if (tid == 0) { cnt_g = 0; cnt_e = 0; }
  unsigned prefix = 0;
  int remaining = 64;
  for (int pass = 0; pass < 4; ++pass) {
    int shift = 24 - 8 * pass;
    unsigned himask = (pass == 0) ? 0u : (0xFFFFFFFFu << (shift + 8));
    hist[tid] = 0;
    __syncthreads();
    for (int j = tid; j < n; j += 256) {
      unsigned u = __float_as_uint(row[j]);
      unsigned key = (u & 0x80000000u) ? ~u : (u | 0x80000000u);
      if (((key ^ prefix) & himask) == 0)
        atomicAdd(&hist[(key >> shift) & 255], 1);
    }
    __syncthreads();
    if (tid == 0) {
      int cum = 0, b = 255;
      for (; b >= 0; --b) {
        cum += hist[b];
        if (cum >= remaining) break;
      }
      sel_prefix = prefix | ((unsigned)b << shift);
      sel_remaining = remaining - (cum - hist[b]);
    }
    __syncthreads();
    prefix = sel_prefix;
    remaining = sel_remaining;
    __syncthreads();
  }
  unsigned T = prefix;
  for (int j = tid; j < n; j += 256) {
    unsigned u = __float_as_uint(row[j]);
    unsigned key = (u & 0x80000000u) ? ~u : (u | 0x80000000u);
    if (key > T) {
      int p = atomicAdd(&cnt_g, 1);
      out_idx[l * 64 + p] = j;
    } else if (key == T) {
      int p = atomicAdd(&cnt_e, 1);
      if (p < 128) eq_list[p] = j;
    }
  }
  __syncthreads();
  if (tid == 0) {
    int G = cnt_g;
    int E = remaining;
    int m = cnt_e < 128 ? cnt_e : 128;
    for (int e = 0; e < E; ++e) {
      int best = 0, bj = 0x7fffffff;
      for (int i = 0; i < m; ++i)
        if (eq_list[i] < bj) { bj = eq_list[i]; best = i; }
      out_idx[l * 64 + G + e] = bj;
      eq_list[best] = 0x7fffffff;
    }
  }
}

// ---------------- RoPE + pack q_final/k_final (fused-buffer strides) ----------------
__global__ __launch_bounds__(128) void rope_pack_kernel(
    const float* __restrict__ qbuf, const float* __restrict__ kv,
    const float* __restrict__ c3,
    float* __restrict__ q_final, float* __restrict__ k_final) {
  int l = blockIdx.x, tid = threadIdx.x;
  __shared__ float s_s[16], s_c[16];
  if (tid < 16) {
    float inv = powf(10000.f, -(float)tid / 16.f);
    float ang = (float)l * inv;
    s_s[tid] = sinf(ang);
    s_c[tid] = cosf(ang);
  }
  __syncthreads();
  const float* qrow = qbuf + (size_t)l * 1536;
  const float* krow = c3 + (size_t)l * 384 + 256;
  for (int e = tid; e < NH * 96; e += 128) {
    int hh = e / 96, d = e - hh * 96;
    float qv, kvv;
    if (d < 64) {
      qv  = qrow[hh * 64 + d];
      kvv = kv[(size_t)l * 2048 + hh * 64 + d];
    } else {
      int r = d - 64;
      if (r < 16) {
        float q1 = qrow[1024 + hh * 32 + r];
        float q2 = qrow[1024 + hh * 32 + 16 + r];
        qv = q1 * s_c[r] - q2 * s_s[r];
        float k1 = krow[r];
        float k2 = krow[16 + r];
        kvv = k1 * s_c[r] - k2 * s_s[r];
      } else {
        int rr = r - 16;
        float q1 = qrow[1024 + hh * 32 + rr];
        float q2 = qrow[1024 + hh * 32 + 16 + rr];
        qv = q1 * s_s[rr] + q2 * s_c[rr];
        float k1 = krow[rr];
        float k2 = krow[16 + rr];
        kvv = k1 * s_s[rr] + k2 * s_c[rr];
      }
    }
    q_final[(size_t)l * 1536 + e] = qv;
    k_final[(size_t)l * 1536 + e] = kvv;
  }
}

// ---------------- sparse attention (coalesced, one block per row) ----------------
// XCD l-chunking: contiguous l-range per XCD for K/V L2 residency (bijective, 2048%8==0).
__global__ __launch_bounds__(256) void attn_kernel(
    const float* __restrict__ q_final, const float* __restrict__ k_final,
    const float* __restrict__ kv, const int* __restrict__ idx,
    unsigned short* __restrict__ attn_aug) {
  int b = blockIdx.x;
  int l = (b & 7) * 256 + (b >> 3);
  int tid = threadIdx.x;
  int h = tid >> 4;
  int s = tid & 15;
  __shared__ __align__(16) float lg[16][64];
  __shared__ int iks[64];

  if (tid < 64) iks[tid] = idx[l * 64 + tid];

  const float* qrow = q_final + (size_t)l * 1536 + h * 96 + s * 2;
  float q0 = qrow[0],  q1 = qrow[1];
  float q2 = qrow[32], q3 = qrow[33];
  float q4 = qrow[64], q5 = qrow[65];
  __syncthreads();

#pragma unroll 4
  for (int k = 0; k < 64; ++k) {
    const float* kr = k_final + (size_t)iks[k] * 1536 + h * 96 + s * 2;
    float2 a = *(const float2*)kr;
    float2 b2 = *(const float2*)(kr + 32);
    float2 c = *(const float2*)(kr + 64);
    float d = q0 * a.x + q1 * a.y + q2 * b2.x + q3 * b2.y + q4 * c.x + q5 * c.y;
    d += __shfl_xor(d, 1);
    d += __shfl_xor(d, 2);
    d += __shfl_xor(d, 4);
    d += __shfl_xor(d, 8);
    if (s == 0) lg[h][k] = d * 0.10206207261596575f;
  }
  __syncthreads();

  f32x4 lv = *(const f32x4*)&lg[h][s * 4];
  float m = fmaxf(fmaxf(lv[0], lv[1]), fmaxf(lv[2], lv[3]));
#pragma unroll
  for (int off = 1; off < 16; off <<= 1) m = fmaxf(m, __shfl_xor(m, off));
  f32x4 ev;
  ev[0] = expf(lv[0] - m); ev[1] = expf(lv[1] - m);
  ev[2] = expf(lv[2] - m); ev[3] = expf(lv[3] - m);
  float ssum = ev[0] + ev[1] + ev[2] + ev[3];
#pragma unroll
  for (int off = 1; off < 16; off <<= 1) ssum += __shfl_xor(ssum, off);
  float inv = 1.f / ssum;
  lg[h][s * 4 + 0] = ev[0] * inv;
  lg[h][s * 4 + 1] = ev[1] * inv;
  lg[h][s * 4 + 2] = ev[2] * inv;
  lg[h][s * 4 + 3] = ev[3] * inv;
  __syncthreads();

  f32x4 acc = {};
#pragma unroll 4
  for (int k = 0; k < 64; ++k) {
    const float* vr = kv + (size_t)iks[k] * 2048 + 1024 + tid * 4;
    f32x4 v = *(const f32x4*)vr;
    acc += splat4(lg[h][k]) * v;
  }

#pragma unroll
  for (int i = 0; i < 4; ++i) {
    float a = acc[i];
    unsigned short hi = f2bf(a);
    unsigned short lo = f2bf(a - bf2f(hi));
    size_t o = ((size_t)l * 1024 + tid * 4 + i) * 3;
    attn_aug[o] = hi; attn_aug[o + 1] = lo; attn_aug[o + 2] = hi;
  }
}

// ---------------- host ----------------
extern "C" void kernel_launch(void* const* d_in, const int* in_sizes, int n_in,
                              void* d_out, int out_size, void* d_ws, size_t ws_size,
                              hipStream_t stream) {
  const float* x          = (const float*)d_in[0];
  const float* idx_in_w   = (const float*)d_in[1];
  const float* idx_conv_w = (const float*)d_in[2];
  const float* idx_conv_b = (const float*)d_in[3];
  const float* idx_dt_b   = (const float*)d_in[4];
  const float* idx_A_log  = (const float*)d_in[5];
  const float* idx_D      = (const float*)d_in[6];
  const float* idx_norm_w = (const float*)d_in[7];
  const float* idx_out_w  = (const float*)d_in[8];
  const float* idx_q_w    = (const float*)d_in[9];
  const float* idx_k_w    = (const float*)d_in[10];
  const float* q_down_w   = (const float*)d_in[11];
  const float* q_up_w     = (const float*)d_in[12];
  const float* q_rope_w   = (const float*)d_in[13];
  const float* kv_down_w  = (const float*)d_in[14];
  const float* kv_up_w    = (const float*)d_in[15];
  const float* k_rope_w   = (const float*)d_in[16];
  const float* out_w      = (const float*)d_in[17];
  float* out = (float*)d_out;

  float* p = (float*)d_ws;
  float* segA = p; p += 4718592;  // zxbcdt[2048x2304] | scores | qbuf
  float* segB = p; p += 2359296;  // xBC | {q_idx, k_idx, c3}
  float* dtb = p; p += 65536;
  float* logdA = p; p += 65536;
  float* lcdb = p; p += 65536;
  int*   idxb = (int*)p; p += 131072;
  float* segD = p; p += 4194304;  // y_ssm+hstate | kvb
  float* segBig1 = p; p += 6291456;  // x_trip | w_outp_aug (after in_proj)
  float* segBig2 = p; p += 7077888;  // w_in_trip | {y_norm|x_aug|q_final}@0, attn_aug@3145728
  float* segH = p; p += 3145728;     // {out_w_T,qwpad,Wq} | k_final
  unsigned short* w_3down_aug = (unsigned short*)p; p += 589824;
  unsigned short* w_qups_aug  = (unsigned short*)p; p += 294912;
  unsigned short* w_kvup_aug  = (unsigned short*)p; p += 393216;
  unsigned short* c_q_aug     = (unsigned short*)p; p += 393216;
  unsigned short* c_kv_aug    = (unsigned short*)p; p += 393216;
  float* Gbuf = p; p += 131072;

  float* zxbcdt = segA;
  float* scores = segA;
  float* qbuf   = segA;
  float* xBC    = segB;
  float* q_idx  = segB;
  float* k_idx  = segB + 131072;
  float* c3     = segB + 262144;
  float* y_ssm  = segD;
  float* hstate = segD + 2097152;
  float* kvb    = segD;
  unsigned short* x_trip     = (unsigned short*)segBig1;  // dead after in_proj
  unsigned short* w_outp_aug = (unsigned short*)segBig1;  // written after in_proj
  unsigned short* w_in_trip  = (unsigned short*)segBig2;  // dead after in_proj
  float* y_norm  = segBig2;                               // gatenorm..q_idx gemm
  unsigned short* x_aug = (unsigned short*)segBig2;       // after topk..down-proj
  float* q_final = segBig2;                               // rope_pack..attn
  unsigned short* attn_aug = (unsigned short*)(segBig2 + 3145728);
  float* out_w_T = segH;
  float* qwpad   = segH + 1048576;
  float* Wq      = segH + 1179648;
  float* k_final = segH;                                  // after q_idx gemm

  dim3 blk(256);
  auto cdiv = [](int a, int b) { return (a + b - 1) / b; };
  auto gemmf3 = [&](const float* A, const float* W, float* C, int M, int N, int K, int S, int tri) {
    dim3 grid(cdiv(N, 128), M / 128, S);
    hipLaunchKernelGGL(gemm_f32_v3, grid, blk, 0, stream, A, W, C, M, N, K, tri);
  };
  auto gemmb = [&](const unsigned short* A, const unsigned short* W, float* C,
                   int M, int N, int K, int lda, int ldb, int ldc, int S) {
    dim3 grid(N / 128, M / 128, S);
    hipLaunchKernelGGL(gemm_bf16_kernel, grid, blk, 0, stream, A, W, C, M, N, K, lda, ldb, ldc);
  };

  // ---- weight precomputes (prep includes the idx_out_w transpose region) ----
  hipLaunchKernelGGL(prep_weights_kernel, dim3(21760), blk, 0, stream,
                     x, x_trip, idx_in_w, w_in_trip,
                     q_down_w, kv_down_w, k_rope_w, w_3down_aug,
                     q_up_w, q_rope_w, w_qups_aug, kv_up_w, w_kvup_aug,
                     idx_out_w, out_w_T);
  hipMemsetAsync(qwpad, 0, 262144 * 4, stream);   // qwpad + adjacent Wq in one memset
  hipMemcpyAsync(qwpad, idx_q_w, (size_t)64 * 1024 * 4, hipMemcpyDeviceToDevice, stream);
  gemmf3(qwpad, out_w_T, Wq, 128, 1024, 1024, 8, 0);

  // ---- mamba branch: in_proj via triple-split MFMA (fp32-accurate) ----
  // S=2: occupancy is LDS-capped at 2 blocks/CU either way; S=2 halves the
  // atomic RMW traffic on zxbcdt (FETCH -37 MB, WRITE -37 MB vs S=4).
  hipMemsetAsync(zxbcdt, 0, (size_t)L * INDIMP * 4, stream);
  gemmb(x_trip, w_in_trip, zxbcdt, 2048, 2304, 6144, 6144, 6144, INDIMP, 2);
  // fused: caugW(out_w -> segBig1, x_trip dead) + conv_silu + dt, one launch
  hipLaunchKernelGGL(post_inproj_kernel, dim3(13568), blk, 0, stream,
                     out_w, w_outp_aug, zxbcdt, idx_conv_w, idx_conv_b, xBC,
                     idx_dt_b, idx_A_log, dtb, logdA);
  // chunk_G + lcd region (blocks 32..35)
  hipLaunchKernelGGL(chunk_G_kernel, dim3(NCH + 4), blk, 0, stream,
                     xBC, Gbuf, logdA, lcdb);
  hipLaunchKernelGGL(scan_local_kernel, dim3(NCH * MNH), blk, 0, stream,
                     xBC, dtb, lcdb, hstate);
  hipLaunchKernelGGL(scan_combine_kernel, dim3(256), blk, 0, stream, hstate, lcdb);
  hipLaunchKernelGGL(scan_y_kernel, dim3(NCH * MNH), blk, 0, stream,
                     xBC, Gbuf, dtb, lcdb, hstate, y_ssm);
  hipLaunchKernelGGL(gatenorm_kernel, dim3(L), blk, 0, stream,
                     y_ssm, xBC, zxbcdt, idx_D, idx_norm_w, y_norm);

  // ---- index scores + topk (out-proj folded into Wq) ----
  hipMemsetAsync(q_idx, 0, 262144 * 4, stream);   // q_idx + adjacent k_idx in one memset
  {
    dim3 grid(1, 16, 32);  // 2 pairs x S=16
    hipLaunchKernelGGL(gemm_f32_dual, grid, blk, 0, stream,
                       y_norm, Wq, q_idx, x, idx_k_w, k_idx, 2048, 64, 1024, 16);
  }
  gemmf3(q_idx, k_idx, scores, 2048, 2048, 64, 1, 1);
  hipLaunchKernelGGL(topk_kernel, dim3(L), blk, 0, stream, scores, idxb);

  // ---- attention value path (aug split-bf16 MFMA) ----
  hipLaunchKernelGGL(conv_augA_kernel, dim3(cdiv(2048 * 1024, 256)), blk, 0, stream,
                     x, x_aug, 2048 * 1024, 1024, 1024);  // segBig2@0 (y_norm dead)
  hipMemsetAsync(c3, 0, 786432 * 4, stream);
  gemmb(x_aug, w_3down_aug, c3, 2048, 384, 3072, 3072, 3072, 384, 8);
  hipLaunchKernelGGL(conv_augA2_kernel, dim3(cdiv(2048 * 256, 256)), blk, 0, stream,
                     c3, c_q_aug, c_kv_aug);
  // fused: q_up (N=1536) + kv_up (N=2048) in one 28x16 launch
  {
    dim3 grid(28, 16, 1);
    hipLaunchKernelGGL(gemm_bf16_dual, grid, blk, 0, stream,
                       c_q_aug, w_qups_aug, qbuf,
                       c_kv_aug, w_kvup_aug, kvb,
                       12, 1536, 2048, 384, 384);
  }
  hipLaunchKernelGGL(rope_pack_kernel, dim3(L), dim3(128), 0, stream,
                     qbuf, kvb, c3, q_final, k_final);

  // ---- sparse attention + output projection ----
  hipLaunchKernelGGL(attn_kernel, dim3(L), blk, 0, stream,
                     q_final, k_final, kvb, idxb, attn_aug);
  hipMemsetAsync(out, 0, (size_t)out_size * 4, stream);
  gemmb(attn_aug, w_outp_aug, out, 2048, 1024, 3072, 3072, 3072, 1024, 4);
}

// Round 10
// 639.109 us; speedup vs baseline: 1.1495x; 1.0104x over previous
//
#include <hip/hip_runtime.h>
#include <math.h>

// ---------------- constants ----------------
constexpr int L      = 2048;
constexpr int NH     = 16;
constexpr int DINNER = 1024;
constexpr int MNH    = 32;
constexpr int CONVCH = 1152;
constexpr int INDIMP = 2304;   // padded stride for zxbcdt (2208 -> 2304, N%128)
constexpr int CHUNK  = 64;
constexpr int NCH    = 32;

using bf16x8 = __attribute__((ext_vector_type(8))) short;
using f32x4  = __attribute__((ext_vector_type(4))) float;

__device__ __forceinline__ f32x4 splat4(float x) { return (f32x4){x, x, x, x}; }

__device__ __forceinline__ unsigned short f2bf(float f) {
  unsigned u = __float_as_uint(f);
  return (unsigned short)((u + 0x7fffu + ((u >> 16) & 1u)) >> 16);
}
__device__ __forceinline__ float bf2f(unsigned short h) {
  return __uint_as_float((unsigned)h << 16);
}

// ---------------- fp32 GEMM v3 (small index-critical shapes) ----------------
// tri=1: skip blocks fully above the causal diagonal (outputs never read by topk).
__global__ __launch_bounds__(256) void gemm_f32_v3(
    const float* __restrict__ A, const float* __restrict__ W,
    float* __restrict__ C, int M, int N, int K, int tri) {
  __shared__ float As[16][132];
  __shared__ float Ws[16][132];
  int tid = threadIdx.x;
  int bm = blockIdx.y * 128, bn = blockIdx.x * 128;
  if (tri && bn > bm + 127) return;
  int kper = K / gridDim.z;
  int kb = blockIdx.z * kper, ke = kb + kper;
  int lr = tid >> 1;
  int lh = (tid & 1) * 8;
  int tx = tid & 15, ty = tid >> 4;
  bool wok = (bn + lr < N);
  const float* arow = A + (size_t)(bm + lr) * K + lh;
  const float* wrow = W + (size_t)(bn + lr) * K + lh;
  float4 a0, a1, w0, w1;
  auto gload = [&](int k0) {
    a0 = *(const float4*)(arow + k0);
    a1 = *(const float4*)(arow + k0 + 4);
    w0 = make_float4(0.f, 0.f, 0.f, 0.f); w1 = w0;
    if (wok) {
      w0 = *(const float4*)(wrow + k0);
      w1 = *(const float4*)(wrow + k0 + 4);
    }
  };
  f32x4 acc0[8] = {}, acc1[8] = {};
  gload(kb);
  for (int k0 = kb; k0 < ke; k0 += 16) {
    __syncthreads();
    As[lh+0][lr]=a0.x; As[lh+1][lr]=a0.y; As[lh+2][lr]=a0.z; As[lh+3][lr]=a0.w;
    As[lh+4][lr]=a1.x; As[lh+5][lr]=a1.y; As[lh+6][lr]=a1.z; As[lh+7][lr]=a1.w;
    Ws[lh+0][lr]=w0.x; Ws[lh+1][lr]=w0.y; Ws[lh+2][lr]=w0.z; Ws[lh+3][lr]=w0.w;
    Ws[lh+4][lr]=w1.x; Ws[lh+5][lr]=w1.y; Ws[lh+6][lr]=w1.z; Ws[lh+7][lr]=w1.w;
    __syncthreads();
    if (k0 + 16 < ke) gload(k0 + 16);
#pragma unroll
    for (int kk = 0; kk < 16; ++kk) {
      f32x4 b0 = *(const f32x4*)&Ws[kk][tx * 4];
      f32x4 b1 = *(const f32x4*)&Ws[kk][64 + tx * 4];
      f32x4 al = *(const f32x4*)&As[kk][ty * 8];
      f32x4 ah = *(const f32x4*)&As[kk][ty * 8 + 4];
#pragma unroll
      for (int i = 0; i < 4; ++i) {
        acc0[i]     += splat4(al[i]) * b0;
        acc1[i]     += splat4(al[i]) * b1;
        acc0[i + 4] += splat4(ah[i]) * b0;
        acc1[i + 4] += splat4(ah[i]) * b1;
      }
    }
  }
  bool single = (gridDim.z == 1);
#pragma unroll
  for (int i = 0; i < 8; ++i) {
    int row = bm + ty * 8 + i;
    float* crow = C + (size_t)row * N;
    int c0 = bn + tx * 4, c1 = bn + 64 + tx * 4;
    if (c0 + 3 < N) {
      if (single) *(f32x4*)(crow + c0) = acc0[i];
      else {
        atomicAdd(crow + c0 + 0, acc0[i][0]); atomicAdd(crow + c0 + 1, acc0[i][1]);
        atomicAdd(crow + c0 + 2, acc0[i][2]); atomicAdd(crow + c0 + 3, acc0[i][3]);
      }
    }
    if (c1 + 3 < N) {
      if (single) *(f32x4*)(crow + c1) = acc1[i];
      else {
        atomicAdd(crow + c1 + 0, acc1[i][0]); atomicAdd(crow + c1 + 1, acc1[i][1]);
        atomicAdd(crow + c1 + 2, acc1[i][2]); atomicAdd(crow + c1 + 3, acc1[i][3]);
      }
    }
  }
}

// ---------------- dual fp32 GEMM: two independent same-shape GEMMs in one grid ----------------
__global__ __launch_bounds__(256) void gemm_f32_dual(
    const float* __restrict__ A0, const float* __restrict__ W0, float* __restrict__ C0,
    const float* __restrict__ A1, const float* __restrict__ W1, float* __restrict__ C1,
    int M, int N, int K, int S) {
  __shared__ float As[16][132];
  __shared__ float Ws[16][132];
  int tid = threadIdx.x;
  int bm = blockIdx.y * 128, bn = blockIdx.x * 128;
  int pair = (int)blockIdx.z >= S;
  int zi = blockIdx.z - pair * S;
  const float* A = pair ? A1 : A0;
  const float* W = pair ? W1 : W0;
  float* C = pair ? C1 : C0;
  int kper = K / S;
  int kb = zi * kper, ke = kb + kper;
  int lr = tid >> 1;
  int lh = (tid & 1) * 8;
  int tx = tid & 15, ty = tid >> 4;
  bool wok = (bn + lr < N);
  const float* arow = A + (size_t)(bm + lr) * K + lh;
  const float* wrow = W + (size_t)(bn + lr) * K + lh;
  float4 a0, a1, w0, w1;
  auto gload = [&](int k0) {
    a0 = *(const float4*)(arow + k0);
    a1 = *(const float4*)(arow + k0 + 4);
    w0 = make_float4(0.f, 0.f, 0.f, 0.f); w1 = w0;
    if (wok) {
      w0 = *(const float4*)(wrow + k0);
      w1 = *(const float4*)(wrow + k0 + 4);
    }
  };
  f32x4 acc0[8] = {}, acc1[8] = {};
  gload(kb);
  for (int k0 = kb; k0 < ke; k0 += 16) {
    __syncthreads();
    As[lh+0][lr]=a0.x; As[lh+1][lr]=a0.y; As[lh+2][lr]=a0.z; As[lh+3][lr]=a0.w;
    As[lh+4][lr]=a1.x; As[lh+5][lr]=a1.y; As[lh+6][lr]=a1.z; As[lh+7][lr]=a1.w;
    Ws[lh+0][lr]=w0.x; Ws[lh+1][lr]=w0.y; Ws[lh+2][lr]=w0.z; Ws[lh+3][lr]=w0.w;
    Ws[lh+4][lr]=w1.x; Ws[lh+5][lr]=w1.y; Ws[lh+6][lr]=w1.z; Ws[lh+7][lr]=w1.w;
    __syncthreads();
    if (k0 + 16 < ke) gload(k0 + 16);
#pragma unroll
    for (int kk = 0; kk < 16; ++kk) {
      f32x4 b0 = *(const f32x4*)&Ws[kk][tx * 4];
      f32x4 b1 = *(const f32x4*)&Ws[kk][64 + tx * 4];
      f32x4 al = *(const f32x4*)&As[kk][ty * 8];
      f32x4 ah = *(const f32x4*)&As[kk][ty * 8 + 4];
#pragma unroll
      for (int i = 0; i < 4; ++i) {
        acc0[i]     += splat4(al[i]) * b0;
        acc1[i]     += splat4(al[i]) * b1;
        acc0[i + 4] += splat4(ah[i]) * b0;
        acc1[i + 4] += splat4(ah[i]) * b1;
      }
    }
  }
#pragma unroll
  for (int i = 0; i < 8; ++i) {
    int row = bm + ty * 8 + i;
    float* crow = C + (size_t)row * N;
    int c0 = bn + tx * 4, c1 = bn + 64 + tx * 4;
    if (c0 + 3 < N) {
      atomicAdd(crow + c0 + 0, acc0[i][0]); atomicAdd(crow + c0 + 1, acc0[i][1]);
      atomicAdd(crow + c0 + 2, acc0[i][2]); atomicAdd(crow + c0 + 3, acc0[i][3]);
    }
    if (c1 + 3 < N) {
      atomicAdd(crow + c1 + 0, acc1[i][0]); atomicAdd(crow + c1 + 1, acc1[i][1]);
      atomicAdd(crow + c1 + 2, acc1[i][2]); atomicAdd(crow + c1 + 3, acc1[i][3]);
    }
  }
}

// ---------------- bf16 MFMA GEMM (double-buffered LDS: stage(t+1) || compute(t)) ----------------
// T1: XCD-aware (x,y) tile swizzle (identity fallback when nwg%8!=0).
// T3-min: 2-deep pipeline (structure-bound at ~445 TF for the 2048-class shapes).
__global__ __launch_bounds__(256) void gemm_bf16_kernel(
    const unsigned short* __restrict__ A, const unsigned short* __restrict__ W,
    float* __restrict__ C, int M, int N, int K, int lda, int ldb, int ldc) {
  __shared__ unsigned short As[2][128 * 64];
  __shared__ unsigned short Ws[2][128 * 64];
  int tid = threadIdx.x;
  int bx = blockIdx.x, by = blockIdx.y;
  int nxy = gridDim.x * gridDim.y;
  if ((nxy & 7) == 0) {
    int lin = by * gridDim.x + bx;
    int cpx = nxy >> 3;
    int swz = (lin & 7) * cpx + (lin >> 3);
    bx = swz % gridDim.x;
    by = swz / gridDim.x;
  }
  int bm = by * 128, bn = bx * 128;
  int kper = K / gridDim.z;
  int k_begin = blockIdx.z * kper;
  int k_end = k_begin + kper;
  int wv = tid >> 6, lane = tid & 63;
  int wrow = (wv >> 1) * 64, wcol = (wv & 1) * 64;
  int lrow = lane & 15, quad = lane >> 4;

  f32x4 acc[4][4] = {};

  auto stage = [&](int b, int k0) {
#pragma unroll
    for (int it = 0; it < 4; ++it) {
      int s = it * 256 + tid;
      int r = s >> 3;
      int q = (s & 7) ^ (r & 7);
      const unsigned short* ga = A + (size_t)(bm + r) * lda + k0 + q * 8;
      const unsigned short* gw = W + (size_t)(bn + r) * ldb + k0 + q * 8;
      __builtin_amdgcn_global_load_lds((const __attribute__((address_space(1))) void*)ga,
                                       (__attribute__((address_space(3))) void*)&As[b][s * 8], 16, 0, 0);
      __builtin_amdgcn_global_load_lds((const __attribute__((address_space(1))) void*)gw,
                                       (__attribute__((address_space(3))) void*)&Ws[b][s * 8], 16, 0, 0);
    }
  };

  stage(0, k_begin);
  int cur = 0;
  for (int k0 = k_begin; k0 < k_end; k0 += 64) {
    __syncthreads();
    if (k0 + 64 < k_end) stage(cur ^ 1, k0 + 64);
#pragma unroll
    for (int ks = 0; ks < 2; ++ks) {
      bf16x8 af[4], wf[4];
#pragma unroll
      for (int i = 0; i < 4; ++i) {
        int ra = wrow + i * 16 + lrow;
        int qa = (ks * 4 + quad) ^ (ra & 7);
        af[i] = *(const bf16x8*)&As[cur][(ra * 8 + qa) * 8];
        int rw = wcol + i * 16 + lrow;
        int qw = (ks * 4 + quad) ^ (rw & 7);
        wf[i] = *(const bf16x8*)&Ws[cur][(rw * 8 + qw) * 8];
      }
#pragma unroll
      for (int i = 0; i < 4; ++i)
#pragma unroll
        for (int j = 0; j < 4; ++j)
          acc[i][j] = __builtin_amdgcn_mfma_f32_16x16x32_bf16(af[i], wf[j], acc[i][j], 0, 0, 0);
    }
    cur ^= 1;
  }
  bool single = (gridDim.z == 1);
#pragma unroll
  for (int i = 0; i < 4; ++i)
#pragma unroll
    for (int j = 0; j < 4; ++j)
#pragma unroll
      for (int r = 0; r < 4; ++r) {
        int row = bm + wrow + i * 16 + quad * 4 + r;
        int col = bn + wcol + j * 16 + lrow;
        float v = acc[i][j][r];
        if (single) C[(size_t)row * ldc + col] = v;
        else atomicAdd(&C[(size_t)row * ldc + col], v);
      }
}

// ---------------- 256^2-tile 8-wave bf16 GEMM with 4-cell half-K (32) pipeline ----------------
// T3/T4 port for in_proj only. 4 LDS cells of (256x32) A+B; 3 stage-units in flight;
// counted s_waitcnt vmcnt(12); raw s_barrier pairs per unit.
//   barrier#1: all waves done compute(u-1) -> cell(u+3)=cell(u-1) reusable (WAR)
//   stage(u+3): 4 gload_lds/thread (A rows via rd 0-1, B rows via rd 2-3)
//   vmcnt(12):  own-wave unit-u loads landed (16 in flight -> keep 12 newest)
//   barrier#2:  unit u visible to all waves (RAW, cross-wave staging)
// Swizzle: LDS dest linear in segment s (gload_lds constraint, rule #21); global src
// k-group = (s&3)^(r&3); read side slot = quad^(ra&3) — involution, 2-way banks (free).
// Always atomic epilogue (split-K via gridDim.z).
__global__ __launch_bounds__(512) void gemm_bf16_256_kernel(
    const unsigned short* __restrict__ A, const unsigned short* __restrict__ W,
    float* __restrict__ C, int K, int lda, int ldc) {
  __shared__ unsigned short As[4][256 * 32];
  __shared__ unsigned short Ws[4][256 * 32];
  int tid = threadIdx.x;
  int bx = blockIdx.x, by = blockIdx.y;
  int nxy = gridDim.x * gridDim.y;
  if ((nxy & 7) == 0) {
    int lin = by * gridDim.x + bx;
    int cpx = nxy >> 3;
    int swz = (lin & 7) * cpx + (lin >> 3);
    bx = swz % gridDim.x;
    by = swz / gridDim.x;
  }
  int bm = by * 256, bn = bx * 256;
  int kper = K / gridDim.z;
  int kb = blockIdx.z * kper;
  int U = kper >> 5;                 // number of 32-k units (>= 4 required)
  int wave = tid >> 6, lane = tid & 63;
  int wr = wave >> 2, wc = wave & 3; // wave tile: 128 rows x 64 cols
  int lrow = lane & 15, quad = lane >> 4;

  f32x4 acc[8][4] = {};

  auto stage = [&](int cell, int u) {
    int k0 = kb + (u << 5);
#pragma unroll
    for (int rd = 0; rd < 2; ++rd) {
      int s = rd * 512 + tid;        // A segments 0..1023 (rows 0..255, 4 segs/row)
      int r = s >> 2;
      int q = (s & 3) ^ (r & 3);
      const unsigned short* ga = A + (size_t)(bm + r) * lda + k0 + q * 8;
      __builtin_amdgcn_global_load_lds((const __attribute__((address_space(1))) void*)ga,
          (__attribute__((address_space(3))) void*)&As[cell][s * 8], 16, 0, 0);
    }
#pragma unroll
    for (int rd = 0; rd < 2; ++rd) {
      int s = rd * 512 + tid;        // B segments, same layout
      int r = s >> 2;
      int q = (s & 3) ^ (r & 3);
      const unsigned short* gw = W + (size_t)(bn + r) * lda + k0 + q * 8;
      __builtin_amdgcn_global_load_lds((const __attribute__((address_space(1))) void*)gw,
          (__attribute__((address_space(3))) void*)&Ws[cell][s * 8], 16, 0, 0);
    }
  };

  auto compute = [&](int cell) {
    bf16x8 af[8], wf[4];
#pragma unroll
    for (int m = 0; m < 8; ++m) {
      int ra = wr * 128 + m * 16 + lrow;
      af[m] = *(const bf16x8*)&As[cell][((ra << 2) + (quad ^ (ra & 3))) * 8];
    }
#pragma unroll
    for (int n = 0; n < 4; ++n) {
      int rw = wc * 64 + n * 16 + lrow;
      wf[n] = *(const bf16x8*)&Ws[cell][((rw << 2) + (quad ^ (rw & 3))) * 8];
    }
#pragma unroll
    for (int m = 0; m < 8; ++m)
#pragma unroll
      for (int n = 0; n < 4; ++n)
        acc[m][n] = __builtin_amdgcn_mfma_f32_16x16x32_bf16(af[m], wf[n], acc[m][n], 0, 0, 0);
  };

  stage(0, 0); stage(1, 1); stage(2, 2);
  for (int u = 0; u + 3 < U; ++u) {
    __builtin_amdgcn_s_barrier();                       // (1) prev compute done everywhere
    asm volatile("" ::: "memory");
    stage((u + 3) & 3, u + 3);
    asm volatile("s_waitcnt vmcnt(12)" ::: "memory");   // unit u landed (own loads)
    __builtin_amdgcn_s_barrier();                       // (2) unit u landed for all waves
    asm volatile("" ::: "memory");
    compute(u & 3);
  }
  for (int u = U - 3; u < U; ++u) {                     // tail: conservative full drain
    __builtin_amdgcn_s_barrier();
    asm volatile("s_waitcnt vmcnt(0)" ::: "memory");
    __builtin_amdgcn_s_barrier();
    asm volatile("" ::: "memory");
    compute(u & 3);
  }

#pragma unroll
  for (int m = 0; m < 8; ++m)
#pragma unroll
    for (int n = 0; n < 4; ++n)
#pragma unroll
      for (int rr = 0; rr < 4; ++rr) {
        int row = bm + wr * 128 + m * 16 + quad * 4 + rr;
        int col = bn + wc * 64 + n * 16 + lrow;
        atomicAdd(&C[(size_t)row * ldc + col], acc[m][n][rr]);
      }
}

// ---------------- dual bf16 MFMA GEMM: q_up + kv_up in one launch ----------------
__global__ __launch_bounds__(256) void gemm_bf16_dual(
    const unsigned short* __restrict__ A0, const unsigned short* __restrict__ W0,
    float* __restrict__ C0,
    const unsigned short* __restrict__ A1, const unsigned short* __restrict__ W1,
    float* __restrict__ C1,
    int nx0, int ldc0, int ldc1, int K, int ld) {
  __shared__ unsigned short As[2][128 * 64];
  __shared__ unsigned short Ws[2][128 * 64];
  int tid = threadIdx.x;
  int bx = blockIdx.x, by = blockIdx.y;
  int pair = bx >= nx0;
  int bxl = pair ? bx - nx0 : bx;
  const unsigned short* A = pair ? A1 : A0;
  const unsigned short* W = pair ? W1 : W0;
  float* C = pair ? C1 : C0;
  int ldc = pair ? ldc1 : ldc0;
  int bm = by * 128, bn = bxl * 128;
  int wv = tid >> 6, lane = tid & 63;
  int wrow = (wv >> 1) * 64, wcol = (wv & 1) * 64;
  int lrow = lane & 15, quad = lane >> 4;

  f32x4 acc[4][4] = {};

  auto stage = [&](int b, int k0) {
#pragma unroll
    for (int it = 0; it < 4; ++it) {
      int s = it * 256 + tid;
      int r = s >> 3;
      int q = (s & 7) ^ (r & 7);
      const unsigned short* ga = A + (size_t)(bm + r) * ld + k0 + q * 8;
      const unsigned short* gw = W + (size_t)(bn + r) * ld + k0 + q * 8;
      __builtin_amdgcn_global_load_lds((const __attribute__((address_space(1))) void*)ga,
                                       (__attribute__((address_space(3))) void*)&As[b][s * 8], 16, 0, 0);
      __builtin_amdgcn_global_load_lds((const __attribute__((address_space(1))) void*)gw,
                                       (__attribute__((address_space(3))) void*)&Ws[b][s * 8], 16, 0, 0);
    }
  };

  stage(0, 0);
  int cur = 0;
  for (int k0 = 0; k0 < K; k0 += 64) {
    __syncthreads();
    if (k0 + 64 < K) stage(cur ^ 1, k0 + 64);
#pragma unroll
    for (int ks = 0; ks < 2; ++ks) {
      bf16x8 af[4], wf[4];
#pragma unroll
      for (int i = 0; i < 4; ++i) {
        int ra = wrow + i * 16 + lrow;
        int qa = (ks * 4 + quad) ^ (ra & 7);
        af[i] = *(const bf16x8*)&As[cur][(ra * 8 + qa) * 8];
        int rw = wcol + i * 16 + lrow;
        int qw = (ks * 4 + quad) ^ (rw & 7);
        wf[i] = *(const bf16x8*)&Ws[cur][(rw * 8 + qw) * 8];
      }
#pragma unroll
      for (int i = 0; i < 4; ++i)
#pragma unroll
        for (int j = 0; j < 4; ++j)
          acc[i][j] = __builtin_amdgcn_mfma_f32_16x16x32_bf16(af[i], wf[j], acc[i][j], 0, 0, 0);
    }
    cur ^= 1;
  }
#pragma unroll
  for (int i = 0; i < 4; ++i)
#pragma unroll
    for (int j = 0; j < 4; ++j)
#pragma unroll
      for (int r = 0; r < 4; ++r) {
        int row = bm + wrow + i * 16 + quad * 4 + r;
        int col = bn + wcol + j * 16 + lrow;
        C[(size_t)row * ldc + col] = acc[i][j][r];
      }
}

// ---------------- fused weight-prep: tripA + tripW + 6x caugW + transpose(idx_out_w) ----------------
__global__ __launch_bounds__(256) void prep_weights_kernel(
    const float* __restrict__ x, unsigned short* __restrict__ x_trip,
    const float* __restrict__ idx_in_w, unsigned short* __restrict__ w_in_trip,
    const float* __restrict__ q_down_w, const float* __restrict__ kv_down_w,
    const float* __restrict__ k_rope_w, unsigned short* __restrict__ w3down,
    const float* __restrict__ q_up_w, const float* __restrict__ q_rope_w,
    unsigned short* __restrict__ wqups,
    const float* __restrict__ kv_up_w, unsigned short* __restrict__ wkvup,
    const float* __restrict__ idx_out_w, float* __restrict__ out_w_T) {
  __shared__ float tsh[32][33];
  int bid = blockIdx.x;
  if (bid >= 20736) {
    int b = bid - 20736;
    int bx = b & 31, by = b >> 5;
    int tx = threadIdx.x & 31, ty8 = threadIdx.x >> 5;
    for (int r = ty8; r < 32; r += 8)
      tsh[r][tx] = idx_out_w[(size_t)(by * 32 + r) * 1024 + bx * 32 + tx];
    __syncthreads();
    for (int r = ty8; r < 32; r += 8)
      out_w_T[(size_t)(bx * 32 + r) * 1024 + by * 32 + tx] = tsh[tx][r];
    return;
  }
  int i = bid * 256 + threadIdx.x;
  if (i < 2097152) {
    float f = x[i];
    unsigned short h = f2bf(f);
    float r1 = f - bf2f(h);
    unsigned short m = f2bf(r1);
    unsigned short l = f2bf(r1 - bf2f(m));
    size_t o = (size_t)i * 6;
    x_trip[o] = h; x_trip[o + 1] = m; x_trip[o + 2] = l;
    x_trip[o + 3] = h; x_trip[o + 4] = m; x_trip[o + 5] = h;
  } else if (i < 4456448) {
    int j = i - 2097152;
    int n = j >> 10, k = j & 1023;
    unsigned short h = 0, m = 0, l = 0;
    if (n < 2208) {
      float f = idx_in_w[(size_t)n * 1024 + k];
      h = f2bf(f);
      float r1 = f - bf2f(h);
      m = f2bf(r1);
      l = f2bf(r1 - bf2f(m));
    }
    size_t o = (size_t)j * 6;
    w_in_trip[o] = h; w_in_trip[o + 1] = h; w_in_trip[o + 2] = h;
    w_in_trip[o + 3] = m; w_in_trip[o + 4] = m; w_in_trip[o + 5] = l;
  } else {
    int j2 = i - 4456448;
    const float* src; unsigned short* dst; int rows, K; size_t obase; int idx;
    if (j2 < 393216) {
      int r = j2 >> 17;
      idx = j2 & 131071;
      K = 1024;
      src = (r == 0) ? q_down_w : (r == 1) ? kv_down_w : k_rope_w;
      rows = (r == 2) ? 32 : 128;
      dst = w3down; obase = (size_t)(r * 131072 + idx) * 3;
    } else if (j2 < 524288) {
      idx = j2 - 393216; K = 128; src = q_up_w; rows = 1024;
      dst = wqups; obase = (size_t)idx * 3;
    } else if (j2 < 589824) {
      idx = j2 - 524288; K = 128; src = q_rope_w; rows = 512;
      dst = wqups; obase = (size_t)393216 + (size_t)idx * 3;
    } else {
      idx = j2 - 589824; K = 128; src = kv_up_w; rows = 2048;
      dst = wkvup; obase = (size_t)idx * 3;
    }
    int n = idx / K, k = idx - n * K;
    unsigned short hi = 0, lo = 0;
    if (n < rows) {
      float f = src[(size_t)n * K + k];
      hi = f2bf(f);
      lo = f2bf(f - bf2f(hi));
    }
    dst[obase] = hi; dst[obase + 1] = hi; dst[obase + 2] = lo;
  }
}

// ---------------- fused post-in_proj: caugW(out_w) + conv_silu + dt ----------------
__global__ __launch_bounds__(256) void post_inproj_kernel(
    const float* __restrict__ out_w, unsigned short* __restrict__ w_outp,
    const float* __restrict__ zxbcdt, const float* __restrict__ conv_w,
    const float* __restrict__ conv_b, float* __restrict__ xBC,
    const float* __restrict__ dt_bias, const float* __restrict__ A_log,
    float* __restrict__ dt, float* __restrict__ logdA) {
  int i = blockIdx.x * 256 + threadIdx.x;
  if (i < 1048576) {
    float f = out_w[i];
    unsigned short hi = f2bf(f);
    unsigned short lo = f2bf(f - bf2f(hi));
    size_t o = (size_t)i * 3;
    w_outp[o] = hi; w_outp[o + 1] = hi; w_outp[o + 2] = lo;
  } else if (i < 3407872) {
    int idx = i - 1048576;
    int l = idx / CONVCH, c = idx - l * CONVCH;
    float acc = conv_b[c];
#pragma unroll
    for (int k = 0; k < 4; ++k) {
      int ls = l - 3 + k;
      if (ls >= 0) acc += zxbcdt[(size_t)ls * INDIMP + DINNER + c] * conv_w[c * 4 + k];
    }
    xBC[idx] = acc / (1.f + expf(-acc));
  } else {
    int idx = i - 3407872;
    int l = idx >> 5, h = idx & 31;
    float xv = zxbcdt[(size_t)l * INDIMP + 2176 + h] + dt_bias[h];
    float sp = fmaxf(xv, 0.f) + log1pf(expf(-fabsf(xv)));
    dt[idx] = sp;
    logdA[idx] = sp * -expf(A_log[h]);
  }
}

// ---------------- conversions ----------------
__global__ __launch_bounds__(256) void conv_augA_kernel(
    const float* __restrict__ src, unsigned short* __restrict__ dst,
    int total, int K, int sld) {
  int i = blockIdx.x * 256 + threadIdx.x;
  if (i >= total) return;
  int m = i / K, k = i - m * K;
  float f = src[(size_t)m * sld + k];
  unsigned short hi = f2bf(f);
  unsigned short lo = f2bf(f - bf2f(hi));
  size_t o = ((size_t)m * K + k) * 3;
  dst[o] = hi; dst[o + 1] = lo; dst[o + 2] = hi;
}
__global__ __launch_bounds__(256) void conv_augA2_kernel(
    const float* __restrict__ c3, unsigned short* __restrict__ dq,
    unsigned short* __restrict__ dkv) {
  int i = blockIdx.x * 256 + threadIdx.x;
  if (i >= 2048 * 256) return;
  int m = i >> 8, k = i & 255;
  float f = c3[(size_t)m * 384 + k];
  unsigned short hi = f2bf(f);
  unsigned short lo = f2bf(f - bf2f(hi));
  if (k < 128) {
    size_t o = ((size_t)m * 128 + k) * 3;
    dq[o] = hi; dq[o + 1] = lo; dq[o + 2] = hi;
  } else {
    size_t o = ((size_t)m * 128 + (k - 128)) * 3;
    dkv[o] = hi; dkv[o + 1] = lo; dkv[o + 2] = hi;
  }
}

// ---------------- G[c][t][s] = C_t . B_s  (+ lcd region in blocks 32..35) ----------------
__global__ __launch_bounds__(256) void chunk_G_kernel(
    const float* __restrict__ xBC, float* __restrict__ G,
    const float* __restrict__ logdA, float* __restrict__ lcd) {
  int c = blockIdx.x, tid = threadIdx.x;
  if (c >= NCH) {
    int i = (c - NCH) * 256 + tid;
    int cc = i >> 5, h = i & 31;
    float s = 0.f;
    for (int t = 0; t < CHUNK; ++t) {
      s += logdA[(cc * CHUNK + t) * MNH + h];
      lcd[(size_t)i * CHUNK + t] = s;
    }
    return;
  }
  __shared__ float BsT[64][68];
  __shared__ float Cs[64][65];
  int t = tid >> 2, q = tid & 3;
  const float* row = xBC + (size_t)(c * 64 + t) * CONVCH + DINNER;
#pragma unroll
  for (int j = 0; j < 16; j += 4) {
    float4 b = *(const float4*)(row + q * 16 + j);
    BsT[q * 16 + j + 0][t] = b.x; BsT[q * 16 + j + 1][t] = b.y;
    BsT[q * 16 + j + 2][t] = b.z; BsT[q * 16 + j + 3][t] = b.w;
    float4 cv = *(const float4*)(row + 64 + q * 16 + j);
    Cs[t][q * 16 + j + 0] = cv.x; Cs[t][q * 16 + j + 1] = cv.y;
    Cs[t][q * 16 + j + 2] = cv.z; Cs[t][q * 16 + j + 3] = cv.w;
  }
  __syncthreads();
  int s0 = q * 16;
  f32x4 g0 = {}, g1 = {}, g2 = {}, g3 = {};
  for (int n = 0; n < 64; ++n) {
    f32x4 cv = splat4(Cs[t][n]);
    g0 += cv * *(const f32x4*)&BsT[n][s0];
    g1 += cv * *(const f32x4*)&BsT[n][s0 + 4];
    g2 += cv * *(const f32x4*)&BsT[n][s0 + 8];
    g3 += cv * *(const f32x4*)&BsT[n][s0 + 12];
  }
  float* gp = G + ((size_t)c * 64 + t) * 64 + s0;
  *(f32x4*)gp = g0; *(f32x4*)(gp + 4) = g1; *(f32x4*)(gp + 8) = g2; *(f32x4*)(gp + 12) = g3;
}

// ---------------- scan pass A ----------------
__global__ __launch_bounds__(256) void scan_local_kernel(
    const float* __restrict__ xBC, const float* __restrict__ dt,
    const float* __restrict__ lcd, float* __restrict__ hstate) {
  int c = blockIdx.x >> 5, h = blockIdx.x & 31;
  int tid = threadIdx.x;
  __shared__ float Bs[64][68];
  __shared__ float xss[64][36];
  __shared__ float w2s[64];
  int t0 = c * CHUNK;
  int t = tid >> 2, q = tid & 3;
  const float* row = xBC + (size_t)(t0 + t) * CONVCH;
#pragma unroll
  for (int j = 0; j < 16; j += 4)
    *(float4*)&Bs[t][q * 16 + j] = *(const float4*)(row + DINNER + q * 16 + j);
  if (q < 2) {
#pragma unroll
    for (int j = 0; j < 16; j += 4)
      *(float4*)&xss[t][q * 16 + j] = *(const float4*)(row + h * 32 + q * 16 + j);
  }
  if (tid < 64) {
    const float* lc = lcd + ((size_t)c * 32 + h) * CHUNK;
    w2s[tid] = expf(lc[63] - lc[tid]) * dt[(t0 + tid) * MNH + h];
  }
  __syncthreads();
  int n = tid >> 2, pg = (tid & 3) * 8;
  f32x4 h0 = {}, h1 = {};
  for (int s = 0; s < 64; ++s) {
    f32x4 wb = splat4(w2s[s] * Bs[s][n]);
    h0 += wb * *(const f32x4*)&xss[s][pg];
    h1 += wb * *(const f32x4*)&xss[s][pg + 4];
  }
  float* hp = hstate + ((size_t)c * 32 + h) * 2048 + n * 32 + pg;
  *(f32x4*)hp = h0; *(f32x4*)(hp + 4) = h1;
}

// ---------------- scan pass B ----------------
__global__ __launch_bounds__(256) void scan_combine_kernel(
    float* __restrict__ hstate, const float* __restrict__ lcd) {
  int i = blockIdx.x * 256 + threadIdx.x;
  int h = i >> 11;
  float H = 0.f;
  for (int c = 0; c < NCH; ++c) {
    float hl = hstate[(size_t)c * 65536 + i];
    hstate[(size_t)c * 65536 + i] = H;
    float P = expf(lcd[((size_t)c * 32 + h) * CHUNK + CHUNK - 1]);
    H = H * P + hl;
  }
}

// ---------------- scan pass C ----------------
__global__ __launch_bounds__(256) void scan_y_kernel(
    const float* __restrict__ xBC, const float* __restrict__ G,
    const float* __restrict__ dt, const float* __restrict__ lcd,
    const float* __restrict__ hstate, float* __restrict__ y) {
  int c = blockIdx.x >> 5, h = blockIdx.x & 31;
  int tid = threadIdx.x;
  __shared__ float Ms[64][65];
  __shared__ float Cs[64][65];
  __shared__ float xss[64][36];
  __shared__ float Hss[64][36];
  __shared__ float lcds[64], dts[64];
  int t0 = c * CHUNK;
  int t = tid >> 2, q = tid & 3;
  const float* row = xBC + (size_t)(t0 + t) * CONVCH;
#pragma unroll
  for (int j = 0; j < 16; j += 4) {
    float4 cv = *(const float4*)(row + DINNER + 64 + q * 16 + j);
    Cs[t][q * 16 + j + 0] = cv.x; Cs[t][q * 16 + j + 1] = cv.y;
    Cs[t][q * 16 + j + 2] = cv.z; Cs[t][q * 16 + j + 3] = cv.w;
  }
  if (q < 2) {
#pragma unroll
    for (int j = 0; j < 16; j += 4)
      *(float4*)&xss[t][q * 16 + j] = *(const float4*)(row + h * 32 + q * 16 + j);
  }
  {
    const float* gp = G + ((size_t)c * 64 + t) * 64 + q * 16;
#pragma unroll
    for (int j = 0; j < 16; j += 4) {
      float4 g = *(const float4*)(gp + j);
      Ms[t][q * 16 + j + 0] = g.x; Ms[t][q * 16 + j + 1] = g.y;
      Ms[t][q * 16 + j + 2] = g.z; Ms[t][q * 16 + j + 3] = g.w;
    }
  }
  {
    const float* hp = hstate + ((size_t)c * 32 + h) * 2048 + tid * 8;
    int n = tid >> 2, p0 = (tid & 3) * 8;
    *(float4*)&Hss[n][p0]     = *(const float4*)hp;
    *(float4*)&Hss[n][p0 + 4] = *(const float4*)(hp + 4);
  }
  if (tid < 64) {
    lcds[tid] = lcd[((size_t)c * 32 + h) * CHUNK + tid];
    dts[tid]  = dt[(t0 + tid) * MNH + h];
  }
  __syncthreads();
  {
    int s0 = q * 16;
#pragma unroll
    for (int j = 0; j < 16; ++j) {
      int s = s0 + j;
      float m = (s <= t) ? expf(lcds[t] - lcds[s]) * dts[s] * Ms[t][s] : 0.f;
      Ms[t][s] = m;
    }
  }
  __syncthreads();
  int pg = q * 8;
  f32x4 y0 = {}, y1 = {}, a0 = {}, a1 = {};
  for (int s = 0; s < 64; ++s) {
    f32x4 m = splat4(Ms[t][s]);
    y0 += m * *(const f32x4*)&xss[s][pg];
    y1 += m * *(const f32x4*)&xss[s][pg + 4];
  }
  for (int n = 0; n < 64; ++n) {
    f32x4 cn = splat4(Cs[t][n]);
    a0 += cn * *(const f32x4*)&Hss[n][pg];
    a1 += cn * *(const f32x4*)&Hss[n][pg + 4];
  }
  f32x4 cd = splat4(expf(lcds[t]));
  y0 += cd * a0; y1 += cd * a1;
  float* yp = y + (size_t)(t0 + t) * DINNER + h * 32 + pg;
  *(f32x4*)yp = y0; *(f32x4*)(yp + 4) = y1;
}

// ---------------- gate + RMSNorm ----------------
__global__ __launch_bounds__(256) void gatenorm_kernel(
    const float* __restrict__ y_ssm, const float* __restrict__ xBC,
    const float* __restrict__ zxbcdt, const float* __restrict__ Dv,
    const float* __restrict__ norm_w, float* __restrict__ out) {
  int l = blockIdx.x, tid = threadIdx.x;
  float vals[4];
  float ss = 0.f;
#pragma unroll
  for (int i = 0; i < 4; ++i) {
    int d = tid + i * 256;
    int h = d >> 5;
    float v = y_ssm[(size_t)l * DINNER + d] + Dv[h] * xBC[(size_t)l * CONVCH + d];
    float z = zxbcdt[(size_t)l * INDIMP + d];
    v *= z / (1.f + expf(-z));
    vals[i] = v;
    ss += v * v;
  }
#pragma unroll
  for (int off = 32; off > 0; off >>= 1) ss += __shfl_xor(ss, off);
  __shared__ float sred[4];
  if ((tid & 63) == 0) sred[tid >> 6] = ss;
  __syncthreads();
  float tot = sred[0] + sred[1] + sred[2] + sred[3];
  float scale = rsqrtf(tot * (1.f / 1024.f) + 1e-5f);
#pragma unroll
  for (int i = 0; i < 4; ++i) {
    int d = tid + i * 256;
    out[(size_t)l * DINNER + d] = vals[i] * scale * norm_w[d];
  }
}

// ---------------- per-row top-64 radix select (R4-verified global-scan) ----------------
__global__ __launch_bounds__(256) void topk_kernel(
    const float* __restrict__ scores, int* __restrict__ out_idx) {
  int l = blockIdx.x, tid = threadIdx.x;
  if (l < 64) {
    if (tid < 64) out_idx[l * 64 + tid] = tid;
    return;
  }
  int n = l + 1;
  const float* row = scores + (size_t)l * L;
  __shared__ int hist[256];
  __shared__ unsigned sel_prefix;
  __shared__ int sel_remaining;
  __shared__ int cnt_g, cnt_e;
  __shared__ int eq_list[128];
  if (tid == 0) { cnt_g = 0; cnt_e = 0; }
  unsigned prefix = 0;
  int remaining = 64;
  for (int pass = 0; pass < 4; ++pass) {
    int shift = 24 - 8 * pass;
    unsigned himask = (pass == 0) ? 0u : (0xFFFFFFFFu << (shift + 8));
    hist[tid] = 0;
    __syncthreads();
    for (int j = tid; j < n; j += 256) {
      unsigned u = __float_as_uint(row[j]);
      unsigned key = (u & 0x80000000u) ? ~u : (u | 0x80000000u);
      if (((key ^ prefix) & himask) == 0)
        atomicAdd(&hist[(key >> shift) & 255], 1);
    }
    __syncthreads();
    if (tid == 0) {
      int cum = 0, b = 255;
      for (; b >= 0; --b) {
        cum += hist[b];
        if (cum >= remaining) break;
      }
      sel_prefix = prefix | ((unsigned)b << shift);
      sel_remaining = remaining - (cum - hist[b]);
    }
    __syncthreads();
    prefix = sel_prefix;
    remaining = sel_remaining;
    __syncthreads();
  }
  unsigned T = prefix;
  for (int j = tid; j < n; j += 256) {
    unsigned u = __float_as_uint(row[j]);
    unsigned key = (u & 0x80000000u) ? ~u : (u | 0x80000000u);
    if (key > T) {
      int p = atomicAdd(&cnt_g, 1);
      out_idx[l * 64 + p] = j;
    } else if (key == T) {
      int p = atomicAdd(&cnt_e, 1);
      if (p < 128) eq_list[p] = j;
    }
  }
  __syncthreads();
  if (tid == 0) {
    int G = cnt_g;
    int E = remaining;
    int m = cnt_e < 128 ? cnt_e : 128;
    for (int e = 0; e < E; ++e) {
      int best = 0, bj = 0x7fffffff;
      for (int i = 0; i < m; ++i)
        if (eq_list[i] < bj) { bj = eq_list[i]; best = i; }
      out_idx[l * 64 + G + e] = bj;
      eq_list[best] = 0x7fffffff;
    }
  }
}

// ---------------- RoPE + pack q_final/k_final (fused-buffer strides) ----------------
__global__ __launch_bounds__(128) void rope_pack_kernel(
    const float* __restrict__ qbuf, const float* __restrict__ kv,
    const float* __restrict__ c3,
    float* __restrict__ q_final, float* __restrict__ k_final) {
  int l = blockIdx.x, tid = threadIdx.x;
  __shared__ float s_s[16], s_c[16];
  if (tid < 16) {
    float inv = powf(10000.f, -(float)tid / 16.f);
    float ang = (float)l * inv;
    s_s[tid] = sinf(ang);
    s_c[tid] = cosf(ang);
  }
  __syncthreads();
  const float* qrow = qbuf + (size_t)l * 1536;
  const float* krow = c3 + (size_t)l * 384 + 256;
  for (int e = tid; e < NH * 96; e += 128) {
    int hh = e / 96, d = e - hh * 96;
    float qv, kvv;
    if (d < 64) {
      qv  = qrow[hh * 64 + d];
      kvv = kv[(size_t)l * 2048 + hh * 64 + d];
    } else {
      int r = d - 64;
      if (r < 16) {
        float q1 = qrow[1024 + hh * 32 + r];
        float q2 = qrow[1024 + hh * 32 + 16 + r];
        qv = q1 * s_c[r] - q2 * s_s[r];
        float k1 = krow[r];
        float k2 = krow[16 + r];
        kvv = k1 * s_c[r] - k2 * s_s[r];
      } else {
        int rr = r - 16;
        float q1 = qrow[1024 + hh * 32 + rr];
        float q2 = qrow[1024 + hh * 32 + 16 + rr];
        qv = q1 * s_s[rr] + q2 * s_c[rr];
        float k1 = krow[rr];
        float k2 = krow[16 + rr];
        kvv = k1 * s_s[rr] + k2 * s_c[rr];
      }
    }
    q_final[(size_t)l * 1536 + e] = qv;
    k_final[(size_t)l * 1536 + e] = kvv;
  }
}

// ---------------- sparse attention (coalesced, one block per row) ----------------
__global__ __launch_bounds__(256) void attn_kernel(
    const float* __restrict__ q_final, const float* __restrict__ k_final,
    const float* __restrict__ kv, const int* __restrict__ idx,
    unsigned short* __restrict__ attn_aug) {
  int b = blockIdx.x;
  int l = (b & 7) * 256 + (b >> 3);
  int tid = threadIdx.x;
  int h = tid >> 4;
  int s = tid & 15;
  __shared__ __align__(16) float lg[16][64];
  __shared__ int iks[64];

  if (tid < 64) iks[tid] = idx[l * 64 + tid];

  const float* qrow = q_final + (size_t)l * 1536 + h * 96 + s * 2;
  float q0 = qrow[0],  q1 = qrow[1];
  float q2 = qrow[32], q3 = qrow[33];
  float q4 = qrow[64], q5 = qrow[65];
  __syncthreads();

#pragma unroll 4
  for (int k = 0; k < 64; ++k) {
    const float* kr = k_final + (size_t)iks[k] * 1536 + h * 96 + s * 2;
    float2 a = *(const float2*)kr;
    float2 b2 = *(const float2*)(kr + 32);
    float2 c = *(const float2*)(kr + 64);
    float d = q0 * a.x + q1 * a.y + q2 * b2.x + q3 * b2.y + q4 * c.x + q5 * c.y;
    d += __shfl_xor(d, 1);
    d += __shfl_xor(d, 2);
    d += __shfl_xor(d, 4);
    d += __shfl_xor(d, 8);
    if (s == 0) lg[h][k] = d * 0.10206207261596575f;
  }
  __syncthreads();

  f32x4 lv = *(const f32x4*)&lg[h][s * 4];
  float m = fmaxf(fmaxf(lv[0], lv[1]), fmaxf(lv[2], lv[3]));
#pragma unroll
  for (int off = 1; off < 16; off <<= 1) m = fmaxf(m, __shfl_xor(m, off));
  f32x4 ev;
  ev[0] = expf(lv[0] - m); ev[1] = expf(lv[1] - m);
  ev[2] = expf(lv[2] - m); ev[3] = expf(lv[3] - m);
  float ssum = ev[0] + ev[1] + ev[2] + ev[3];
#pragma unroll
  for (int off = 1; off < 16; off <<= 1) ssum += __shfl_xor(ssum, off);
  float inv = 1.f / ssum;
  lg[h][s * 4 + 0] = ev[0] * inv;
  lg[h][s * 4 + 1] = ev[1] * inv;
  lg[h][s * 4 + 2] = ev[2] * inv;
  lg[h][s * 4 + 3] = ev[3] * inv;
  __syncthreads();

  f32x4 acc = {};
#pragma unroll 4
  for (int k = 0; k < 64; ++k) {
    const float* vr = kv + (size_t)iks[k] * 2048 + 1024 + tid * 4;
    f32x4 v = *(const f32x4*)vr;
    acc += splat4(lg[h][k]) * v;
  }

#pragma unroll
  for (int i = 0; i < 4; ++i) {
    float a = acc[i];
    unsigned short hi = f2bf(a);
    unsigned short lo = f2bf(a - bf2f(hi));
    size_t o = ((size_t)l * 1024 + tid * 4 + i) * 3;
    attn_aug[o] = hi; attn_aug[o + 1] = lo; attn_aug[o + 2] = hi;
  }
}

// ---------------- host ----------------
extern "C" void kernel_launch(void* const* d_in, const int* in_sizes, int n_in,
                              void* d_out, int out_size, void* d_ws, size_t ws_size,
                              hipStream_t stream) {
  const float* x          = (const float*)d_in[0];
  const float* idx_in_w   = (const float*)d_in[1];
  const float* idx_conv_w = (const float*)d_in[2];
  const float* idx_conv_b = (const float*)d_in[3];
  const float* idx_dt_b   = (const float*)d_in[4];
  const float* idx_A_log  = (const float*)d_in[5];
  const float* idx_D      = (const float*)d_in[6];
  const float* idx_norm_w = (const float*)d_in[7];
  const float* idx_out_w  = (const float*)d_in[8];
  const float* idx_q_w    = (const float*)d_in[9];
  const float* idx_k_w    = (const float*)d_in[10];
  const float* q_down_w   = (const float*)d_in[11];
  const float* q_up_w     = (const float*)d_in[12];
  const float* q_rope_w   = (const float*)d_in[13];
  const float* kv_down_w  = (const float*)d_in[14];
  const float* kv_up_w    = (const float*)d_in[15];
  const float* k_rope_w   = (const float*)d_in[16];
  const float* out_w      = (const float*)d_in[17];
  float* out = (float*)d_out;

  float* p = (float*)d_ws;
  float* segA = p; p += 4718592;  // zxbcdt[2048x2304] | scores | qbuf
  float* segB = p; p += 2359296;  // xBC | {q_idx, k_idx, c3}
  float* dtb = p; p += 65536;
  float* logdA = p; p += 65536;
  float* lcdb = p; p += 65536;
  int*   idxb = (int*)p; p += 131072;
  float* segD = p; p += 4194304;  // y_ssm+hstate | kvb
  float* segBig1 = p; p += 6291456;  // x_trip | w_outp_aug (after in_proj)
  float* segBig2 = p; p += 7077888;  // w_in_trip | {y_norm|x_aug|q_final}@0, attn_aug@3145728
  float* segH = p; p += 3145728;     // {out_w_T,qwpad,Wq} | k_final
  unsigned short* w_3down_aug = (unsigned short*)p; p += 589824;
  unsigned short* w_qups_aug  = (unsigned short*)p; p += 294912;
  unsigned short* w_kvup_aug  = (unsigned short*)p; p += 393216;
  unsigned short* c_q_aug     = (unsigned short*)p; p += 393216;
  unsigned short* c_kv_aug    = (unsigned short*)p; p += 393216;
  float* Gbuf = p; p += 131072;

  float* zxbcdt = segA;
  float* scores = segA;
  float* qbuf   = segA;
  float* xBC    = segB;
  float* q_idx  = segB;
  float* k_idx  = segB + 131072;
  float* c3     = segB + 262144;
  float* y_ssm  = segD;
  float* hstate = segD + 2097152;
  float* kvb    = segD;
  unsigned short* x_trip     = (unsigned short*)segBig1;  // dead after in_proj
  unsigned short* w_outp_aug = (unsigned short*)segBig1;  // written after in_proj
  unsigned short* w_in_trip  = (unsigned short*)segBig2;  // dead after in_proj
  float* y_norm  = segBig2;                               // gatenorm..q_idx gemm
  unsigned short* x_aug = (unsigned short*)segBig2;       // after topk..down-proj
  float* q_final = segBig2;                               // rope_pack..attn
  unsigned short* attn_aug = (unsigned short*)(segBig2 + 3145728);
  float* out_w_T = segH;
  float* qwpad   = segH + 1048576;
  float* Wq      = segH + 1179648;
  float* k_final = segH;                                  // after q_idx gemm

  dim3 blk(256);
  auto cdiv = [](int a, int b) { return (a + b - 1) / b; };
  auto gemmf3 = [&](const float* A, const float* W, float* C, int M, int N, int K, int S, int tri) {
    dim3 grid(cdiv(N, 128), M / 128, S);
    hipLaunchKernelGGL(gemm_f32_v3, grid, blk, 0, stream, A, W, C, M, N, K, tri);
  };
  auto gemmb = [&](const unsigned short* A, const unsigned short* W, float* C,
                   int M, int N, int K, int lda, int ldb, int ldc, int S) {
    dim3 grid(N / 128, M / 128, S);
    hipLaunchKernelGGL(gemm_bf16_kernel, grid, blk, 0, stream, A, W, C, M, N, K, lda, ldb, ldc);
  };

  // ---- weight precomputes (prep includes the idx_out_w transpose region) ----
  hipLaunchKernelGGL(prep_weights_kernel, dim3(21760), blk, 0, stream,
                     x, x_trip, idx_in_w, w_in_trip,
                     q_down_w, kv_down_w, k_rope_w, w_3down_aug,
                     q_up_w, q_rope_w, w_qups_aug, kv_up_w, w_kvup_aug,
                     idx_out_w, out_w_T);
  hipMemsetAsync(qwpad, 0, 262144 * 4, stream);   // qwpad + adjacent Wq in one memset
  hipMemcpyAsync(qwpad, idx_q_w, (size_t)64 * 1024 * 4, hipMemcpyDeviceToDevice, stream);
  gemmf3(qwpad, out_w_T, Wq, 128, 1024, 1024, 8, 0);

  // ---- mamba branch: in_proj via 256^2 pipelined MFMA (S=3, atomic) ----
  hipMemsetAsync(zxbcdt, 0, (size_t)L * INDIMP * 4, stream);
  {
    dim3 grid(9, 8, 3);   // N=2304/256, M=2048/256, split-K 3 (K/S=2048 -> 64 units)
    hipLaunchKernelGGL(gemm_bf16_256_kernel, grid, dim3(512), 0, stream,
                       x_trip, w_in_trip, zxbcdt, 6144, 6144, INDIMP);
  }
  // fused: caugW(out_w -> segBig1, x_trip dead) + conv_silu + dt, one launch
  hipLaunchKernelGGL(post_inproj_kernel, dim3(13568), blk, 0, stream,
                     out_w, w_outp_aug, zxbcdt, idx_conv_w, idx_conv_b, xBC,
                     idx_dt_b, idx_A_log, dtb, logdA);
  // chunk_G + lcd region (blocks 32..35)
  hipLaunchKernelGGL(chunk_G_kernel, dim3(NCH + 4), blk, 0, stream,
                     xBC, Gbuf, logdA, lcdb);
  hipLaunchKernelGGL(scan_local_kernel, dim3(NCH * MNH), blk, 0, stream,
                     xBC, dtb, lcdb, hstate);
  hipLaunchKernelGGL(scan_combine_kernel, dim3(256), blk, 0, stream, hstate, lcdb);
  hipLaunchKernelGGL(scan_y_kernel, dim3(NCH * MNH), blk, 0, stream,
                     xBC, Gbuf, dtb, lcdb, hstate, y_ssm);
  hipLaunchKernelGGL(gatenorm_kernel, dim3(L), blk, 0, stream,
                     y_ssm, xBC, zxbcdt, idx_D, idx_norm_w, y_norm);

  // ---- index scores + topk (out-proj folded into Wq) ----
  hipMemsetAsync(q_idx, 0, 262144 * 4, stream);   // q_idx + adjacent k_idx in one memset
  {
    dim3 grid(1, 16, 32);  // 2 pairs x S=16
    hipLaunchKernelGGL(gemm_f32_dual, grid, blk, 0, stream,
                       y_norm, Wq, q_idx, x, idx_k_w, k_idx, 2048, 64, 1024, 16);
  }
  gemmf3(q_idx, k_idx, scores, 2048, 2048, 64, 1, 1);
  hipLaunchKernelGGL(topk_kernel, dim3(L), blk, 0, stream, scores, idxb);

  // ---- attention value path (aug split-bf16 MFMA) ----
  hipLaunchKernelGGL(conv_augA_kernel, dim3(cdiv(2048 * 1024, 256)), blk, 0, stream,
                     x, x_aug, 2048 * 1024, 1024, 1024);  // segBig2@0 (y_norm dead)
  hipMemsetAsync(c3, 0, 786432 * 4, stream);
  gemmb(x_aug, w_3down_aug, c3, 2048, 384, 3072, 3072, 3072, 384, 8);
  hipLaunchKernelGGL(conv_augA2_kernel, dim3(cdiv(2048 * 256, 256)), blk, 0, stream,
                     c3, c_q_aug, c_kv_aug);
  // fused: q_up (N=1536) + kv_up (N=2048) in one 28x16 launch
  {
    dim3 grid(28, 16, 1);
    hipLaunchKernelGGL(gemm_bf16_dual, grid, blk, 0, stream,
                       c_q_aug, w_qups_aug, qbuf,
                       c_kv_aug, w_kvup_aug, kvb,
                       12, 1536, 2048, 384, 384);
  }
  hipLaunchKernelGGL(rope_pack_kernel, dim3(L), dim3(128), 0, stream,
                     qbuf, kvb, c3, q_final, k_final);

  // ---- sparse attention + output projection ----
  hipLaunchKernelGGL(attn_kernel, dim3(L), blk, 0, stream,
                     q_final, k_final, kvb, idxb, attn_aug);
  hipMemsetAsync(out, 0, (size_t)out_size * 4, stream);
  gemmb(attn_aug, w_outp_aug, out, 2048, 1024, 3072, 3072, 3072, 1024, 4);
}

// Round 11
// 636.010 us; speedup vs baseline: 1.1551x; 1.0049x over previous
//
#include <hip/hip_runtime.h>
#include <math.h>

// ---------------- constants ----------------
constexpr int L      = 2048;
constexpr int NH     = 16;
constexpr int DINNER = 1024;
constexpr int MNH    = 32;
constexpr int CONVCH = 1152;
constexpr int INDIMP = 2304;   // padded stride for zxbcdt (2208 -> 2304, N%128)
constexpr int CHUNK  = 64;
constexpr int NCH    = 32;

using bf16x8 = __attribute__((ext_vector_type(8))) short;
using f32x4  = __attribute__((ext_vector_type(4))) float;

__device__ __forceinline__ f32x4 splat4(float x) { return (f32x4){x, x, x, x}; }

__device__ __forceinline__ unsigned short f2bf(float f) {
  unsigned u = __float_as_uint(f);
  return (unsigned short)((u + 0x7fffu + ((u >> 16) & 1u)) >> 16);
}
__device__ __forceinline__ float bf2f(unsigned short h) {
  return __uint_as_float((unsigned)h << 16);
}

// ---------------- fp32 GEMM v3 (small index-critical shapes) ----------------
// tri=1: skip blocks fully above the causal diagonal (outputs never read by topk).
__global__ __launch_bounds__(256) void gemm_f32_v3(
    const float* __restrict__ A, const float* __restrict__ W,
    float* __restrict__ C, int M, int N, int K, int tri) {
  __shared__ float As[16][132];
  __shared__ float Ws[16][132];
  int tid = threadIdx.x;
  int bm = blockIdx.y * 128, bn = blockIdx.x * 128;
  if (tri && bn > bm + 127) return;
  int kper = K / gridDim.z;
  int kb = blockIdx.z * kper, ke = kb + kper;
  int lr = tid >> 1;
  int lh = (tid & 1) * 8;
  int tx = tid & 15, ty = tid >> 4;
  bool wok = (bn + lr < N);
  const float* arow = A + (size_t)(bm + lr) * K + lh;
  const float* wrow = W + (size_t)(bn + lr) * K + lh;
  float4 a0, a1, w0, w1;
  auto gload = [&](int k0) {
    a0 = *(const float4*)(arow + k0);
    a1 = *(const float4*)(arow + k0 + 4);
    w0 = make_float4(0.f, 0.f, 0.f, 0.f); w1 = w0;
    if (wok) {
      w0 = *(const float4*)(wrow + k0);
      w1 = *(const float4*)(wrow + k0 + 4);
    }
  };
  f32x4 acc0[8] = {}, acc1[8] = {};
  gload(kb);
  for (int k0 = kb; k0 < ke; k0 += 16) {
    __syncthreads();
    As[lh+0][lr]=a0.x; As[lh+1][lr]=a0.y; As[lh+2][lr]=a0.z; As[lh+3][lr]=a0.w;
    As[lh+4][lr]=a1.x; As[lh+5][lr]=a1.y; As[lh+6][lr]=a1.z; As[lh+7][lr]=a1.w;
    Ws[lh+0][lr]=w0.x; Ws[lh+1][lr]=w0.y; Ws[lh+2][lr]=w0.z; Ws[lh+3][lr]=w0.w;
    Ws[lh+4][lr]=w1.x; Ws[lh+5][lr]=w1.y; Ws[lh+6][lr]=w1.z; Ws[lh+7][lr]=w1.w;
    __syncthreads();
    if (k0 + 16 < ke) gload(k0 + 16);
#pragma unroll
    for (int kk = 0; kk < 16; ++kk) {
      f32x4 b0 = *(const f32x4*)&Ws[kk][tx * 4];
      f32x4 b1 = *(const f32x4*)&Ws[kk][64 + tx * 4];
      f32x4 al = *(const f32x4*)&As[kk][ty * 8];
      f32x4 ah = *(const f32x4*)&As[kk][ty * 8 + 4];
#pragma unroll
      for (int i = 0; i < 4; ++i) {
        acc0[i]     += splat4(al[i]) * b0;
        acc1[i]     += splat4(al[i]) * b1;
        acc0[i + 4] += splat4(ah[i]) * b0;
        acc1[i + 4] += splat4(ah[i]) * b1;
      }
    }
  }
  bool single = (gridDim.z == 1);
#pragma unroll
  for (int i = 0; i < 8; ++i) {
    int row = bm + ty * 8 + i;
    float* crow = C + (size_t)row * N;
    int c0 = bn + tx * 4, c1 = bn + 64 + tx * 4;
    if (c0 + 3 < N) {
      if (single) *(f32x4*)(crow + c0) = acc0[i];
      else {
        atomicAdd(crow + c0 + 0, acc0[i][0]); atomicAdd(crow + c0 + 1, acc0[i][1]);
        atomicAdd(crow + c0 + 2, acc0[i][2]); atomicAdd(crow + c0 + 3, acc0[i][3]);
      }
    }
    if (c1 + 3 < N) {
      if (single) *(f32x4*)(crow + c1) = acc1[i];
      else {
        atomicAdd(crow + c1 + 0, acc1[i][0]); atomicAdd(crow + c1 + 1, acc1[i][1]);
        atomicAdd(crow + c1 + 2, acc1[i][2]); atomicAdd(crow + c1 + 3, acc1[i][3]);
      }
    }
  }
}

// ---------------- dual fp32 GEMM: two independent same-shape GEMMs in one grid ----------------
__global__ __launch_bounds__(256) void gemm_f32_dual(
    const float* __restrict__ A0, const float* __restrict__ W0, float* __restrict__ C0,
    const float* __restrict__ A1, const float* __restrict__ W1, float* __restrict__ C1,
    int M, int N, int K, int S) {
  __shared__ float As[16][132];
  __shared__ float Ws[16][132];
  int tid = threadIdx.x;
  int bm = blockIdx.y * 128, bn = blockIdx.x * 128;
  int pair = (int)blockIdx.z >= S;
  int zi = blockIdx.z - pair * S;
  const float* A = pair ? A1 : A0;
  const float* W = pair ? W1 : W0;
  float* C = pair ? C1 : C0;
  int kper = K / S;
  int kb = zi * kper, ke = kb + kper;
  int lr = tid >> 1;
  int lh = (tid & 1) * 8;
  int tx = tid & 15, ty = tid >> 4;
  bool wok = (bn + lr < N);
  const float* arow = A + (size_t)(bm + lr) * K + lh;
  const float* wrow = W + (size_t)(bn + lr) * K + lh;
  float4 a0, a1, w0, w1;
  auto gload = [&](int k0) {
    a0 = *(const float4*)(arow + k0);
    a1 = *(const float4*)(arow + k0 + 4);
    w0 = make_float4(0.f, 0.f, 0.f, 0.f); w1 = w0;
    if (wok) {
      w0 = *(const float4*)(wrow + k0);
      w1 = *(const float4*)(wrow + k0 + 4);
    }
  };
  f32x4 acc0[8] = {}, acc1[8] = {};
  gload(kb);
  for (int k0 = kb; k0 < ke; k0 += 16) {
    __syncthreads();
    As[lh+0][lr]=a0.x; As[lh+1][lr]=a0.y; As[lh+2][lr]=a0.z; As[lh+3][lr]=a0.w;
    As[lh+4][lr]=a1.x; As[lh+5][lr]=a1.y; As[lh+6][lr]=a1.z; As[lh+7][lr]=a1.w;
    Ws[lh+0][lr]=w0.x; Ws[lh+1][lr]=w0.y; Ws[lh+2][lr]=w0.z; Ws[lh+3][lr]=w0.w;
    Ws[lh+4][lr]=w1.x; Ws[lh+5][lr]=w1.y; Ws[lh+6][lr]=w1.z; Ws[lh+7][lr]=w1.w;
    __syncthreads();
    if (k0 + 16 < ke) gload(k0 + 16);
#pragma unroll
    for (int kk = 0; kk < 16; ++kk) {
      f32x4 b0 = *(const f32x4*)&Ws[kk][tx * 4];
      f32x4 b1 = *(const f32x4*)&Ws[kk][64 + tx * 4];
      f32x4 al = *(const f32x4*)&As[kk][ty * 8];
      f32x4 ah = *(const f32x4*)&As[kk][ty * 8 + 4];
#pragma unroll
      for (int i = 0; i < 4; ++i) {
        acc0[i]     += splat4(al[i]) * b0;
        acc1[i]     += splat4(al[i]) * b1;
        acc0[i + 4] += splat4(ah[i]) * b0;
        acc1[i + 4] += splat4(ah[i]) * b1;
      }
    }
  }
#pragma unroll
  for (int i = 0; i < 8; ++i) {
    int row = bm + ty * 8 + i;
    float* crow = C + (size_t)row * N;
    int c0 = bn + tx * 4, c1 = bn + 64 + tx * 4;
    if (c0 + 3 < N) {
      atomicAdd(crow + c0 + 0, acc0[i][0]); atomicAdd(crow + c0 + 1, acc0[i][1]);
      atomicAdd(crow + c0 + 2, acc0[i][2]); atomicAdd(crow + c0 + 3, acc0[i][3]);
    }
    if (c1 + 3 < N) {
      atomicAdd(crow + c1 + 0, acc1[i][0]); atomicAdd(crow + c1 + 1, acc1[i][1]);
      atomicAdd(crow + c1 + 2, acc1[i][2]); atomicAdd(crow + c1 + 3, acc1[i][3]);
    }
  }
}

// ---------------- bf16 MFMA GEMM (double-buffered LDS: stage(t+1) || compute(t)) ----------------
__global__ __launch_bounds__(256) void gemm_bf16_kernel(
    const unsigned short* __restrict__ A, const unsigned short* __restrict__ W,
    float* __restrict__ C, int M, int N, int K, int lda, int ldb, int ldc) {
  __shared__ unsigned short As[2][128 * 64];
  __shared__ unsigned short Ws[2][128 * 64];
  int tid = threadIdx.x;
  int bx = blockIdx.x, by = blockIdx.y;
  int nxy = gridDim.x * gridDim.y;
  if ((nxy & 7) == 0) {
    int lin = by * gridDim.x + bx;
    int cpx = nxy >> 3;
    int swz = (lin & 7) * cpx + (lin >> 3);
    bx = swz % gridDim.x;
    by = swz / gridDim.x;
  }
  int bm = by * 128, bn = bx * 128;
  int kper = K / gridDim.z;
  int k_begin = blockIdx.z * kper;
  int k_end = k_begin + kper;
  int wv = tid >> 6, lane = tid & 63;
  int wrow = (wv >> 1) * 64, wcol = (wv & 1) * 64;
  int lrow = lane & 15, quad = lane >> 4;

  f32x4 acc[4][4] = {};

  auto stage = [&](int b, int k0) {
#pragma unroll
    for (int it = 0; it < 4; ++it) {
      int s = it * 256 + tid;
      int r = s >> 3;
      int q = (s & 7) ^ (r & 7);
      const unsigned short* ga = A + (size_t)(bm + r) * lda + k0 + q * 8;
      const unsigned short* gw = W + (size_t)(bn + r) * ldb + k0 + q * 8;
      __builtin_amdgcn_global_load_lds((const __attribute__((address_space(1))) void*)ga,
                                       (__attribute__((address_space(3))) void*)&As[b][s * 8], 16, 0, 0);
      __builtin_amdgcn_global_load_lds((const __attribute__((address_space(1))) void*)gw,
                                       (__attribute__((address_space(3))) void*)&Ws[b][s * 8], 16, 0, 0);
    }
  };

  stage(0, k_begin);
  int cur = 0;
  for (int k0 = k_begin; k0 < k_end; k0 += 64) {
    __syncthreads();
    if (k0 + 64 < k_end) stage(cur ^ 1, k0 + 64);
#pragma unroll
    for (int ks = 0; ks < 2; ++ks) {
      bf16x8 af[4], wf[4];
#pragma unroll
      for (int i = 0; i < 4; ++i) {
        int ra = wrow + i * 16 + lrow;
        int qa = (ks * 4 + quad) ^ (ra & 7);
        af[i] = *(const bf16x8*)&As[cur][(ra * 8 + qa) * 8];
        int rw = wcol + i * 16 + lrow;
        int qw = (ks * 4 + quad) ^ (rw & 7);
        wf[i] = *(const bf16x8*)&Ws[cur][(rw * 8 + qw) * 8];
      }
#pragma unroll
      for (int i = 0; i < 4; ++i)
#pragma unroll
        for (int j = 0; j < 4; ++j)
          acc[i][j] = __builtin_amdgcn_mfma_f32_16x16x32_bf16(af[i], wf[j], acc[i][j], 0, 0, 0);
    }
    cur ^= 1;
  }
  bool single = (gridDim.z == 1);
#pragma unroll
  for (int i = 0; i < 4; ++i)
#pragma unroll
    for (int j = 0; j < 4; ++j)
#pragma unroll
      for (int r = 0; r < 4; ++r) {
        int row = bm + wrow + i * 16 + quad * 4 + r;
        int col = bn + wcol + j * 16 + lrow;
        float v = acc[i][j][r];
        if (single) C[(size_t)row * ldc + col] = v;
        else atomicAdd(&C[(size_t)row * ldc + col], v);
      }
}

// ---------------- 256^2-tile 8-wave bf16 GEMM with 4-cell half-K (32) pipeline ----------------
// R11 fixes vs R10 (verified-correct base):
//  * swizzle f(r) = (r>>1)&3 (was r&3): bank-group (r&1, slot) now covers all 8
//    groups 2x per 16 lanes -> 2-way (free, m136). R10's f(r)=r&3 collapsed to
//    4 groups -> 4-way, SQ_LDS_BANK_CONFLICT 5.3M.
//  * T5 s_setprio(1) around the MFMA cluster (8-wave phase-split regime).
__global__ __launch_bounds__(512) void gemm_bf16_256_kernel(
    const unsigned short* __restrict__ A, const unsigned short* __restrict__ W,
    float* __restrict__ C, int K, int lda, int ldc) {
  __shared__ unsigned short As[4][256 * 32];
  __shared__ unsigned short Ws[4][256 * 32];
  int tid = threadIdx.x;
  int bx = blockIdx.x, by = blockIdx.y;
  int nxy = gridDim.x * gridDim.y;
  if ((nxy & 7) == 0) {
    int lin = by * gridDim.x + bx;
    int cpx = nxy >> 3;
    int swz = (lin & 7) * cpx + (lin >> 3);
    bx = swz % gridDim.x;
    by = swz / gridDim.x;
  }
  int bm = by * 256, bn = bx * 256;
  int kper = K / gridDim.z;
  int kb = blockIdx.z * kper;
  int U = kper >> 5;                 // number of 32-k units (>= 4 required)
  int wave = tid >> 6, lane = tid & 63;
  int wr = wave >> 2, wc = wave & 3; // wave tile: 128 rows x 64 cols
  int lrow = lane & 15, quad = lane >> 4;

  f32x4 acc[8][4] = {};

  auto stage = [&](int cell, int u) {
    int k0 = kb + (u << 5);
#pragma unroll
    for (int rd = 0; rd < 2; ++rd) {
      int s = rd * 512 + tid;        // A segments 0..1023 (rows 0..255, 4 segs/row)
      int r = s >> 2;
      int q = (s & 3) ^ ((r >> 1) & 3);
      const unsigned short* ga = A + (size_t)(bm + r) * lda + k0 + q * 8;
      __builtin_amdgcn_global_load_lds((const __attribute__((address_space(1))) void*)ga,
          (__attribute__((address_space(3))) void*)&As[cell][s * 8], 16, 0, 0);
    }
#pragma unroll
    for (int rd = 0; rd < 2; ++rd) {
      int s = rd * 512 + tid;        // B segments, same layout
      int r = s >> 2;
      int q = (s & 3) ^ ((r >> 1) & 3);
      const unsigned short* gw = W + (size_t)(bn + r) * lda + k0 + q * 8;
      __builtin_amdgcn_global_load_lds((const __attribute__((address_space(1))) void*)gw,
          (__attribute__((address_space(3))) void*)&Ws[cell][s * 8], 16, 0, 0);
    }
  };

  auto compute = [&](int cell) {
    bf16x8 af[8], wf[4];
#pragma unroll
    for (int m = 0; m < 8; ++m) {
      int ra = wr * 128 + m * 16 + lrow;
      af[m] = *(const bf16x8*)&As[cell][((ra << 2) + (quad ^ ((ra >> 1) & 3))) * 8];
    }
#pragma unroll
    for (int n = 0; n < 4; ++n) {
      int rw = wc * 64 + n * 16 + lrow;
      wf[n] = *(const bf16x8*)&Ws[cell][((rw << 2) + (quad ^ ((rw >> 1) & 3))) * 8];
    }
    __builtin_amdgcn_s_setprio(1);
#pragma unroll
    for (int m = 0; m < 8; ++m)
#pragma unroll
      for (int n = 0; n < 4; ++n)
        acc[m][n] = __builtin_amdgcn_mfma_f32_16x16x32_bf16(af[m], wf[n], acc[m][n], 0, 0, 0);
    __builtin_amdgcn_s_setprio(0);
  };

  stage(0, 0); stage(1, 1); stage(2, 2);
  for (int u = 0; u + 3 < U; ++u) {
    __builtin_amdgcn_s_barrier();                       // (1) prev compute done everywhere
    asm volatile("" ::: "memory");
    stage((u + 3) & 3, u + 3);
    asm volatile("s_waitcnt vmcnt(12)" ::: "memory");   // unit u landed (own loads)
    __builtin_amdgcn_s_barrier();                       // (2) unit u landed for all waves
    asm volatile("" ::: "memory");
    compute(u & 3);
  }
  for (int u = U - 3; u < U; ++u) {                     // tail: conservative full drain
    __builtin_amdgcn_s_barrier();
    asm volatile("s_waitcnt vmcnt(0)" ::: "memory");
    __builtin_amdgcn_s_barrier();
    asm volatile("" ::: "memory");
    compute(u & 3);
  }

#pragma unroll
  for (int m = 0; m < 8; ++m)
#pragma unroll
    for (int n = 0; n < 4; ++n)
#pragma unroll
      for (int rr = 0; rr < 4; ++rr) {
        int row = bm + wr * 128 + m * 16 + quad * 4 + rr;
        int col = bn + wc * 64 + n * 16 + lrow;
        atomicAdd(&C[(size_t)row * ldc + col], acc[m][n][rr]);
      }
}

// ---------------- dual bf16 MFMA GEMM: q_up + kv_up in one launch ----------------
__global__ __launch_bounds__(256) void gemm_bf16_dual(
    const unsigned short* __restrict__ A0, const unsigned short* __restrict__ W0,
    float* __restrict__ C0,
    const unsigned short* __restrict__ A1, const unsigned short* __restrict__ W1,
    float* __restrict__ C1,
    int nx0, int ldc0, int ldc1, int K, int ld) {
  __shared__ unsigned short As[2][128 * 64];
  __shared__ unsigned short Ws[2][128 * 64];
  int tid = threadIdx.x;
  int bx = blockIdx.x, by = blockIdx.y;
  int pair = bx >= nx0;
  int bxl = pair ? bx - nx0 : bx;
  const unsigned short* A = pair ? A1 : A0;
  const unsigned short* W = pair ? W1 : W0;
  float* C = pair ? C1 : C0;
  int ldc = pair ? ldc1 : ldc0;
  int bm = by * 128, bn = bxl * 128;
  int wv = tid >> 6, lane = tid & 63;
  int wrow = (wv >> 1) * 64, wcol = (wv & 1) * 64;
  int lrow = lane & 15, quad = lane >> 4;

  f32x4 acc[4][4] = {};

  auto stage = [&](int b, int k0) {
#pragma unroll
    for (int it = 0; it < 4; ++it) {
      int s = it * 256 + tid;
      int r = s >> 3;
      int q = (s & 7) ^ (r & 7);
      const unsigned short* ga = A + (size_t)(bm + r) * ld + k0 + q * 8;
      const unsigned short* gw = W + (size_t)(bn + r) * ld + k0 + q * 8;
      __builtin_amdgcn_global_load_lds((const __attribute__((address_space(1))) void*)ga,
                                       (__attribute__((address_space(3))) void*)&As[b][s * 8], 16, 0, 0);
      __builtin_amdgcn_global_load_lds((const __attribute__((address_space(1))) void*)gw,
                                       (__attribute__((address_space(3))) void*)&Ws[b][s * 8], 16, 0, 0);
    }
  };

  stage(0, 0);
  int cur = 0;
  for (int k0 = 0; k0 < K; k0 += 64) {
    __syncthreads();
    if (k0 + 64 < K) stage(cur ^ 1, k0 + 64);
#pragma unroll
    for (int ks = 0; ks < 2; ++ks) {
      bf16x8 af[4], wf[4];
#pragma unroll
      for (int i = 0; i < 4; ++i) {
        int ra = wrow + i * 16 + lrow;
        int qa = (ks * 4 + quad) ^ (ra & 7);
        af[i] = *(const bf16x8*)&As[cur][(ra * 8 + qa) * 8];
        int rw = wcol + i * 16 + lrow;
        int qw = (ks * 4 + quad) ^ (rw & 7);
        wf[i] = *(const bf16x8*)&Ws[cur][(rw * 8 + qw) * 8];
      }
#pragma unroll
      for (int i = 0; i < 4; ++i)
#pragma unroll
        for (int j = 0; j < 4; ++j)
          acc[i][j] = __builtin_amdgcn_mfma_f32_16x16x32_bf16(af[i], wf[j], acc[i][j], 0, 0, 0);
    }
    cur ^= 1;
  }
#pragma unroll
  for (int i = 0; i < 4; ++i)
#pragma unroll
    for (int j = 0; j < 4; ++j)
#pragma unroll
      for (int r = 0; r < 4; ++r) {
        int row = bm + wrow + i * 16 + quad * 4 + r;
        int col = bn + wcol + j * 16 + lrow;
        C[(size_t)row * ldc + col] = acc[i][j][r];
      }
}

// ---------------- fused weight-prep: tripA + tripW + 6x caugW + transpose(idx_out_w) ----------------
__global__ __launch_bounds__(256) void prep_weights_kernel(
    const float* __restrict__ x, unsigned short* __restrict__ x_trip,
    const float* __restrict__ idx_in_w, unsigned short* __restrict__ w_in_trip,
    const float* __restrict__ q_down_w, const float* __restrict__ kv_down_w,
    const float* __restrict__ k_rope_w, unsigned short* __restrict__ w3down,
    const float* __restrict__ q_up_w, const float* __restrict__ q_rope_w,
    unsigned short* __restrict__ wqups,
    const float* __restrict__ kv_up_w, unsigned short* __restrict__ wkvup,
    const float* __restrict__ idx_out_w, float* __restrict__ out_w_T) {
  __shared__ float tsh[32][33];
  int bid = blockIdx.x;
  if (bid >= 20736) {
    int b = bid - 20736;
    int bx = b & 31, by = b >> 5;
    int tx = threadIdx.x & 31, ty8 = threadIdx.x >> 5;
    for (int r = ty8; r < 32; r += 8)
      tsh[r][tx] = idx_out_w[(size_t)(by * 32 + r) * 1024 + bx * 32 + tx];
    __syncthreads();
    for (int r = ty8; r < 32; r += 8)
      out_w_T[(size_t)(bx * 32 + r) * 1024 + by * 32 + tx] = tsh[tx][r];
    return;
  }
  int i = bid * 256 + threadIdx.x;
  if (i < 2097152) {
    float f = x[i];
    unsigned short h = f2bf(f);
    float r1 = f - bf2f(h);
    unsigned short m = f2bf(r1);
    unsigned short l = f2bf(r1 - bf2f(m));
    size_t o = (size_t)i * 6;
    x_trip[o] = h; x_trip[o + 1] = m; x_trip[o + 2] = l;
    x_trip[o + 3] = h; x_trip[o + 4] = m; x_trip[o + 5] = h;
  } else if (i < 4456448) {
    int j = i - 2097152;
    int n = j >> 10, k = j & 1023;
    unsigned short h = 0, m = 0, l = 0;
    if (n < 2208) {
      float f = idx_in_w[(size_t)n * 1024 + k];
      h = f2bf(f);
      float r1 = f - bf2f(h);
      m = f2bf(r1);
      l = f2bf(r1 - bf2f(m));
    }
    size_t o = (size_t)j * 6;
    w_in_trip[o] = h; w_in_trip[o + 1] = h; w_in_trip[o + 2] = h;
    w_in_trip[o + 3] = m; w_in_trip[o + 4] = m; w_in_trip[o + 5] = l;
  } else {
    int j2 = i - 4456448;
    const float* src; unsigned short* dst; int rows, K; size_t obase; int idx;
    if (j2 < 393216) {
      int r = j2 >> 17;
      idx = j2 & 131071;
      K = 1024;
      src = (r == 0) ? q_down_w : (r == 1) ? kv_down_w : k_rope_w;
      rows = (r == 2) ? 32 : 128;
      dst = w3down; obase = (size_t)(r * 131072 + idx) * 3;
    } else if (j2 < 524288) {
      idx = j2 - 393216; K = 128; src = q_up_w; rows = 1024;
      dst = wqups; obase = (size_t)idx * 3;
    } else if (j2 < 589824) {
      idx = j2 - 524288; K = 128; src = q_rope_w; rows = 512;
      dst = wqups; obase = (size_t)393216 + (size_t)idx * 3;
    } else {
      idx = j2 - 589824; K = 128; src = kv_up_w; rows = 2048;
      dst = wkvup; obase = (size_t)idx * 3;
    }
    int n = idx / K, k = idx - n * K;
    unsigned short hi = 0, lo = 0;
    if (n < rows) {
      float f = src[(size_t)n * K + k];
      hi = f2bf(f);
      lo = f2bf(f - bf2f(hi));
    }
    dst[obase] = hi; dst[obase + 1] = hi; dst[obase + 2] = lo;
  }
}

// ---------------- fused post-in_proj: caugW(out_w) + conv_silu + dt ----------------
__global__ __launch_bounds__(256) void post_inproj_kernel(
    const float* __restrict__ out_w, unsigned short* __restrict__ w_outp,
    const float* __restrict__ zxbcdt, const float* __restrict__ conv_w,
    const float* __restrict__ conv_b, float* __restrict__ xBC,
    const float* __restrict__ dt_bias, const float* __restrict__ A_log,
    float* __restrict__ dt, float* __restrict__ logdA) {
  int i = blockIdx.x * 256 + threadIdx.x;
  if (i < 1048576) {
    float f = out_w[i];
    unsigned short hi = f2bf(f);
    unsigned short lo = f2bf(f - bf2f(hi));
    size_t o = (size_t)i * 3;
    w_outp[o] = hi; w_outp[o + 1] = hi; w_outp[o + 2] = lo;
  } else if (i < 3407872) {
    int idx = i - 1048576;
    int l = idx / CONVCH, c = idx - l * CONVCH;
    float acc = conv_b[c];
#pragma unroll
    for (int k = 0; k < 4; ++k) {
      int ls = l - 3 + k;
      if (ls >= 0) acc += zxbcdt[(size_t)ls * INDIMP + DINNER + c] * conv_w[c * 4 + k];
    }
    xBC[idx] = acc / (1.f + expf(-acc));
  } else {
    int idx = i - 3407872;
    int l = idx >> 5, h = idx & 31;
    float xv = zxbcdt[(size_t)l * INDIMP + 2176 + h] + dt_bias[h];
    float sp = fmaxf(xv, 0.f) + log1pf(expf(-fabsf(xv)));
    dt[idx] = sp;
    logdA[idx] = sp * -expf(A_log[h]);
  }
}

// ---------------- conversions ----------------
__global__ __launch_bounds__(256) void conv_augA_kernel(
    const float* __restrict__ src, unsigned short* __restrict__ dst,
    int total, int K, int sld) {
  int i = blockIdx.x * 256 + threadIdx.x;
  if (i >= total) return;
  int m = i / K, k = i - m * K;
  float f = src[(size_t)m * sld + k];
  unsigned short hi = f2bf(f);
  unsigned short lo = f2bf(f - bf2f(hi));
  size_t o = ((size_t)m * K + k) * 3;
  dst[o] = hi; dst[o + 1] = lo; dst[o + 2] = hi;
}
__global__ __launch_bounds__(256) void conv_augA2_kernel(
    const float* __restrict__ c3, unsigned short* __restrict__ dq,
    unsigned short* __restrict__ dkv) {
  int i = blockIdx.x * 256 + threadIdx.x;
  if (i >= 2048 * 256) return;
  int m = i >> 8, k = i & 255;
  float f = c3[(size_t)m * 384 + k];
  unsigned short hi = f2bf(f);
  unsigned short lo = f2bf(f - bf2f(hi));
  if (k < 128) {
    size_t o = ((size_t)m * 128 + k) * 3;
    dq[o] = hi; dq[o + 1] = lo; dq[o + 2] = hi;
  } else {
    size_t o = ((size_t)m * 128 + (k - 128)) * 3;
    dkv[o] = hi; dkv[o + 1] = lo; dkv[o + 2] = hi;
  }
}

// ---------------- G[c][t][s] = C_t . B_s  (+ lcd region in blocks 32..35) ----------------
__global__ __launch_bounds__(256) void chunk_G_kernel(
    const float* __restrict__ xBC, float* __restrict__ G,
    const float* __restrict__ logdA, float* __restrict__ lcd) {
  int c = blockIdx.x, tid = threadIdx.x;
  if (c >= NCH) {
    int i = (c - NCH) * 256 + tid;
    int cc = i >> 5, h = i & 31;
    float s = 0.f;
    for (int t = 0; t < CHUNK; ++t) {
      s += logdA[(cc * CHUNK + t) * MNH + h];
      lcd[(size_t)i * CHUNK + t] = s;
    }
    return;
  }
  __shared__ float BsT[64][68];
  __shared__ float Cs[64][65];
  int t = tid >> 2, q = tid & 3;
  const float* row = xBC + (size_t)(c * 64 + t) * CONVCH + DINNER;
#pragma unroll
  for (int j = 0; j < 16; j += 4) {
    float4 b = *(const float4*)(row + q * 16 + j);
    BsT[q * 16 + j + 0][t] = b.x; BsT[q * 16 + j + 1][t] = b.y;
    BsT[q * 16 + j + 2][t] = b.z; BsT[q * 16 + j + 3][t] = b.w;
    float4 cv = *(const float4*)(row + 64 + q * 16 + j);
    Cs[t][q * 16 + j + 0] = cv.x; Cs[t][q * 16 + j + 1] = cv.y;
    Cs[t][q * 16 + j + 2] = cv.z; Cs[t][q * 16 + j + 3] = cv.w;
  }
  __syncthreads();
  int s0 = q * 16;
  f32x4 g0 = {}, g1 = {}, g2 = {}, g3 = {};
  for (int n = 0; n < 64; ++n) {
    f32x4 cv = splat4(Cs[t][n]);
    g0 += cv * *(const f32x4*)&BsT[n][s0];
    g1 += cv * *(const f32x4*)&BsT[n][s0 + 4];
    g2 += cv * *(const f32x4*)&BsT[n][s0 + 8];
    g3 += cv * *(const f32x4*)&BsT[n][s0 + 12];
  }
  float* gp = G + ((size_t)c * 64 + t) * 64 + s0;
  *(f32x4*)gp = g0; *(f32x4*)(gp + 4) = g1; *(f32x4*)(gp + 8) = g2; *(f32x4*)(gp + 12) = g3;
}

// ---------------- scan pass A ----------------
__global__ __launch_bounds__(256) void scan_local_kernel(
    const float* __restrict__ xBC, const float* __restrict__ dt,
    const float* __restrict__ lcd, float* __restrict__ hstate) {
  int c = blockIdx.x >> 5, h = blockIdx.x & 31;
  int tid = threadIdx.x;
  __shared__ float Bs[64][68];
  __shared__ float xss[64][36];
  __shared__ float w2s[64];
  int t0 = c * CHUNK;
  int t = tid >> 2, q = tid & 3;
  const float* row = xBC + (size_t)(t0 + t) * CONVCH;
#pragma unroll
  for (int j = 0; j < 16; j += 4)
    *(float4*)&Bs[t][q * 16 + j] = *(const float4*)(row + DINNER + q * 16 + j);
  if (q < 2) {
#pragma unroll
    for (int j = 0; j < 16; j += 4)
      *(float4*)&xss[t][q * 16 + j] = *(const float4*)(row + h * 32 + q * 16 + j);
  }
  if (tid < 64) {
    const float* lc = lcd + ((size_t)c * 32 + h) * CHUNK;
    w2s[tid] = expf(lc[63] - lc[tid]) * dt[(t0 + tid) * MNH + h];
  }
  __syncthreads();
  int n = tid >> 2, pg = (tid & 3) * 8;
  f32x4 h0 = {}, h1 = {};
  for (int s = 0; s < 64; ++s) {
    f32x4 wb = splat4(w2s[s] * Bs[s][n]);
    h0 += wb * *(const f32x4*)&xss[s][pg];
    h1 += wb * *(const f32x4*)&xss[s][pg + 4];
  }
  float* hp = hstate + ((size_t)c * 32 + h) * 2048 + n * 32 + pg;
  *(f32x4*)hp = h0; *(f32x4*)(hp + 4) = h1;
}

// ---------------- scan pass B ----------------
__global__ __launch_bounds__(256) void scan_combine_kernel(
    float* __restrict__ hstate, const float* __restrict__ lcd) {
  int i = blockIdx.x * 256 + threadIdx.x;
  int h = i >> 11;
  float H = 0.f;
  for (int c = 0; c < NCH; ++c) {
    float hl = hstate[(size_t)c * 65536 + i];
    hstate[(size_t)c * 65536 + i] = H;
    float P = expf(lcd[((size_t)c * 32 + h) * CHUNK + CHUNK - 1]);
    H = H * P + hl;
  }
}

// ---------------- scan pass C ----------------
__global__ __launch_bounds__(256) void scan_y_kernel(
    const float* __restrict__ xBC, const float* __restrict__ G,
    const float* __restrict__ dt, const float* __restrict__ lcd,
    const float* __restrict__ hstate, float* __restrict__ y) {
  int c = blockIdx.x >> 5, h = blockIdx.x & 31;
  int tid = threadIdx.x;
  __shared__ float Ms[64][65];
  __shared__ float Cs[64][65];
  __shared__ float xss[64][36];
  __shared__ float Hss[64][36];
  __shared__ float lcds[64], dts[64];
  int t0 = c * CHUNK;
  int t = tid >> 2, q = tid & 3;
  const float* row = xBC + (size_t)(t0 + t) * CONVCH;
#pragma unroll
  for (int j = 0; j < 16; j += 4) {
    float4 cv = *(const float4*)(row + DINNER + 64 + q * 16 + j);
    Cs[t][q * 16 + j + 0] = cv.x; Cs[t][q * 16 + j + 1] = cv.y;
    Cs[t][q * 16 + j + 2] = cv.z; Cs[t][q * 16 + j + 3] = cv.w;
  }
  if (q < 2) {
#pragma unroll
    for (int j = 0; j < 16; j += 4)
      *(float4*)&xss[t][q * 16 + j] = *(const float4*)(row + h * 32 + q * 16 + j);
  }
  {
    const float* gp = G + ((size_t)c * 64 + t) * 64 + q * 16;
#pragma unroll
    for (int j = 0; j < 16; j += 4) {
      float4 g = *(const float4*)(gp + j);
      Ms[t][q * 16 + j + 0] = g.x; Ms[t][q * 16 + j + 1] = g.y;
      Ms[t][q * 16 + j + 2] = g.z; Ms[t][q * 16 + j + 3] = g.w;
    }
  }
  {
    const float* hp = hstate + ((size_t)c * 32 + h) * 2048 + tid * 8;
    int n = tid >> 2, p0 = (tid & 3) * 8;
    *(float4*)&Hss[n][p0]     = *(const float4*)hp;
    *(float4*)&Hss[n][p0 + 4] = *(const float4*)(hp + 4);
  }
  if (tid < 64) {
    lcds[tid] = lcd[((size_t)c * 32 + h) * CHUNK + tid];
    dts[tid]  = dt[(t0 + tid) * MNH + h];
  }
  __syncthreads();
  {
    int s0 = q * 16;
#pragma unroll
    for (int j = 0; j < 16; ++j) {
      int s = s0 + j;
      float m = (s <= t) ? expf(lcds[t] - lcds[s]) * dts[s] * Ms[t][s] : 0.f;
      Ms[t][s] = m;
    }
  }
  __syncthreads();
  int pg = q * 8;
  f32x4 y0 = {}, y1 = {}, a0 = {}, a1 = {};
  for (int s = 0; s < 64; ++s) {
    f32x4 m = splat4(Ms[t][s]);
    y0 += m * *(const f32x4*)&xss[s][pg];
    y1 += m * *(const f32x4*)&xss[s][pg + 4];
  }
  for (int n = 0; n < 64; ++n) {
    f32x4 cn = splat4(Cs[t][n]);
    a0 += cn * *(const f32x4*)&Hss[n][pg];
    a1 += cn * *(const f32x4*)&Hss[n][pg + 4];
  }
  f32x4 cd = splat4(expf(lcds[t]));
  y0 += cd * a0; y1 += cd * a1;
  float* yp = y + (size_t)(t0 + t) * DINNER + h * 32 + pg;
  *(f32x4*)yp = y0; *(f32x4*)(yp + 4) = y1;
}

// ---------------- gate + RMSNorm ----------------
__global__ __launch_bounds__(256) void gatenorm_kernel(
    const float* __restrict__ y_ssm, const float* __restrict__ xBC,
    const float* __restrict__ zxbcdt, const float* __restrict__ Dv,
    const float* __restrict__ norm_w, float* __restrict__ out) {
  int l = blockIdx.x, tid = threadIdx.x;
  float vals[4];
  float ss = 0.f;
#pragma unroll
  for (int i = 0; i < 4; ++i) {
    int d = tid + i * 256;
    int h = d >> 5;
    float v = y_ssm[(size_t)l * DINNER + d] + Dv[h] * xBC[(size_t)l * CONVCH + d];
    float z = zxbcdt[(size_t)l * INDIMP + d];
    v *= z / (1.f + expf(-z));
    vals[i] = v;
    ss += v * v;
  }
#pragma unroll
  for (int off = 32; off > 0; off >>= 1) ss += __shfl_xor(ss, off);
  __shared__ float sred[4];
  if ((tid & 63) == 0) sred[tid >> 6] = ss;
  __syncthreads();
  float tot = sred[0] + sred[1] + sred[2] + sred[3];
  float scale = rsqrtf(tot * (1.f / 1024.f) + 1e-5f);
#pragma unroll
  for (int i = 0; i < 4; ++i) {
    int d = tid + i * 256;
    out[(size_t)l * DINNER + d] = vals[i] * scale * norm_w[d];
  }
}

// ---------------- per-row top-64 radix select (R4-verified global-scan) ----------------
__global__ __launch_bounds__(256) void topk_kernel(
    const float* __restrict__ scores, int* __restrict__ out_idx) {
  int l = blockIdx.x, tid = threadIdx.x;
  if (l < 64) {
    if (tid < 64) out_idx[l * 64 + tid] = tid;
    return;
  }
  int n = l + 1;
  const float* row = scores + (size_t)l * L;
  __shared__ int hist[256];
  __shared__ unsigned sel_prefix;
  __shared__ int sel_remaining;
  __shared__ int cnt_g, cnt_e;
  __shared__ int eq_list[128];
  if (tid == 0) { cnt_g = 0; cnt_e = 0; }
  unsigned prefix = 0;
  int remaining = 64;
  for (int pass = 0; pass < 4; ++pass) {
    int shift = 24 - 8 * pass;
    unsigned himask = (pass == 0) ? 0u : (0xFFFFFFFFu << (shift + 8));
    hist[tid] = 0;
    __syncthreads();
    for (int j = tid; j < n; j += 256) {
      unsigned u = __float_as_uint(row[j]);
      unsigned key = (u & 0x80000000u) ? ~u : (u | 0x80000000u);
      if (((key ^ prefix) & himask) == 0)
        atomicAdd(&hist[(key >> shift) & 255], 1);
    }
    __syncthreads();
    if (tid == 0) {
      int cum = 0, b = 255;
      for (; b >= 0; --b) {
        cum += hist[b];
        if (cum >= remaining) break;
      }
      sel_prefix = prefix | ((unsigned)b << shift);
      sel_remaining = remaining - (cum - hist[b]);
    }
    __syncthreads();
    prefix = sel_prefix;
    remaining = sel_remaining;
    __syncthreads();
  }
  unsigned T = prefix;
  for (int j = tid; j < n; j += 256) {
    unsigned u = __float_as_uint(row[j]);
    unsigned key = (u & 0x80000000u) ? ~u : (u | 0x80000000u);
    if (key > T) {
      int p = atomicAdd(&cnt_g, 1);
      out_idx[l * 64 + p] = j;
    } else if (key == T) {
      int p = atomicAdd(&cnt_e, 1);
      if (p < 128) eq_list[p] = j;
    }
  }
  __syncthreads();
  if (tid == 0) {
    int G = cnt_g;
    int E = remaining;
    int m = cnt_e < 128 ? cnt_e : 128;
    for (int e = 0; e < E; ++e) {
      int best = 0, bj = 0x7fffffff;
      for (int i = 0; i < m; ++i)
        if (eq_list[i] < bj) { bj = eq_list[i]; best = i; }
      out_idx[l * 64 + G + e] = bj;
      eq_list[best] = 0x7fffffff;
    }
  }
}

// ---------------- RoPE + pack q_final/k_final (fused-buffer strides) ----------------
__global__ __launch_bounds__(128) void rope_pack_kernel(
    const float* __restrict__ qbuf, const float* __restrict__ kv,
    const float* __restrict__ c3,
    float* __restrict__ q_final, float* __restrict__ k_final) {
  int l = blockIdx.x, tid = threadIdx.x;
  __shared__ float s_s[16], s_c[16];
  if (tid < 16) {
    float inv = powf(10000.f, -(float)tid / 16.f);
    float ang = (float)l * inv;
    s_s[tid] = sinf(ang);
    s_c[tid] = cosf(ang);
  }
  __syncthreads();
  const float* qrow = qbuf + (size_t)l * 1536;
  const float* krow = c3 + (size_t)l * 384 + 256;
  for (int e = tid; e < NH * 96; e += 128) {
    int hh = e / 96, d = e - hh * 96;
    float qv, kvv;
    if (d < 64) {
      qv  = qrow[hh * 64 + d];
      kvv = kv[(size_t)l * 2048 + hh * 64 + d];
    } else {
      int r = d - 64;
      if (r < 16) {
        float q1 = qrow[1024 + hh * 32 + r];
        float q2 = qrow[1024 + hh * 32 + 16 + r];
        qv = q1 * s_c[r] - q2 * s_s[r];
        float k1 = krow[r];
        float k2 = krow[16 + r];
        kvv = k1 * s_c[r] - k2 * s_s[r];
      } else {
        int rr = r - 16;
        float q1 = qrow[1024 + hh * 32 + rr];
        float q2 = qrow[1024 + hh * 32 + 16 + rr];
        qv = q1 * s_s[rr] + q2 * s_c[rr];
        float k1 = krow[rr];
        float k2 = krow[16 + rr];
        kvv = k1 * s_s[rr] + k2 * s_c[rr];
      }
    }
    q_final[(size_t)l * 1536 + e] = qv;
    k_final[(size_t)l * 1536 + e] = kvv;
  }
}

// ---------------- sparse attention (coalesced, one block per row) ----------------
__global__ __launch_bounds__(256) void attn_kernel(
    const float* __restrict__ q_final, const float* __restrict__ k_final,
    const float* __restrict__ kv, const int* __restrict__ idx,
    unsigned short* __restrict__ attn_aug) {
  int b = blockIdx.x;
  int l = (b & 7) * 256 + (b >> 3);
  int tid = threadIdx.x;
  int h = tid >> 4;
  int s = tid & 15;
  __shared__ __align__(16) float lg[16][64];
  __shared__ int iks[64];

  if (tid < 64) iks[tid] = idx[l * 64 + tid];

  const float* qrow = q_final + (size_t)l * 1536 + h * 96 + s * 2;
  float q0 = qrow[0],  q1 = qrow[1];
  float q2 = qrow[32], q3 = qrow[33];
  float q4 = qrow[64], q5 = qrow[65];
  __syncthreads();

#pragma unroll 4
  for (int k = 0; k < 64; ++k) {
    const float* kr = k_final + (size_t)iks[k] * 1536 + h * 96 + s * 2;
    float2 a = *(const float2*)kr;
    float2 b2 = *(const float2*)(kr + 32);
    float2 c = *(const float2*)(kr + 64);
    float d = q0 * a.x + q1 * a.y + q2 * b2.x + q3 * b2.y + q4 * c.x + q5 * c.y;
    d += __shfl_xor(d, 1);
    d += __shfl_xor(d, 2);
    d += __shfl_xor(d, 4);
    d += __shfl_xor(d, 8);
    if (s == 0) lg[h][k] = d * 0.10206207261596575f;
  }
  __syncthreads();

  f32x4 lv = *(const f32x4*)&lg[h][s * 4];
  float m = fmaxf(fmaxf(lv[0], lv[1]), fmaxf(lv[2], lv[3]));
#pragma unroll
  for (int off = 1; off < 16; off <<= 1) m = fmaxf(m, __shfl_xor(m, off));
  f32x4 ev;
  ev[0] = expf(lv[0] - m); ev[1] = expf(lv[1] - m);
  ev[2] = expf(lv[2] - m); ev[3] = expf(lv[3] - m);
  float ssum = ev[0] + ev[1] + ev[2] + ev[3];
#pragma unroll
  for (int off = 1; off < 16; off <<= 1) ssum += __shfl_xor(ssum, off);
  float inv = 1.f / ssum;
  lg[h][s * 4 + 0] = ev[0] * inv;
  lg[h][s * 4 + 1] = ev[1] * inv;
  lg[h][s * 4 + 2] = ev[2] * inv;
  lg[h][s * 4 + 3] = ev[3] * inv;
  __syncthreads();

  f32x4 acc = {};
#pragma unroll 4
  for (int k = 0; k < 64; ++k) {
    const float* vr = kv + (size_t)iks[k] * 2048 + 1024 + tid * 4;
    f32x4 v = *(const f32x4*)vr;
    acc += splat4(lg[h][k]) * v;
  }

#pragma unroll
  for (int i = 0; i < 4; ++i) {
    float a = acc[i];
    unsigned short hi = f2bf(a);
    unsigned short lo = f2bf(a - bf2f(hi));
    size_t o = ((size_t)l * 1024 + tid * 4 + i) * 3;
    attn_aug[o] = hi; attn_aug[o + 1] = lo; attn_aug[o + 2] = hi;
  }
}

// ---------------- host ----------------
extern "C" void kernel_launch(void* const* d_in, const int* in_sizes, int n_in,
                              void* d_out, int out_size, void* d_ws, size_t ws_size,
                              hipStream_t stream) {
  const float* x          = (const float*)d_in[0];
  const float* idx_in_w   = (const float*)d_in[1];
  const float* idx_conv_w = (const float*)d_in[2];
  const float* idx_conv_b = (const float*)d_in[3];
  const float* idx_dt_b   = (const float*)d_in[4];
  const float* idx_A_log  = (const float*)d_in[5];
  const float* idx_D      = (const float*)d_in[6];
  const float* idx_norm_w = (const float*)d_in[7];
  const float* idx_out_w  = (const float*)d_in[8];
  const float* idx_q_w    = (const float*)d_in[9];
  const float* idx_k_w    = (const float*)d_in[10];
  const float* q_down_w   = (const float*)d_in[11];
  const float* q_up_w     = (const float*)d_in[12];
  const float* q_rope_w   = (const float*)d_in[13];
  const float* kv_down_w  = (const float*)d_in[14];
  const float* kv_up_w    = (const float*)d_in[15];
  const float* k_rope_w   = (const float*)d_in[16];
  const float* out_w      = (const float*)d_in[17];
  float* out = (float*)d_out;

  float* p = (float*)d_ws;
  float* segA = p; p += 4718592;  // zxbcdt[2048x2304] | scores | qbuf
  float* segB = p; p += 2359296;  // xBC | {q_idx, k_idx, c3}
  float* dtb = p; p += 65536;
  float* logdA = p; p += 65536;
  float* lcdb = p; p += 65536;
  int*   idxb = (int*)p; p += 131072;
  float* segD = p; p += 4194304;  // y_ssm+hstate | kvb
  float* segBig1 = p; p += 6291456;  // x_trip | w_outp_aug (after in_proj)
  float* segBig2 = p; p += 7077888;  // w_in_trip | {y_norm|x_aug|q_final}@0, attn_aug@3145728
  float* segH = p; p += 3145728;     // {out_w_T,qwpad,Wq} | k_final
  unsigned short* w_3down_aug = (unsigned short*)p; p += 589824;
  unsigned short* w_qups_aug  = (unsigned short*)p; p += 294912;
  unsigned short* w_kvup_aug  = (unsigned short*)p; p += 393216;
  unsigned short* c_q_aug     = (unsigned short*)p; p += 393216;
  unsigned short* c_kv_aug    = (unsigned short*)p; p += 393216;
  float* Gbuf = p; p += 131072;

  float* zxbcdt = segA;
  float* scores = segA;
  float* qbuf   = segA;
  float* xBC    = segB;
  float* q_idx  = segB;
  float* k_idx  = segB + 131072;
  float* c3     = segB + 262144;
  float* y_ssm  = segD;
  float* hstate = segD + 2097152;
  float* kvb    = segD;
  unsigned short* x_trip     = (unsigned short*)segBig1;  // dead after in_proj
  unsigned short* w_outp_aug = (unsigned short*)segBig1;  // written after in_proj
  unsigned short* w_in_trip  = (unsigned short*)segBig2;  // dead after in_proj
  float* y_norm  = segBig2;                               // gatenorm..q_idx gemm
  unsigned short* x_aug = (unsigned short*)segBig2;       // after topk..down-proj
  float* q_final = segBig2;                               // rope_pack..attn
  unsigned short* attn_aug = (unsigned short*)(segBig2 + 3145728);
  float* out_w_T = segH;
  float* qwpad   = segH + 1048576;
  float* Wq      = segH + 1179648;
  float* k_final = segH;                                  // after q_idx gemm

  dim3 blk(256);
  auto cdiv = [](int a, int b) { return (a + b - 1) / b; };
  auto gemmf3 = [&](const float* A, const float* W, float* C, int M, int N, int K, int S, int tri) {
    dim3 grid(cdiv(N, 128), M / 128, S);
    hipLaunchKernelGGL(gemm_f32_v3, grid, blk, 0, stream, A, W, C, M, N, K, tri);
  };
  auto gemmb = [&](const unsigned short* A, const unsigned short* W, float* C,
                   int M, int N, int K, int lda, int ldb, int ldc, int S) {
    dim3 grid(N / 128, M / 128, S);
    hipLaunchKernelGGL(gemm_bf16_kernel, grid, blk, 0, stream, A, W, C, M, N, K, lda, ldb, ldc);
  };

  // ---- weight precomputes (prep includes the idx_out_w transpose region) ----
  hipLaunchKernelGGL(prep_weights_kernel, dim3(21760), blk, 0, stream,
                     x, x_trip, idx_in_w, w_in_trip,
                     q_down_w, kv_down_w, k_rope_w, w_3down_aug,
                     q_up_w, q_rope_w, w_qups_aug, kv_up_w, w_kvup_aug,
                     idx_out_w, out_w_T);
  hipMemsetAsync(qwpad, 0, 262144 * 4, stream);   // qwpad + adjacent Wq in one memset
  hipMemcpyAsync(qwpad, idx_q_w, (size_t)64 * 1024 * 4, hipMemcpyDeviceToDevice, stream);
  gemmf3(qwpad, out_w_T, Wq, 128, 1024, 1024, 8, 0);

  // ---- mamba branch: in_proj via 256^2 pipelined MFMA (S=3, atomic) ----
  hipMemsetAsync(zxbcdt, 0, (size_t)L * INDIMP * 4, stream);
  {
    dim3 grid(9, 8, 3);   // N=2304/256, M=2048/256, split-K 3 (K/S=2048 -> 64 units)
    hipLaunchKernelGGL(gemm_bf16_256_kernel, grid, dim3(512), 0, stream,
                       x_trip, w_in_trip, zxbcdt, 6144, 6144, INDIMP);
  }
  // fused: caugW(out_w -> segBig1, x_trip dead) + conv_silu + dt, one launch
  hipLaunchKernelGGL(post_inproj_kernel, dim3(13568), blk, 0, stream,
                     out_w, w_outp_aug, zxbcdt, idx_conv_w, idx_conv_b, xBC,
                     idx_dt_b, idx_A_log, dtb, logdA);
  // chunk_G + lcd region (blocks 32..35)
  hipLaunchKernelGGL(chunk_G_kernel, dim3(NCH + 4), blk, 0, stream,
                     xBC, Gbuf, logdA, lcdb);
  hipLaunchKernelGGL(scan_local_kernel, dim3(NCH * MNH), blk, 0, stream,
                     xBC, dtb, lcdb, hstate);
  hipLaunchKernelGGL(scan_combine_kernel, dim3(256), blk, 0, stream, hstate, lcdb);
  hipLaunchKernelGGL(scan_y_kernel, dim3(NCH * MNH), blk, 0, stream,
                     xBC, Gbuf, dtb, lcdb, hstate, y_ssm);
  hipLaunchKernelGGL(gatenorm_kernel, dim3(L), blk, 0, stream,
                     y_ssm, xBC, zxbcdt, idx_D, idx_norm_w, y_norm);

  // ---- index scores + topk (out-proj folded into Wq) ----
  hipMemsetAsync(q_idx, 0, 262144 * 4, stream);   // q_idx + adjacent k_idx in one memset
  {
    dim3 grid(1, 16, 32);  // 2 pairs x S=16
    hipLaunchKernelGGL(gemm_f32_dual, grid, blk, 0, stream,
                       y_norm, Wq, q_idx, x, idx_k_w, k_idx, 2048, 64, 1024, 16);
  }
  gemmf3(q_idx, k_idx, scores, 2048, 2048, 64, 1, 1);
  hipLaunchKernelGGL(topk_kernel, dim3(L), blk, 0, stream, scores, idxb);

  // ---- attention value path (aug split-bf16 MFMA) ----
  hipLaunchKernelGGL(conv_augA_kernel, dim3(cdiv(2048 * 1024, 256)), blk, 0, stream,
                     x, x_aug, 2048 * 1024, 1024, 1024);  // segBig2@0 (y_norm dead)
  hipMemsetAsync(c3, 0, 786432 * 4, stream);
  gemmb(x_aug, w_3down_aug, c3, 2048, 384, 3072, 3072, 3072, 384, 8);
  hipLaunchKernelGGL(conv_augA2_kernel, dim3(cdiv(2048 * 256, 256)), blk, 0, stream,
                     c3, c_q_aug, c_kv_aug);
  // fused: q_up (N=1536) + kv_up (N=2048) in one 28x16 launch
  {
    dim3 grid(28, 16, 1);
    hipLaunchKernelGGL(gemm_bf16_dual, grid, blk, 0, stream,
                       c_q_aug, w_qups_aug, qbuf,
                       c_kv_aug, w_kvup_aug, kvb,
                       12, 1536, 2048, 384, 384);
  }
  hipLaunchKernelGGL(rope_pack_kernel, dim3(L), dim3(128), 0, stream,
                     qbuf, kvb, c3, q_final, k_final);

  // ---- sparse attention + output projection ----
  hipLaunchKernelGGL(attn_kernel, dim3(L), blk, 0, stream,
                     q_final, k_final, kvb, idxb, attn_aug);
  hipMemsetAsync(out, 0, (size_t)out_size * 4, stream);
  gemmb(attn_aug, w_outp_aug, out, 2048, 1024, 3072, 3072, 3072, 1024, 4);
}

// Round 12
// 625.513 us; speedup vs baseline: 1.1745x; 1.0168x over previous
//
#include <hip/hip_runtime.h>
#include <math.h>

// ---------------- constants ----------------
constexpr int L      = 2048;
constexpr int NH     = 16;
constexpr int DINNER = 1024;
constexpr int MNH    = 32;
constexpr int CONVCH = 1152;
constexpr int INDIMP = 2304;   // padded stride for zxbcdt (2208 -> 2304, N%128)
constexpr int CHUNK  = 64;
constexpr int NCH    = 32;

using bf16x8 = __attribute__((ext_vector_type(8))) short;
using f32x4  = __attribute__((ext_vector_type(4))) float;

__device__ __forceinline__ f32x4 splat4(float x) { return (f32x4){x, x, x, x}; }

__device__ __forceinline__ unsigned short f2bf(float f) {
  unsigned u = __float_as_uint(f);
  return (unsigned short)((u + 0x7fffu + ((u >> 16) & 1u)) >> 16);
}
__device__ __forceinline__ float bf2f(unsigned short h) {
  return __uint_as_float((unsigned)h << 16);
}

// ---------------- fp32 GEMM v3 (small index-critical shapes) ----------------
// tri=1: skip blocks fully above the causal diagonal (outputs never read by topk).
__global__ __launch_bounds__(256) void gemm_f32_v3(
    const float* __restrict__ A, const float* __restrict__ W,
    float* __restrict__ C, int M, int N, int K, int tri) {
  __shared__ float As[16][132];
  __shared__ float Ws[16][132];
  int tid = threadIdx.x;
  int bm = blockIdx.y * 128, bn = blockIdx.x * 128;
  if (tri && bn > bm + 127) return;
  int kper = K / gridDim.z;
  int kb = blockIdx.z * kper, ke = kb + kper;
  int lr = tid >> 1;
  int lh = (tid & 1) * 8;
  int tx = tid & 15, ty = tid >> 4;
  bool wok = (bn + lr < N);
  const float* arow = A + (size_t)(bm + lr) * K + lh;
  const float* wrow = W + (size_t)(bn + lr) * K + lh;
  float4 a0, a1, w0, w1;
  auto gload = [&](int k0) {
    a0 = *(const float4*)(arow + k0);
    a1 = *(const float4*)(arow + k0 + 4);
    w0 = make_float4(0.f, 0.f, 0.f, 0.f); w1 = w0;
    if (wok) {
      w0 = *(const float4*)(wrow + k0);
      w1 = *(const float4*)(wrow + k0 + 4);
    }
  };
  f32x4 acc0[8] = {}, acc1[8] = {};
  gload(kb);
  for (int k0 = kb; k0 < ke; k0 += 16) {
    __syncthreads();
    As[lh+0][lr]=a0.x; As[lh+1][lr]=a0.y; As[lh+2][lr]=a0.z; As[lh+3][lr]=a0.w;
    As[lh+4][lr]=a1.x; As[lh+5][lr]=a1.y; As[lh+6][lr]=a1.z; As[lh+7][lr]=a1.w;
    Ws[lh+0][lr]=w0.x; Ws[lh+1][lr]=w0.y; Ws[lh+2][lr]=w0.z; Ws[lh+3][lr]=w0.w;
    Ws[lh+4][lr]=w1.x; Ws[lh+5][lr]=w1.y; Ws[lh+6][lr]=w1.z; Ws[lh+7][lr]=w1.w;
    __syncthreads();
    if (k0 + 16 < ke) gload(k0 + 16);
#pragma unroll
    for (int kk = 0; kk < 16; ++kk) {
      f32x4 b0 = *(const f32x4*)&Ws[kk][tx * 4];
      f32x4 b1 = *(const f32x4*)&Ws[kk][64 + tx * 4];
      f32x4 al = *(const f32x4*)&As[kk][ty * 8];
      f32x4 ah = *(const f32x4*)&As[kk][ty * 8 + 4];
#pragma unroll
      for (int i = 0; i < 4; ++i) {
        acc0[i]     += splat4(al[i]) * b0;
        acc1[i]     += splat4(al[i]) * b1;
        acc0[i + 4] += splat4(ah[i]) * b0;
        acc1[i + 4] += splat4(ah[i]) * b1;
      }
    }
  }
  bool single = (gridDim.z == 1);
#pragma unroll
  for (int i = 0; i < 8; ++i) {
    int row = bm + ty * 8 + i;
    float* crow = C + (size_t)row * N;
    int c0 = bn + tx * 4, c1 = bn + 64 + tx * 4;
    if (c0 + 3 < N) {
      if (single) *(f32x4*)(crow + c0) = acc0[i];
      else {
        atomicAdd(crow + c0 + 0, acc0[i][0]); atomicAdd(crow + c0 + 1, acc0[i][1]);
        atomicAdd(crow + c0 + 2, acc0[i][2]); atomicAdd(crow + c0 + 3, acc0[i][3]);
      }
    }
    if (c1 + 3 < N) {
      if (single) *(f32x4*)(crow + c1) = acc1[i];
      else {
        atomicAdd(crow + c1 + 0, acc1[i][0]); atomicAdd(crow + c1 + 1, acc1[i][1]);
        atomicAdd(crow + c1 + 2, acc1[i][2]); atomicAdd(crow + c1 + 3, acc1[i][3]);
      }
    }
  }
}

// ---------------- dual fp32 GEMM: two independent same-shape GEMMs in one grid ----------------
__global__ __launch_bounds__(256) void gemm_f32_dual(
    const float* __restrict__ A0, const float* __restrict__ W0, float* __restrict__ C0,
    const float* __restrict__ A1, const float* __restrict__ W1, float* __restrict__ C1,
    int M, int N, int K, int S) {
  __shared__ float As[16][132];
  __shared__ float Ws[16][132];
  int tid = threadIdx.x;
  int bm = blockIdx.y * 128, bn = blockIdx.x * 128;
  int pair = (int)blockIdx.z >= S;
  int zi = blockIdx.z - pair * S;
  const float* A = pair ? A1 : A0;
  const float* W = pair ? W1 : W0;
  float* C = pair ? C1 : C0;
  int kper = K / S;
  int kb = zi * kper, ke = kb + kper;
  int lr = tid >> 1;
  int lh = (tid & 1) * 8;
  int tx = tid & 15, ty = tid >> 4;
  bool wok = (bn + lr < N);
  const float* arow = A + (size_t)(bm + lr) * K + lh;
  const float* wrow = W + (size_t)(bn + lr) * K + lh;
  float4 a0, a1, w0, w1;
  auto gload = [&](int k0) {
    a0 = *(const float4*)(arow + k0);
    a1 = *(const float4*)(arow + k0 + 4);
    w0 = make_float4(0.f, 0.f, 0.f, 0.f); w1 = w0;
    if (wok) {
      w0 = *(const float4*)(wrow + k0);
      w1 = *(const float4*)(wrow + k0 + 4);
    }
  };
  f32x4 acc0[8] = {}, acc1[8] = {};
  gload(kb);
  for (int k0 = kb; k0 < ke; k0 += 16) {
    __syncthreads();
    As[lh+0][lr]=a0.x; As[lh+1][lr]=a0.y; As[lh+2][lr]=a0.z; As[lh+3][lr]=a0.w;
    As[lh+4][lr]=a1.x; As[lh+5][lr]=a1.y; As[lh+6][lr]=a1.z; As[lh+7][lr]=a1.w;
    Ws[lh+0][lr]=w0.x; Ws[lh+1][lr]=w0.y; Ws[lh+2][lr]=w0.z; Ws[lh+3][lr]=w0.w;
    Ws[lh+4][lr]=w1.x; Ws[lh+5][lr]=w1.y; Ws[lh+6][lr]=w1.z; Ws[lh+7][lr]=w1.w;
    __syncthreads();
    if (k0 + 16 < ke) gload(k0 + 16);
#pragma unroll
    for (int kk = 0; kk < 16; ++kk) {
      f32x4 b0 = *(const f32x4*)&Ws[kk][tx * 4];
      f32x4 b1 = *(const f32x4*)&Ws[kk][64 + tx * 4];
      f32x4 al = *(const f32x4*)&As[kk][ty * 8];
      f32x4 ah = *(const f32x4*)&As[kk][ty * 8 + 4];
#pragma unroll
      for (int i = 0; i < 4; ++i) {
        acc0[i]     += splat4(al[i]) * b0;
        acc1[i]     += splat4(al[i]) * b1;
        acc0[i + 4] += splat4(ah[i]) * b0;
        acc1[i + 4] += splat4(ah[i]) * b1;
      }
    }
  }
#pragma unroll
  for (int i = 0; i < 8; ++i) {
    int row = bm + ty * 8 + i;
    float* crow = C + (size_t)row * N;
    int c0 = bn + tx * 4, c1 = bn + 64 + tx * 4;
    if (c0 + 3 < N) {
      atomicAdd(crow + c0 + 0, acc0[i][0]); atomicAdd(crow + c0 + 1, acc0[i][1]);
      atomicAdd(crow + c0 + 2, acc0[i][2]); atomicAdd(crow + c0 + 3, acc0[i][3]);
    }
    if (c1 + 3 < N) {
      atomicAdd(crow + c1 + 0, acc1[i][0]); atomicAdd(crow + c1 + 1, acc1[i][1]);
      atomicAdd(crow + c1 + 2, acc1[i][2]); atomicAdd(crow + c1 + 3, acc1[i][3]);
    }
  }
}

// ---------------- bf16 MFMA GEMM (double-buffered LDS: stage(t+1) || compute(t)) ----------------
__global__ __launch_bounds__(256) void gemm_bf16_kernel(
    const unsigned short* __restrict__ A, const unsigned short* __restrict__ W,
    float* __restrict__ C, int M, int N, int K, int lda, int ldb, int ldc) {
  __shared__ unsigned short As[2][128 * 64];
  __shared__ unsigned short Ws[2][128 * 64];
  int tid = threadIdx.x;
  int bx = blockIdx.x, by = blockIdx.y;
  int nxy = gridDim.x * gridDim.y;
  if ((nxy & 7) == 0) {
    int lin = by * gridDim.x + bx;
    int cpx = nxy >> 3;
    int swz = (lin & 7) * cpx + (lin >> 3);
    bx = swz % gridDim.x;
    by = swz / gridDim.x;
  }
  int bm = by * 128, bn = bx * 128;
  int kper = K / gridDim.z;
  int k_begin = blockIdx.z * kper;
  int k_end = k_begin + kper;
  int wv = tid >> 6, lane = tid & 63;
  int wrow = (wv >> 1) * 64, wcol = (wv & 1) * 64;
  int lrow = lane & 15, quad = lane >> 4;

  f32x4 acc[4][4] = {};

  auto stage = [&](int b, int k0) {
#pragma unroll
    for (int it = 0; it < 4; ++it) {
      int s = it * 256 + tid;
      int r = s >> 3;
      int q = (s & 7) ^ (r & 7);
      const unsigned short* ga = A + (size_t)(bm + r) * lda + k0 + q * 8;
      const unsigned short* gw = W + (size_t)(bn + r) * ldb + k0 + q * 8;
      __builtin_amdgcn_global_load_lds((const __attribute__((address_space(1))) void*)ga,
                                       (__attribute__((address_space(3))) void*)&As[b][s * 8], 16, 0, 0);
      __builtin_amdgcn_global_load_lds((const __attribute__((address_space(1))) void*)gw,
                                       (__attribute__((address_space(3))) void*)&Ws[b][s * 8], 16, 0, 0);
    }
  };

  stage(0, k_begin);
  int cur = 0;
  for (int k0 = k_begin; k0 < k_end; k0 += 64) {
    __syncthreads();
    if (k0 + 64 < k_end) stage(cur ^ 1, k0 + 64);
#pragma unroll
    for (int ks = 0; ks < 2; ++ks) {
      bf16x8 af[4], wf[4];
#pragma unroll
      for (int i = 0; i < 4; ++i) {
        int ra = wrow + i * 16 + lrow;
        int qa = (ks * 4 + quad) ^ (ra & 7);
        af[i] = *(const bf16x8*)&As[cur][(ra * 8 + qa) * 8];
        int rw = wcol + i * 16 + lrow;
        int qw = (ks * 4 + quad) ^ (rw & 7);
        wf[i] = *(const bf16x8*)&Ws[cur][(rw * 8 + qw) * 8];
      }
#pragma unroll
      for (int i = 0; i < 4; ++i)
#pragma unroll
        for (int j = 0; j < 4; ++j)
          acc[i][j] = __builtin_amdgcn_mfma_f32_16x16x32_bf16(af[i], wf[j], acc[i][j], 0, 0, 0);
    }
    cur ^= 1;
  }
  bool single = (gridDim.z == 1);
#pragma unroll
  for (int i = 0; i < 4; ++i)
#pragma unroll
    for (int j = 0; j < 4; ++j)
#pragma unroll
      for (int r = 0; r < 4; ++r) {
        int row = bm + wrow + i * 16 + quad * 4 + r;
        int col = bn + wcol + j * 16 + lrow;
        float v = acc[i][j][r];
        if (single) C[(size_t)row * ldc + col] = v;
        else atomicAdd(&C[(size_t)row * ldc + col], v);
      }
}

// ---------------- 256^2-tile 8-wave bf16 GEMM with 4-cell half-K (32) pipeline ----------------
// R11-verified: swizzle f(r)=(r>>1)&3 (2-way banks, conflict-free) + T5 setprio.
__global__ __launch_bounds__(512) void gemm_bf16_256_kernel(
    const unsigned short* __restrict__ A, const unsigned short* __restrict__ W,
    float* __restrict__ C, int K, int lda, int ldc) {
  __shared__ unsigned short As[4][256 * 32];
  __shared__ unsigned short Ws[4][256 * 32];
  int tid = threadIdx.x;
  int bx = blockIdx.x, by = blockIdx.y;
  int nxy = gridDim.x * gridDim.y;
  if ((nxy & 7) == 0) {
    int lin = by * gridDim.x + bx;
    int cpx = nxy >> 3;
    int swz = (lin & 7) * cpx + (lin >> 3);
    bx = swz % gridDim.x;
    by = swz / gridDim.x;
  }
  int bm = by * 256, bn = bx * 256;
  int kper = K / gridDim.z;
  int kb = blockIdx.z * kper;
  int U = kper >> 5;
  int wave = tid >> 6, lane = tid & 63;
  int wr = wave >> 2, wc = wave & 3;
  int lrow = lane & 15, quad = lane >> 4;

  f32x4 acc[8][4] = {};

  auto stage = [&](int cell, int u) {
    int k0 = kb + (u << 5);
#pragma unroll
    for (int rd = 0; rd < 2; ++rd) {
      int s = rd * 512 + tid;
      int r = s >> 2;
      int q = (s & 3) ^ ((r >> 1) & 3);
      const unsigned short* ga = A + (size_t)(bm + r) * lda + k0 + q * 8;
      __builtin_amdgcn_global_load_lds((const __attribute__((address_space(1))) void*)ga,
          (__attribute__((address_space(3))) void*)&As[cell][s * 8], 16, 0, 0);
    }
#pragma unroll
    for (int rd = 0; rd < 2; ++rd) {
      int s = rd * 512 + tid;
      int r = s >> 2;
      int q = (s & 3) ^ ((r >> 1) & 3);
      const unsigned short* gw = W + (size_t)(bn + r) * lda + k0 + q * 8;
      __builtin_amdgcn_global_load_lds((const __attribute__((address_space(1))) void*)gw,
          (__attribute__((address_space(3))) void*)&Ws[cell][s * 8], 16, 0, 0);
    }
  };

  auto compute = [&](int cell) {
    bf16x8 af[8], wf[4];
#pragma unroll
    for (int m = 0; m < 8; ++m) {
      int ra = wr * 128 + m * 16 + lrow;
      af[m] = *(const bf16x8*)&As[cell][((ra << 2) + (quad ^ ((ra >> 1) & 3))) * 8];
    }
#pragma unroll
    for (int n = 0; n < 4; ++n) {
      int rw = wc * 64 + n * 16 + lrow;
      wf[n] = *(const bf16x8*)&Ws[cell][((rw << 2) + (quad ^ ((rw >> 1) & 3))) * 8];
    }
    __builtin_amdgcn_s_setprio(1);
#pragma unroll
    for (int m = 0; m < 8; ++m)
#pragma unroll
      for (int n = 0; n < 4; ++n)
        acc[m][n] = __builtin_amdgcn_mfma_f32_16x16x32_bf16(af[m], wf[n], acc[m][n], 0, 0, 0);
    __builtin_amdgcn_s_setprio(0);
  };

  stage(0, 0); stage(1, 1); stage(2, 2);
  for (int u = 0; u + 3 < U; ++u) {
    __builtin_amdgcn_s_barrier();
    asm volatile("" ::: "memory");
    stage((u + 3) & 3, u + 3);
    asm volatile("s_waitcnt vmcnt(12)" ::: "memory");
    __builtin_amdgcn_s_barrier();
    asm volatile("" ::: "memory");
    compute(u & 3);
  }
  for (int u = U - 3; u < U; ++u) {
    __builtin_amdgcn_s_barrier();
    asm volatile("s_waitcnt vmcnt(0)" ::: "memory");
    __builtin_amdgcn_s_barrier();
    asm volatile("" ::: "memory");
    compute(u & 3);
  }

#pragma unroll
  for (int m = 0; m < 8; ++m)
#pragma unroll
    for (int n = 0; n < 4; ++n)
#pragma unroll
      for (int rr = 0; rr < 4; ++rr) {
        int row = bm + wr * 128 + m * 16 + quad * 4 + rr;
        int col = bn + wc * 64 + n * 16 + lrow;
        atomicAdd(&C[(size_t)row * ldc + col], acc[m][n][rr]);
      }
}

// ---------------- dual bf16 MFMA GEMM: q_up + kv_up in one launch ----------------
__global__ __launch_bounds__(256) void gemm_bf16_dual(
    const unsigned short* __restrict__ A0, const unsigned short* __restrict__ W0,
    float* __restrict__ C0,
    const unsigned short* __restrict__ A1, const unsigned short* __restrict__ W1,
    float* __restrict__ C1,
    int nx0, int ldc0, int ldc1, int K, int ld) {
  __shared__ unsigned short As[2][128 * 64];
  __shared__ unsigned short Ws[2][128 * 64];
  int tid = threadIdx.x;
  int bx = blockIdx.x, by = blockIdx.y;
  int pair = bx >= nx0;
  int bxl = pair ? bx - nx0 : bx;
  const unsigned short* A = pair ? A1 : A0;
  const unsigned short* W = pair ? W1 : W0;
  float* C = pair ? C1 : C0;
  int ldc = pair ? ldc1 : ldc0;
  int bm = by * 128, bn = bxl * 128;
  int wv = tid >> 6, lane = tid & 63;
  int wrow = (wv >> 1) * 64, wcol = (wv & 1) * 64;
  int lrow = lane & 15, quad = lane >> 4;

  f32x4 acc[4][4] = {};

  auto stage = [&](int b, int k0) {
#pragma unroll
    for (int it = 0; it < 4; ++it) {
      int s = it * 256 + tid;
      int r = s >> 3;
      int q = (s & 7) ^ (r & 7);
      const unsigned short* ga = A + (size_t)(bm + r) * ld + k0 + q * 8;
      const unsigned short* gw = W + (size_t)(bn + r) * ld + k0 + q * 8;
      __builtin_amdgcn_global_load_lds((const __attribute__((address_space(1))) void*)ga,
                                       (__attribute__((address_space(3))) void*)&As[b][s * 8], 16, 0, 0);
      __builtin_amdgcn_global_load_lds((const __attribute__((address_space(1))) void*)gw,
                                       (__attribute__((address_space(3))) void*)&Ws[b][s * 8], 16, 0, 0);
    }
  };

  stage(0, 0);
  int cur = 0;
  for (int k0 = 0; k0 < K; k0 += 64) {
    __syncthreads();
    if (k0 + 64 < K) stage(cur ^ 1, k0 + 64);
#pragma unroll
    for (int ks = 0; ks < 2; ++ks) {
      bf16x8 af[4], wf[4];
#pragma unroll
      for (int i = 0; i < 4; ++i) {
        int ra = wrow + i * 16 + lrow;
        int qa = (ks * 4 + quad) ^ (ra & 7);
        af[i] = *(const bf16x8*)&As[cur][(ra * 8 + qa) * 8];
        int rw = wcol + i * 16 + lrow;
        int qw = (ks * 4 + quad) ^ (rw & 7);
        wf[i] = *(const bf16x8*)&Ws[cur][(rw * 8 + qw) * 8];
      }
#pragma unroll
      for (int i = 0; i < 4; ++i)
#pragma unroll
        for (int j = 0; j < 4; ++j)
          acc[i][j] = __builtin_amdgcn_mfma_f32_16x16x32_bf16(af[i], wf[j], acc[i][j], 0, 0, 0);
    }
    cur ^= 1;
  }
#pragma unroll
  for (int i = 0; i < 4; ++i)
#pragma unroll
    for (int j = 0; j < 4; ++j)
#pragma unroll
      for (int r = 0; r < 4; ++r) {
        int row = bm + wrow + i * 16 + quad * 4 + r;
        int col = bn + wcol + j * 16 + lrow;
        C[(size_t)row * ldc + col] = acc[i][j][r];
      }
}

// ---------------- fused weight-prep ----------------
// regions: [0,20736) elementwise conversions | [20736,21760) transpose(idx_out_w)
//        | [21760,22784) qwpad+Wq init (copy idx_q_w rows, zero rest; Wq contiguous)
//        | [22784,41216) zxbcdt zero (accumulation base for in_proj atomics)
__global__ __launch_bounds__(256) void prep_weights_kernel(
    const float* __restrict__ x, unsigned short* __restrict__ x_trip,
    const float* __restrict__ idx_in_w, unsigned short* __restrict__ w_in_trip,
    const float* __restrict__ q_down_w, const float* __restrict__ kv_down_w,
    const float* __restrict__ k_rope_w, unsigned short* __restrict__ w3down,
    const float* __restrict__ q_up_w, const float* __restrict__ q_rope_w,
    unsigned short* __restrict__ wqups,
    const float* __restrict__ kv_up_w, unsigned short* __restrict__ wkvup,
    const float* __restrict__ idx_out_w, float* __restrict__ out_w_T,
    const float* __restrict__ idx_q_w, float* __restrict__ qwpad,
    float* __restrict__ zxbcdt) {
  __shared__ float tsh[32][33];
  int bid = blockIdx.x;
  if (bid >= 22784) {
    int j = (bid - 22784) * 256 + threadIdx.x;   // < 4718592 exact
    zxbcdt[j] = 0.f;
    return;
  }
  if (bid >= 21760) {
    int j = (bid - 21760) * 256 + threadIdx.x;   // < 262144: qwpad[0..131071] | Wq contiguous after
    qwpad[j] = (j < 65536) ? idx_q_w[j] : 0.f;
    return;
  }
  if (bid >= 20736) {
    int b = bid - 20736;
    int bx = b & 31, by = b >> 5;
    int tx = threadIdx.x & 31, ty8 = threadIdx.x >> 5;
    for (int r = ty8; r < 32; r += 8)
      tsh[r][tx] = idx_out_w[(size_t)(by * 32 + r) * 1024 + bx * 32 + tx];
    __syncthreads();
    for (int r = ty8; r < 32; r += 8)
      out_w_T[(size_t)(bx * 32 + r) * 1024 + by * 32 + tx] = tsh[tx][r];
    return;
  }
  int i = bid * 256 + threadIdx.x;
  if (i < 2097152) {
    float f = x[i];
    unsigned short h = f2bf(f);
    float r1 = f - bf2f(h);
    unsigned short m = f2bf(r1);
    unsigned short l = f2bf(r1 - bf2f(m));
    size_t o = (size_t)i * 6;
    x_trip[o] = h; x_trip[o + 1] = m; x_trip[o + 2] = l;
    x_trip[o + 3] = h; x_trip[o + 4] = m; x_trip[o + 5] = h;
  } else if (i < 4456448) {
    int j = i - 2097152;
    int n = j >> 10, k = j & 1023;
    unsigned short h = 0, m = 0, l = 0;
    if (n < 2208) {
      float f = idx_in_w[(size_t)n * 1024 + k];
      h = f2bf(f);
      float r1 = f - bf2f(h);
      m = f2bf(r1);
      l = f2bf(r1 - bf2f(m));
    }
    size_t o = (size_t)j * 6;
    w_in_trip[o] = h; w_in_trip[o + 1] = h; w_in_trip[o + 2] = h;
    w_in_trip[o + 3] = m; w_in_trip[o + 4] = m; w_in_trip[o + 5] = l;
  } else {
    int j2 = i - 4456448;
    const float* src; unsigned short* dst; int rows, K; size_t obase; int idx;
    if (j2 < 393216) {
      int r = j2 >> 17;
      idx = j2 & 131071;
      K = 1024;
      src = (r == 0) ? q_down_w : (r == 1) ? kv_down_w : k_rope_w;
      rows = (r == 2) ? 32 : 128;
      dst = w3down; obase = (size_t)(r * 131072 + idx) * 3;
    } else if (j2 < 524288) {
      idx = j2 - 393216; K = 128; src = q_up_w; rows = 1024;
      dst = wqups; obase = (size_t)idx * 3;
    } else if (j2 < 589824) {
      idx = j2 - 524288; K = 128; src = q_rope_w; rows = 512;
      dst = wqups; obase = (size_t)393216 + (size_t)idx * 3;
    } else {
      idx = j2 - 589824; K = 128; src = kv_up_w; rows = 2048;
      dst = wkvup; obase = (size_t)idx * 3;
    }
    int n = idx / K, k = idx - n * K;
    unsigned short hi = 0, lo = 0;
    if (n < rows) {
      float f = src[(size_t)n * K + k];
      hi = f2bf(f);
      lo = f2bf(f - bf2f(hi));
    }
    dst[obase] = hi; dst[obase + 1] = hi; dst[obase + 2] = lo;
  }
}

// ---------------- fused post-in_proj: caugW(out_w) + conv_silu + dt ----------------
__global__ __launch_bounds__(256) void post_inproj_kernel(
    const float* __restrict__ out_w, unsigned short* __restrict__ w_outp,
    const float* __restrict__ zxbcdt, const float* __restrict__ conv_w,
    const float* __restrict__ conv_b, float* __restrict__ xBC,
    const float* __restrict__ dt_bias, const float* __restrict__ A_log,
    float* __restrict__ dt, float* __restrict__ logdA) {
  int i = blockIdx.x * 256 + threadIdx.x;
  if (i < 1048576) {
    float f = out_w[i];
    unsigned short hi = f2bf(f);
    unsigned short lo = f2bf(f - bf2f(hi));
    size_t o = (size_t)i * 3;
    w_outp[o] = hi; w_outp[o + 1] = hi; w_outp[o + 2] = lo;
  } else if (i < 3407872) {
    int idx = i - 1048576;
    int l = idx / CONVCH, c = idx - l * CONVCH;
    float acc = conv_b[c];
#pragma unroll
    for (int k = 0; k < 4; ++k) {
      int ls = l - 3 + k;
      if (ls >= 0) acc += zxbcdt[(size_t)ls * INDIMP + DINNER + c] * conv_w[c * 4 + k];
    }
    xBC[idx] = acc / (1.f + expf(-acc));
  } else {
    int idx = i - 3407872;
    int l = idx >> 5, h = idx & 31;
    float xv = zxbcdt[(size_t)l * INDIMP + 2176 + h] + dt_bias[h];
    float sp = fmaxf(xv, 0.f) + log1pf(expf(-fabsf(xv)));
    dt[idx] = sp;
    logdA[idx] = sp * -expf(A_log[h]);
  }
}

// ---------------- conversions ----------------
__global__ __launch_bounds__(256) void conv_augA2_kernel(
    const float* __restrict__ c3, unsigned short* __restrict__ dq,
    unsigned short* __restrict__ dkv) {
  int i = blockIdx.x * 256 + threadIdx.x;
  if (i >= 2048 * 256) return;
  int m = i >> 8, k = i & 255;
  float f = c3[(size_t)m * 384 + k];
  unsigned short hi = f2bf(f);
  unsigned short lo = f2bf(f - bf2f(hi));
  if (k < 128) {
    size_t o = ((size_t)m * 128 + k) * 3;
    dq[o] = hi; dq[o + 1] = lo; dq[o + 2] = hi;
  } else {
    size_t o = ((size_t)m * 128 + (k - 128)) * 3;
    dkv[o] = hi; dkv[o + 1] = lo; dkv[o + 2] = hi;
  }
}

// ---------------- G[c][t][s] = C_t . B_s  (+ lcd region in blocks 32..35) ----------------
__global__ __launch_bounds__(256) void chunk_G_kernel(
    const float* __restrict__ xBC, float* __restrict__ G,
    const float* __restrict__ logdA, float* __restrict__ lcd) {
  int c = blockIdx.x, tid = threadIdx.x;
  if (c >= NCH) {
    int i = (c - NCH) * 256 + tid;
    int cc = i >> 5, h = i & 31;
    float s = 0.f;
    for (int t = 0; t < CHUNK; ++t) {
      s += logdA[(cc * CHUNK + t) * MNH + h];
      lcd[(size_t)i * CHUNK + t] = s;
    }
    return;
  }
  __shared__ float BsT[64][68];
  __shared__ float Cs[64][65];
  int t = tid >> 2, q = tid & 3;
  const float* row = xBC + (size_t)(c * 64 + t) * CONVCH + DINNER;
#pragma unroll
  for (int j = 0; j < 16; j += 4) {
    float4 b = *(const float4*)(row + q * 16 + j);
    BsT[q * 16 + j + 0][t] = b.x; BsT[q * 16 + j + 1][t] = b.y;
    BsT[q * 16 + j + 2][t] = b.z; BsT[q * 16 + j + 3][t] = b.w;
    float4 cv = *(const float4*)(row + 64 + q * 16 + j);
    Cs[t][q * 16 + j + 0] = cv.x; Cs[t][q * 16 + j + 1] = cv.y;
    Cs[t][q * 16 + j + 2] = cv.z; Cs[t][q * 16 + j + 3] = cv.w;
  }
  __syncthreads();
  int s0 = q * 16;
  f32x4 g0 = {}, g1 = {}, g2 = {}, g3 = {};
  for (int n = 0; n < 64; ++n) {
    f32x4 cv = splat4(Cs[t][n]);
    g0 += cv * *(const f32x4*)&BsT[n][s0];
    g1 += cv * *(const f32x4*)&BsT[n][s0 + 4];
    g2 += cv * *(const f32x4*)&BsT[n][s0 + 8];
    g3 += cv * *(const f32x4*)&BsT[n][s0 + 12];
  }
  float* gp = G + ((size_t)c * 64 + t) * 64 + s0;
  *(f32x4*)gp = g0; *(f32x4*)(gp + 4) = g1; *(f32x4*)(gp + 8) = g2; *(f32x4*)(gp + 12) = g3;
}

// ---------------- scan pass A ----------------
__global__ __launch_bounds__(256) void scan_local_kernel(
    const float* __restrict__ xBC, const float* __restrict__ dt,
    const float* __restrict__ lcd, float* __restrict__ hstate) {
  int c = blockIdx.x >> 5, h = blockIdx.x & 31;
  int tid = threadIdx.x;
  __shared__ float Bs[64][68];
  __shared__ float xss[64][36];
  __shared__ float w2s[64];
  int t0 = c * CHUNK;
  int t = tid >> 2, q = tid & 3;
  const float* row = xBC + (size_t)(t0 + t) * CONVCH;
#pragma unroll
  for (int j = 0; j < 16; j += 4)
    *(float4*)&Bs[t][q * 16 + j] = *(const float4*)(row + DINNER + q * 16 + j);
  if (q < 2) {
#pragma unroll
    for (int j = 0; j < 16; j += 4)
      *(float4*)&xss[t][q * 16 + j] = *(const float4*)(row + h * 32 + q * 16 + j);
  }
  if (tid < 64) {
    const float* lc = lcd + ((size_t)c * 32 + h) * CHUNK;
    w2s[tid] = expf(lc[63] - lc[tid]) * dt[(t0 + tid) * MNH + h];
  }
  __syncthreads();
  int n = tid >> 2, pg = (tid & 3) * 8;
  f32x4 h0 = {}, h1 = {};
  for (int s = 0; s < 64; ++s) {
    f32x4 wb = splat4(w2s[s] * Bs[s][n]);
    h0 += wb * *(const f32x4*)&xss[s][pg];
    h1 += wb * *(const f32x4*)&xss[s][pg + 4];
  }
  float* hp = hstate + ((size_t)c * 32 + h) * 2048 + n * 32 + pg;
  *(f32x4*)hp = h0; *(f32x4*)(hp + 4) = h1;
}

// ---------------- scan pass B ----------------
__global__ __launch_bounds__(256) void scan_combine_kernel(
    float* __restrict__ hstate, const float* __restrict__ lcd) {
  int i = blockIdx.x * 256 + threadIdx.x;
  int h = i >> 11;
  float H = 0.f;
  for (int c = 0; c < NCH; ++c) {
    float hl = hstate[(size_t)c * 65536 + i];
    hstate[(size_t)c * 65536 + i] = H;
    float P = expf(lcd[((size_t)c * 32 + h) * CHUNK + CHUNK - 1]);
    H = H * P + hl;
  }
}

// ---------------- scan pass C ----------------
__global__ __launch_bounds__(256) void scan_y_kernel(
    const float* __restrict__ xBC, const float* __restrict__ G,
    const float* __restrict__ dt, const float* __restrict__ lcd,
    const float* __restrict__ hstate, float* __restrict__ y) {
  int c = blockIdx.x >> 5, h = blockIdx.x & 31;
  int tid = threadIdx.x;
  __shared__ float Ms[64][65];
  __shared__ float Cs[64][65];
  __shared__ float xss[64][36];
  __shared__ float Hss[64][36];
  __shared__ float lcds[64], dts[64];
  int t0 = c * CHUNK;
  int t = tid >> 2, q = tid & 3;
  const float* row = xBC + (size_t)(t0 + t) * CONVCH;
#pragma unroll
  for (int j = 0; j < 16; j += 4) {
    float4 cv = *(const float4*)(row + DINNER + 64 + q * 16 + j);
    Cs[t][q * 16 + j + 0] = cv.x; Cs[t][q * 16 + j + 1] = cv.y;
    Cs[t][q * 16 + j + 2] = cv.z; Cs[t][q * 16 + j + 3] = cv.w;
  }
  if (q < 2) {
#pragma unroll
    for (int j = 0; j < 16; j += 4)
      *(float4*)&xss[t][q * 16 + j] = *(const float4*)(row + h * 32 + q * 16 + j);
  }
  {
    const float* gp = G + ((size_t)c * 64 + t) * 64 + q * 16;
#pragma unroll
    for (int j = 0; j < 16; j += 4) {
      float4 g = *(const float4*)(gp + j);
      Ms[t][q * 16 + j + 0] = g.x; Ms[t][q * 16 + j + 1] = g.y;
      Ms[t][q * 16 + j + 2] = g.z; Ms[t][q * 16 + j + 3] = g.w;
    }
  }
  {
    const float* hp = hstate + ((size_t)c * 32 + h) * 2048 + tid * 8;
    int n = tid >> 2, p0 = (tid & 3) * 8;
    *(float4*)&Hss[n][p0]     = *(const float4*)hp;
    *(float4*)&Hss[n][p0 + 4] = *(const float4*)(hp + 4);
  }
  if (tid < 64) {
    lcds[tid] = lcd[((size_t)c * 32 + h) * CHUNK + tid];
    dts[tid]  = dt[(t0 + tid) * MNH + h];
  }
  __syncthreads();
  {
    int s0 = q * 16;
#pragma unroll
    for (int j = 0; j < 16; ++j) {
      int s = s0 + j;
      float m = (s <= t) ? expf(lcds[t] - lcds[s]) * dts[s] * Ms[t][s] : 0.f;
      Ms[t][s] = m;
    }
  }
  __syncthreads();
  int pg = q * 8;
  f32x4 y0 = {}, y1 = {}, a0 = {}, a1 = {};
  for (int s = 0; s < 64; ++s) {
    f32x4 m = splat4(Ms[t][s]);
    y0 += m * *(const f32x4*)&xss[s][pg];
    y1 += m * *(const f32x4*)&xss[s][pg + 4];
  }
  for (int n = 0; n < 64; ++n) {
    f32x4 cn = splat4(Cs[t][n]);
    a0 += cn * *(const f32x4*)&Hss[n][pg];
    a1 += cn * *(const f32x4*)&Hss[n][pg + 4];
  }
  f32x4 cd = splat4(expf(lcds[t]));
  y0 += cd * a0; y1 += cd * a1;
  float* yp = y + (size_t)(t0 + t) * DINNER + h * 32 + pg;
  *(f32x4*)yp = y0; *(f32x4*)(yp + 4) = y1;
}

// ---------------- gate + RMSNorm ----------------
__global__ __launch_bounds__(256) void gatenorm_kernel(
    const float* __restrict__ y_ssm, const float* __restrict__ xBC,
    const float* __restrict__ zxbcdt, const float* __restrict__ Dv,
    const float* __restrict__ norm_w, float* __restrict__ out) {
  int l = blockIdx.x, tid = threadIdx.x;
  float vals[4];
  float ss = 0.f;
#pragma unroll
  for (int i = 0; i < 4; ++i) {
    int d = tid + i * 256;
    int h = d >> 5;
    float v = y_ssm[(size_t)l * DINNER + d] + Dv[h] * xBC[(size_t)l * CONVCH + d];
    float z = zxbcdt[(size_t)l * INDIMP + d];
    v *= z / (1.f + expf(-z));
    vals[i] = v;
    ss += v * v;
  }
#pragma unroll
  for (int off = 32; off > 0; off >>= 1) ss += __shfl_xor(ss, off);
  __shared__ float sred[4];
  if ((tid & 63) == 0) sred[tid >> 6] = ss;
  __syncthreads();
  float tot = sred[0] + sred[1] + sred[2] + sred[3];
  float scale = rsqrtf(tot * (1.f / 1024.f) + 1e-5f);
#pragma unroll
  for (int i = 0; i < 4; ++i) {
    int d = tid + i * 256;
    out[(size_t)l * DINNER + d] = vals[i] * scale * norm_w[d];
  }
}

// ---------------- fused: topk (blocks 0..2047) + augA x->x_aug + c3 zero ----------------
// Safe: y_norm(segBig2@0)'s last reader is the dual q_idx gemm (before scores);
// c3 aliases xBC whose last reader (gatenorm) precedes this launch.
__global__ __launch_bounds__(256) void topk_augA_kernel(
    const float* __restrict__ scores, int* __restrict__ out_idx,
    const float* __restrict__ x, unsigned short* __restrict__ x_aug,
    float* __restrict__ c3) {
  int bid = blockIdx.x, tid = threadIdx.x;
  if (bid >= 10240) {
    int j = (bid - 10240) * 256 + tid;   // < 786432 exact
    c3[j] = 0.f;
    return;
  }
  if (bid >= 2048) {
    int i = (bid - 2048) * 256 + tid;    // < 2097152 exact (x is contiguous 2048x1024)
    float f = x[i];
    unsigned short hi = f2bf(f);
    unsigned short lo = f2bf(f - bf2f(hi));
    size_t o = (size_t)i * 3;
    x_aug[o] = hi; x_aug[o + 1] = lo; x_aug[o + 2] = hi;
    return;
  }
  int l = bid;
  if (l < 64) {
    if (tid < 64) out_idx[l * 64 + tid] = tid;
    return;
  }
  int n = l + 1;
  const float* row = scores + (size_t)l * L;
  __shared__ int hist[256];
  __shared__ unsigned sel_prefix;
  __shared__ int sel_remaining;
  __shared__ int cnt_g, cnt_e;
  __shared__ int eq_list[128];
  if (tid == 0) { cnt_g = 0; cnt_e = 0; }
  unsigned prefix = 0;
  int remaining = 64;
  for (int pass = 0; pass < 4; ++pass) {
    int shift = 24 - 8 * pass;
    unsigned himask = (pass == 0) ? 0u : (0xFFFFFFFFu << (shift + 8));
    hist[tid] = 0;
    __syncthreads();
    for (int j = tid; j < n; j += 256) {
      unsigned u = __float_as_uint(row[j]);
      unsigned key = (u & 0x80000000u) ? ~u : (u | 0x80000000u);
      if (((key ^ prefix) & himask) == 0)
        atomicAdd(&hist[(key >> shift) & 255], 1);
    }
    __syncthreads();
    if (tid == 0) {
      int cum = 0, b = 255;
      for (; b >= 0; --b) {
        cum += hist[b];
        if (cum >= remaining) break;
      }
      sel_prefix = prefix | ((unsigned)b << shift);
      sel_remaining = remaining - (cum - hist[b]);
    }
    __syncthreads();
    prefix = sel_prefix;
    remaining = sel_remaining;
    __syncthreads();
  }
  unsigned T = prefix;
  for (int j = tid; j < n; j += 256) {
    unsigned u = __float_as_uint(row[j]);
    unsigned key = (u & 0x80000000u) ? ~u : (u | 0x80000000u);
    if (key > T) {
      int p = atomicAdd(&cnt_g, 1);
      out_idx[l * 64 + p] = j;
    } else if (key == T) {
      int p = atomicAdd(&cnt_e, 1);
      if (p < 128) eq_list[p] = j;
    }
  }
  __syncthreads();
  if (tid == 0) {
    int G = cnt_g;
    int E = remaining;
    int m = cnt_e < 128 ? cnt_e : 128;
    for (int e = 0; e < E; ++e) {
      int best = 0, bj = 0x7fffffff;
      for (int i = 0; i < m; ++i)
        if (eq_list[i] < bj) { bj = eq_list[i]; best = i; }
      out_idx[l * 64 + G + e] = bj;
      eq_list[best] = 0x7fffffff;
    }
  }
}

// ---------------- RoPE + pack q_final/k_final (fused-buffer strides) ----------------
__global__ __launch_bounds__(128) void rope_pack_kernel(
    const float* __restrict__ qbuf, const float* __restrict__ kv,
    const float* __restrict__ c3,
    float* __restrict__ q_final, float* __restrict__ k_final) {
  int l = blockIdx.x, tid = threadIdx.x;
  __shared__ float s_s[16], s_c[16];
  if (tid < 16) {
    float inv = powf(10000.f, -(float)tid / 16.f);
    float ang = (float)l * inv;
    s_s[tid] = sinf(ang);
    s_c[tid] = cosf(ang);
  }
  __syncthreads();
  const float* qrow = qbuf + (size_t)l * 1536;
  const float* krow = c3 + (size_t)l * 384 + 256;
  for (int e = tid; e < NH * 96; e += 128) {
    int hh = e / 96, d = e - hh * 96;
    float qv, kvv;
    if (d < 64) {
      qv  = qrow[hh * 64 + d];
      kvv = kv[(size_t)l * 2048 + hh * 64 + d];
    } else {
      int r = d - 64;
      if (r < 16) {
        float q1 = qrow[1024 + hh * 32 + r];
        float q2 = qrow[1024 + hh * 32 + 16 + r];
        qv = q1 * s_c[r] - q2 * s_s[r];
        float k1 = krow[r];
        float k2 = krow[16 + r];
        kvv = k1 * s_c[r] - k2 * s_s[r];
      } else {
        int rr = r - 16;
        float q1 = qrow[1024 + hh * 32 + rr];
        float q2 = qrow[1024 + hh * 32 + 16 + rr];
        qv = q1 * s_s[rr] + q2 * s_c[rr];
        float k1 = krow[rr];
        float k2 = krow[16 + rr];
        kvv = k1 * s_s[rr] + k2 * s_c[rr];
      }
    }
    q_final[(size_t)l * 1536 + e] = qv;
    k_final[(size_t)l * 1536 + e] = kvv;
  }
}

// ---------------- fused: sparse attention (blocks 0..2047) + out zero ----------------
__global__ __launch_bounds__(256) void attn_out_kernel(
    const float* __restrict__ q_final, const float* __restrict__ k_final,
    const float* __restrict__ kv, const int* __restrict__ idx,
    unsigned short* __restrict__ attn_aug, float* __restrict__ outz) {
  int b = blockIdx.x;
  int tid = threadIdx.x;
  if (b >= 2048) {
    int j = (b - 2048) * 256 + tid;   // < 2097152 exact
    outz[j] = 0.f;
    return;
  }
  int l = (b & 7) * 256 + (b >> 3);
  int h = tid >> 4;
  int s = tid & 15;
  __shared__ __align__(16) float lg[16][64];
  __shared__ int iks[64];

  if (tid < 64) iks[tid] = idx[l * 64 + tid];

  const float* qrow = q_final + (size_t)l * 1536 + h * 96 + s * 2;
  float q0 = qrow[0],  q1 = qrow[1];
  float q2 = qrow[32], q3 = qrow[33];
  float q4 = qrow[64], q5 = qrow[65];
  __syncthreads();

#pragma unroll 4
  for (int k = 0; k < 64; ++k) {
    const float* kr = k_final + (size_t)iks[k] * 1536 + h * 96 + s * 2;
    float2 a = *(const float2*)kr;
    float2 b2 = *(const float2*)(kr + 32);
    float2 c = *(const float2*)(kr + 64);
    float d = q0 * a.x + q1 * a.y + q2 * b2.x + q3 * b2.y + q4 * c.x + q5 * c.y;
    d += __shfl_xor(d, 1);
    d += __shfl_xor(d, 2);
    d += __shfl_xor(d, 4);
    d += __shfl_xor(d, 8);
    if (s == 0) lg[h][k] = d * 0.10206207261596575f;
  }
  __syncthreads();

  f32x4 lv = *(const f32x4*)&lg[h][s * 4];
  float m = fmaxf(fmaxf(lv[0], lv[1]), fmaxf(lv[2], lv[3]));
#pragma unroll
  for (int off = 1; off < 16; off <<= 1) m = fmaxf(m, __shfl_xor(m, off));
  f32x4 ev;
  ev[0] = expf(lv[0] - m); ev[1] = expf(lv[1] - m);
  ev[2] = expf(lv[2] - m); ev[3] = expf(lv[3] - m);
  float ssum = ev[0] + ev[1] + ev[2] + ev[3];
#pragma unroll
  for (int off = 1; off < 16; off <<= 1) ssum += __shfl_xor(ssum, off);
  float inv = 1.f / ssum;
  lg[h][s * 4 + 0] = ev[0] * inv;
  lg[h][s * 4 + 1] = ev[1] * inv;
  lg[h][s * 4 + 2] = ev[2] * inv;
  lg[h][s * 4 + 3] = ev[3] * inv;
  __syncthreads();

  f32x4 acc = {};
#pragma unroll 4
  for (int k = 0; k < 64; ++k) {
    const float* vr = kv + (size_t)iks[k] * 2048 + 1024 + tid * 4;
    f32x4 v = *(const f32x4*)vr;
    acc += splat4(lg[h][k]) * v;
  }

#pragma unroll
  for (int i = 0; i < 4; ++i) {
    float a = acc[i];
    unsigned short hi = f2bf(a);
    unsigned short lo = f2bf(a - bf2f(hi));
    size_t o = ((size_t)l * 1024 + tid * 4 + i) * 3;
    attn_aug[o] = hi; attn_aug[o + 1] = lo; attn_aug[o + 2] = hi;
  }
}

// ---------------- host ----------------
extern "C" void kernel_launch(void* const* d_in, const int* in_sizes, int n_in,
                              void* d_out, int out_size, void* d_ws, size_t ws_size,
                              hipStream_t stream) {
  const float* x          = (const float*)d_in[0];
  const float* idx_in_w   = (const float*)d_in[1];
  const float* idx_conv_w = (const float*)d_in[2];
  const float* idx_conv_b = (const float*)d_in[3];
  const float* idx_dt_b   = (const float*)d_in[4];
  const float* idx_A_log  = (const float*)d_in[5];
  const float* idx_D      = (const float*)d_in[6];
  const float* idx_norm_w = (const float*)d_in[7];
  const float* idx_out_w  = (const float*)d_in[8];
  const float* idx_q_w    = (const float*)d_in[9];
  const float* idx_k_w    = (const float*)d_in[10];
  const float* q_down_w   = (const float*)d_in[11];
  const float* q_up_w     = (const float*)d_in[12];
  const float* q_rope_w   = (const float*)d_in[13];
  const float* kv_down_w  = (const float*)d_in[14];
  const float* kv_up_w    = (const float*)d_in[15];
  const float* k_rope_w   = (const float*)d_in[16];
  const float* out_w      = (const float*)d_in[17];
  float* out = (float*)d_out;

  float* p = (float*)d_ws;
  float* segA = p; p += 4718592;  // zxbcdt[2048x2304] | scores | qbuf
  float* segB = p; p += 2359296;  // xBC | {q_idx, k_idx, c3}
  float* dtb = p; p += 65536;
  float* logdA = p; p += 65536;
  float* lcdb = p; p += 65536;
  int*   idxb = (int*)p; p += 131072;
  float* segD = p; p += 4194304;  // y_ssm+hstate | kvb
  float* segBig1 = p; p += 6291456;  // x_trip | w_outp_aug (after in_proj)
  float* segBig2 = p; p += 7077888;  // w_in_trip | {y_norm|x_aug|q_final}@0, attn_aug@3145728
  float* segH = p; p += 3145728;     // {out_w_T,qwpad,Wq} | k_final
  unsigned short* w_3down_aug = (unsigned short*)p; p += 589824;
  unsigned short* w_qups_aug  = (unsigned short*)p; p += 294912;
  unsigned short* w_kvup_aug  = (unsigned short*)p; p += 393216;
  unsigned short* c_q_aug     = (unsigned short*)p; p += 393216;
  unsigned short* c_kv_aug    = (unsigned short*)p; p += 393216;
  float* Gbuf = p; p += 131072;

  float* zxbcdt = segA;
  float* scores = segA;
  float* qbuf   = segA;
  float* xBC    = segB;
  float* q_idx  = segB;
  float* k_idx  = segB + 131072;
  float* c3     = segB + 262144;
  float* y_ssm  = segD;
  float* hstate = segD + 2097152;
  float* kvb    = segD;
  unsigned short* x_trip     = (unsigned short*)segBig1;  // dead after in_proj
  unsigned short* w_outp_aug = (unsigned short*)segBig1;  // written after in_proj
  unsigned short* w_in_trip  = (unsigned short*)segBig2;  // dead after in_proj
  float* y_norm  = segBig2;                               // gatenorm..q_idx gemm
  unsigned short* x_aug = (unsigned short*)segBig2;       // after topk..down-proj
  float* q_final = segBig2;                               // rope_pack..attn
  unsigned short* attn_aug = (unsigned short*)(segBig2 + 3145728);
  float* out_w_T = segH;
  float* qwpad   = segH + 1048576;
  float* Wq      = segH + 1179648;
  float* k_final = segH;                                  // after q_idx gemm

  dim3 blk(256);
  auto cdiv = [](int a, int b) { return (a + b - 1) / b; };
  auto gemmf3 = [&](const float* A, const float* W, float* C, int M, int N, int K, int S, int tri) {
    dim3 grid(cdiv(N, 128), M / 128, S);
    hipLaunchKernelGGL(gemm_f32_v3, grid, blk, 0, stream, A, W, C, M, N, K, tri);
  };
  auto gemmb = [&](const unsigned short* A, const unsigned short* W, float* C,
                   int M, int N, int K, int lda, int ldb, int ldc, int S) {
    dim3 grid(N / 128, M / 128, S);
    hipLaunchKernelGGL(gemm_bf16_kernel, grid, blk, 0, stream, A, W, C, M, N, K, lda, ldb, ldc);
  };

  // ---- weight precomputes: one launch (conversions + transpose + qwpad/Wq init + zxbcdt zero) ----
  hipLaunchKernelGGL(prep_weights_kernel, dim3(41216), blk, 0, stream,
                     x, x_trip, idx_in_w, w_in_trip,
                     q_down_w, kv_down_w, k_rope_w, w_3down_aug,
                     q_up_w, q_rope_w, w_qups_aug, kv_up_w, w_kvup_aug,
                     idx_out_w, out_w_T, idx_q_w, qwpad, zxbcdt);
  gemmf3(qwpad, out_w_T, Wq, 128, 1024, 1024, 8, 0);

  // ---- mamba branch: in_proj via 256^2 pipelined MFMA (S=3, atomic; zxbcdt pre-zeroed) ----
  {
    dim3 grid(9, 8, 3);
    hipLaunchKernelGGL(gemm_bf16_256_kernel, grid, dim3(512), 0, stream,
                       x_trip, w_in_trip, zxbcdt, 6144, 6144, INDIMP);
  }
  hipLaunchKernelGGL(post_inproj_kernel, dim3(13568), blk, 0, stream,
                     out_w, w_outp_aug, zxbcdt, idx_conv_w, idx_conv_b, xBC,
                     idx_dt_b, idx_A_log, dtb, logdA);
  hipLaunchKernelGGL(chunk_G_kernel, dim3(NCH + 4), blk, 0, stream,
                     xBC, Gbuf, logdA, lcdb);
  hipLaunchKernelGGL(scan_local_kernel, dim3(NCH * MNH), blk, 0, stream,
                     xBC, dtb, lcdb, hstate);
  hipLaunchKernelGGL(scan_combine_kernel, dim3(256), blk, 0, stream, hstate, lcdb);
  hipLaunchKernelGGL(scan_y_kernel, dim3(NCH * MNH), blk, 0, stream,
                     xBC, Gbuf, dtb, lcdb, hstate, y_ssm);
  hipLaunchKernelGGL(gatenorm_kernel, dim3(L), blk, 0, stream,
                     y_ssm, xBC, zxbcdt, idx_D, idx_norm_w, y_norm);

  // ---- index scores + topk (out-proj folded into Wq) ----
  hipMemsetAsync(q_idx, 0, 262144 * 4, stream);   // q_idx+k_idx (aliases xBC; must follow gatenorm)
  {
    dim3 grid(1, 16, 32);
    hipLaunchKernelGGL(gemm_f32_dual, grid, blk, 0, stream,
                       y_norm, Wq, q_idx, x, idx_k_w, k_idx, 2048, 64, 1024, 16);
  }
  gemmf3(q_idx, k_idx, scores, 2048, 2048, 64, 1, 1);
  // fused: topk + augA(x->x_aug; y_norm dead) + c3 zero
  hipLaunchKernelGGL(topk_augA_kernel, dim3(13312), blk, 0, stream,
                     scores, idxb, x, x_aug, c3);

  // ---- attention value path (aug split-bf16 MFMA) ----
  gemmb(x_aug, w_3down_aug, c3, 2048, 384, 3072, 3072, 3072, 384, 8);
  hipLaunchKernelGGL(conv_augA2_kernel, dim3(cdiv(2048 * 256, 256)), blk, 0, stream,
                     c3, c_q_aug, c_kv_aug);
  {
    dim3 grid(28, 16, 1);
    hipLaunchKernelGGL(gemm_bf16_dual, grid, blk, 0, stream,
                       c_q_aug, w_qups_aug, qbuf,
                       c_kv_aug, w_kvup_aug, kvb,
                       12, 1536, 2048, 384, 384);
  }
  hipLaunchKernelGGL(rope_pack_kernel, dim3(L), dim3(128), 0, stream,
                     qbuf, kvb, c3, q_final, k_final);

  // ---- sparse attention (+ out zero region) + output projection ----
  hipLaunchKernelGGL(attn_out_kernel, dim3(10240), blk, 0, stream,
                     q_final, k_final, kvb, idxb, attn_aug, out);
  gemmb(attn_aug, w_outp_aug, out, 2048, 1024, 3072, 3072, 3072, 1024, 4);
}